// Round 13
// baseline (4304.073 us; speedup 1.0000x reference)
//
#include <hip/hip_runtime.h>
#include <math.h>

typedef unsigned short ushortT;
typedef __attribute__((ext_vector_type(4))) float f32x4;
typedef __attribute__((ext_vector_type(4))) unsigned int u32x4;
typedef __attribute__((ext_vector_type(4))) unsigned short u16x4;
typedef __attribute__((ext_vector_type(4))) int i32x4;
typedef __attribute__((ext_vector_type(8))) __bf16 bf16x8;

namespace {
constexpr int S = 256;
constexpr int H = 768;
constexpr int NLAY = 12;
constexpr int NHD = 12;
constexpr int FF = 3072;
constexpr int LBL = 9;
constexpr int DH = 64;
constexpr int BATCH = 32;
constexpr int TOKENS = BATCH * S;      // 8192
constexpr int QKVN = 3 * H;            // 2304
// softmax scale folded into exponent: p = exp2(C2*(s_raw - m_raw)), C2 = 0.125*log2(e)
constexpr float C2 = 0.18033688011112042f;

// workspace layout (float-slot units)
constexpr size_t HB_OFF  = 0;                            // h bf16 (half slots)
constexpr size_t QB_OFF  = HB_OFF + (size_t)TOKENS*H/2;  // q / ctx / ff2out bf16
constexpr size_t KB_OFF  = QB_OFF + (size_t)TOKENS*H/2;  // k / attn-out bf16
constexpr size_t VT_OFF  = KB_OFF + (size_t)TOKENS*H/2;  // v^T bf16 [B*NH*DH][S]
constexpr size_t BIG_OFF = VT_OFF + (size_t)TOKENS*H/2;  // probs bf16 == ff1 bf16
constexpr size_t WTQ_OFF = BIG_OFF + (size_t)TOKENS*FF/2;  // Wq^T,Wk^T,Wv^T contiguous
constexpr size_t WTO_OFF = WTQ_OFF + 3*(size_t)H*H/2;
constexpr size_t WT1_OFF = WTO_OFF + (size_t)H*H/2;      // W1^T [3072][768]
constexpr size_t WT2_OFF = WT1_OFF + (size_t)H*FF/2;     // W2^T [768][3072]
constexpr size_t EM_OFF  = WT2_OFF + (size_t)H*FF/2;
constexpr size_t PART_OFF= EM_OFF + (size_t)TOKENS*LBL;
constexpr size_t BQKV_OFF= PART_OFF + 64;                // packed qkv bias [12][2304]
constexpr size_t WS_FLOATS = BQKV_OFF + (size_t)NLAY*QKVN;
}

__device__ __forceinline__ ushortT f2bf(float x) {
    unsigned u = __builtin_bit_cast(unsigned, x);
    u += 0x7fffu + ((u >> 16) & 1u);
    return (ushortT)(u >> 16);
}
__device__ __forceinline__ float bf2f(ushortT h) {
    unsigned u = ((unsigned)h) << 16;
    return __builtin_bit_cast(float, u);
}

__device__ __forceinline__ float exp2i(float x) {
    float r; asm("v_exp_f32 %0, %1" : "=v"(r) : "v"(x)); return r;
}
__device__ __forceinline__ float log2i(float x) {
    float r; asm("v_log_f32 %0, %1" : "=v"(r) : "v"(x)); return r;
}

// tanh-gelu in sigmoid form: 0.5x(1+tanh(u)) == x*sigmoid(2u) == x/(1+exp2(-2u*log2e))
__device__ __forceinline__ float gelu_tanh(float x) {
    float u = 0.7978845608028654f * (x + 0.044715f * x * x * x);
    float t = exp2i(-2.8853900817779268f * u);
    return x / (1.0f + t);
}

__device__ __forceinline__ f32x4 mfma16(u32x4 a, u32x4 b, f32x4 c) {
    return __builtin_amdgcn_mfma_f32_16x16x32_bf16(
        __builtin_bit_cast(bf16x8, a), __builtin_bit_cast(bf16x8, b), c, 0, 0, 0);
}

__device__ __forceinline__ void gload_lds16(const ushortT* g, ushortT* l) {
    __builtin_amdgcn_global_load_lds(
        (const __attribute__((address_space(1))) unsigned int*)g,
        (__attribute__((address_space(3))) unsigned int*)l,
        16, 0, 0);
}

// =====================================================================
// WIDE bf16 MFMA GEMM: BM=128 x BN=256, 4 waves (2M x 2N), wave tile
// 64x128 (a[4] + b[8] frags -> 42.7 FLOP per LDS-byte vs 32 at 64x64 —
// the 128^2 kernel is LDS-read-bandwidth-bound at MfmaUtil 21%).
// Same 3-buffer counted-vmcnt pipeline; stage group = 6 loads/wave
// (A: 2 chunks, B: 4 chunks) -> vmcnt(6) certifies tile t landed with
// one group (tile t+1's) outstanding. Same both-sides T2 swizzle.
// MODE: 0 bias | 1 bias+gelu | 5 fused-QKV routing.
// Grid 2D, %8==0 -> XCD swizzle (T1).
// =====================================================================
template<int MODE>
__global__ __launch_bounds__(256) void gemm_wide(
    const ushortT* __restrict__ A, int lda,
    const ushortT* __restrict__ Bt, int ldb,
    const float* __restrict__ bias,
    void* __restrict__ Cv, int ldc, int K)
{
    __shared__ __align__(16) ushortT As[3][128 * 32];   // 24 KB
    __shared__ __align__(16) ushortT Bs[3][256 * 32];   // 48 KB
    const int tid = threadIdx.x;
    const int wave = tid >> 6, lane = tid & 63;

    int bxi = blockIdx.x, byi = blockIdx.y;
    {
        const int nwg = gridDim.x * gridDim.y;
        const int lin = byi * gridDim.x + bxi;
        const int cpx = nwg >> 3;
        const int sw = (lin & 7) * cpx + (lin >> 3);
        byi = sw / gridDim.x; bxi = sw - byi * gridDim.x;
    }
    const int bm = byi * 128, bn = bxi * 256;
    const ushortT* Ab = A + (size_t)bm * lda;
    const ushortT* Bb = Bt + (size_t)bn * ldb;
    const int wm = wave >> 1, wn = wave & 1;

    const int lrow = lane >> 2;
    const int lsw16 = ((lane & 3) ^ ((lrow >> 1) & 3)) * 8;
    const int rl = lane & 15;
    const int kg4 = (lane >> 4) << 2;
    const int ksw = ((lane >> 4) ^ ((rl >> 1) & 3)) << 3;

    f32x4 acc[4][8];
#pragma unroll
    for (int i = 0; i < 4; ++i)
#pragma unroll
        for (int j = 0; j < 8; ++j) acc[i][j] = (f32x4){0.f, 0.f, 0.f, 0.f};

    auto stage = [&](int buf, int k0) {
#pragma unroll
        for (int j = 0; j < 2; ++j) {
            int chunk = j * 4 + wave;                    // A chunks 0..7
            gload_lds16(Ab + (size_t)(chunk * 16 + lrow) * lda + k0 + lsw16,
                        &As[buf][chunk * 512]);
        }
#pragma unroll
        for (int j = 0; j < 4; ++j) {
            int chunk = j * 4 + wave;                    // B chunks 0..15
            gload_lds16(Bb + (size_t)(chunk * 16 + lrow) * ldb + k0 + lsw16,
                        &Bs[buf][chunk * 512]);
        }
    };

    const int nt = K >> 5;
    stage(0, 0);
    stage(1, ((nt > 1) ? 1 : 0) << 5);
    int cur = 0;
    for (int t = 0; t < nt; ++t) {
        asm volatile("s_waitcnt vmcnt(6)" ::: "memory"); // tile t landed (1 group out)
        __builtin_amdgcn_s_barrier();
        __builtin_amdgcn_sched_barrier(0);
        u32x4 a[4], b[8];
#pragma unroll
        for (int mf = 0; mf < 4; ++mf)
            a[mf] = *(const u32x4*)&As[cur][(wm * 64 + mf * 16 + rl) * 32 + ksw];
#pragma unroll
        for (int nf = 0; nf < 8; ++nf)
            b[nf] = *(const u32x4*)&Bs[cur][(wn * 128 + nf * 16 + rl) * 32 + ksw];
        {
            const int nx = (t + 2 < nt) ? t + 2 : nt - 1;
            int nb = cur + 2; if (nb >= 3) nb -= 3;
            stage(nb, nx << 5);
        }
#pragma unroll
        for (int mf = 0; mf < 4; ++mf)
#pragma unroll
            for (int nf = 0; nf < 8; ++nf)
                acc[mf][nf] = mfma16(a[mf], b[nf], acc[mf][nf]);
        cur = (cur + 1 == 3) ? 0 : cur + 1;
    }
    asm volatile("s_waitcnt vmcnt(0)" ::: "memory");

    ushortT* Ch = (ushortT*)Cv;
#pragma unroll
    for (int nf = 0; nf < 8; ++nf) {
        const int gn = bn + wn * 128 + nf * 16 + rl;
        const float bv = bias[gn];
#pragma unroll
        for (int mf = 0; mf < 4; ++mf) {
            const int gm = bm + wm * 64 + mf * 16 + kg4;
            if constexpr (MODE == 5) {
                const int region = gn / H;          // 0=q,1=k,2=v
                const int col = gn - region * H;
                if (region < 2) {
                    ushortT* o = (ushortT*)Cv + (size_t)region * TOKENS * H;
#pragma unroll
                    for (int r = 0; r < 4; ++r)
                        o[(size_t)(gm + r) * H + col] = f2bf(acc[mf][nf][r] + bv);
                } else {
                    u16x4 o;
#pragma unroll
                    for (int r = 0; r < 4; ++r) o[r] = f2bf(acc[mf][nf][r] + bv);
                    const int b_ = gm >> 8, s0 = gm & 255;
                    const int h_ = col >> 6, dh = col & 63;
                    *(u16x4*)((ushortT*)Cv + 2 * (size_t)TOKENS * H +
                              (((size_t)(b_ * NHD + h_) * DH + dh) << 8) + s0) = o;
                }
            } else {
#pragma unroll
                for (int r = 0; r < 4; ++r) {
                    float x = acc[mf][nf][r] + bv;
                    if constexpr (MODE == 1) x = gelu_tanh(x);
                    Ch[(size_t)(gm + r) * ldc + gn] = f2bf(x);
                }
            }
        }
    }
}

// ---------------- narrow bf16 MFMA GEMM (64x64/wave), 3-buffer pipeline ----------------
// Retained for the batched attention GEMMs (scores MODE 6, PV MODE 4).
template<int WM, int WN, int MODE>
__global__ __launch_bounds__(256) void gemm_mfma(
    const ushortT* __restrict__ A, int lda, long long sAo, long long sAi,
    const ushortT* __restrict__ Bt, int ldb, long long sBo, long long sBi,
    const float* __restrict__ bias,
    void* __restrict__ Cv, int ldc, long long sCo, long long sCi,
    int K, int innerN)
{
    constexpr int BM = WM * 64, BN = WN * 64;
    __shared__ __align__(16) ushortT As[3][BM * 32];
    __shared__ __align__(16) ushortT Bs[3][BN * 32];
    const int tid = threadIdx.x;
    const int wave = tid >> 6, lane = tid & 63;
    const int ob = blockIdx.z / innerN, ib = blockIdx.z - ob * innerN;

    int bxi = blockIdx.x, byi = blockIdx.y;
    if (gridDim.z == 1) {
        const int nwg = gridDim.x * gridDim.y;
        const int lin = byi * gridDim.x + bxi;
        const int cpx = nwg >> 3;
        const int sw = (lin & 7) * cpx + (lin >> 3);
        byi = sw / gridDim.x; bxi = sw - byi * gridDim.x;
    }
    const int bm = byi * BM, bn = bxi * BN;
    const ushortT* Ab = A + ob * sAo + ib * sAi + (size_t)bm * lda;
    const ushortT* Bb = Bt + ob * sBo + ib * sBi + (size_t)bn * ldb;
    const int wm = wave / WN, wn = wave - wm * WN;

    const int lrow = lane >> 2;
    const int lsw16 = ((lane & 3) ^ ((lrow >> 1) & 3)) * 8;
    const int rl = lane & 15;
    const int kg4 = (lane >> 4) << 2;
    const int ksw = ((lane >> 4) ^ ((rl >> 1) & 3)) << 3;

    f32x4 acc[4][4];
#pragma unroll
    for (int i = 0; i < 4; ++i)
#pragma unroll
        for (int j = 0; j < 4; ++j) acc[i][j] = (f32x4){0.f, 0.f, 0.f, 0.f};

    auto stage = [&](int buf, int k0) {
#pragma unroll
        for (int j = 0; j < WM; ++j) {
            int chunk = j * 4 + wave;
            gload_lds16(Ab + (size_t)(chunk * 16 + lrow) * lda + k0 + lsw16,
                        &As[buf][chunk * 512]);
        }
#pragma unroll
        for (int j = 0; j < WN; ++j) {
            int chunk = j * 4 + wave;
            gload_lds16(Bb + (size_t)(chunk * 16 + lrow) * ldb + k0 + lsw16,
                        &Bs[buf][chunk * 512]);
        }
    };

    const int nt = K >> 5;
    stage(0, 0);
    stage(1, ((nt > 1) ? 1 : 0) << 5);
    int cur = 0;
    for (int t = 0; t < nt; ++t) {
        if constexpr (WM + WN == 4)
            asm volatile("s_waitcnt vmcnt(4)" ::: "memory");
        else
            asm volatile("s_waitcnt vmcnt(5)" ::: "memory");
        __builtin_amdgcn_s_barrier();
        __builtin_amdgcn_sched_barrier(0);
        u32x4 a[4], b[4];
#pragma unroll
        for (int mf = 0; mf < 4; ++mf)
            a[mf] = *(const u32x4*)&As[cur][(wm * 64 + mf * 16 + rl) * 32 + ksw];
#pragma unroll
        for (int nf = 0; nf < 4; ++nf)
            b[nf] = *(const u32x4*)&Bs[cur][(wn * 64 + nf * 16 + rl) * 32 + ksw];
        {
            const int nx = (t + 2 < nt) ? t + 2 : nt - 1;
            int nb = cur + 2; if (nb >= 3) nb -= 3;
            stage(nb, nx << 5);
        }
#pragma unroll
        for (int mf = 0; mf < 4; ++mf)
#pragma unroll
            for (int nf = 0; nf < 4; ++nf)
                acc[mf][nf] = mfma16(a[mf], b[nf], acc[mf][nf]);
        cur = (cur + 1 == 3) ? 0 : cur + 1;
    }
    asm volatile("s_waitcnt vmcnt(0)" ::: "memory");

    ushortT* Ch = (ushortT*)Cv + ob * sCo + ib * sCi;
    if constexpr (MODE == 6) {
        __shared__ float red6[2][4][64];
        const int* mrow = (const int*)bias + ob * S;
        float mb[4];
#pragma unroll
        for (int nf = 0; nf < 4; ++nf)
            mb[nf] = mrow[bn + wn * 64 + nf * 16 + rl] ? 0.f : -8e9f;
        float pm[4][4];
#pragma unroll
        for (int mf = 0; mf < 4; ++mf)
#pragma unroll
            for (int r = 0; r < 4; ++r) pm[mf][r] = -1e30f;
#pragma unroll
        for (int mf = 0; mf < 4; ++mf)
#pragma unroll
            for (int nf = 0; nf < 4; ++nf)
#pragma unroll
                for (int r = 0; r < 4; ++r) {
                    acc[mf][nf][r] += mb[nf];
                    pm[mf][r] = fmaxf(pm[mf][r], acc[mf][nf][r]);
                }
#pragma unroll
        for (int mf = 0; mf < 4; ++mf)
#pragma unroll
            for (int r = 0; r < 4; ++r) {
                float v = pm[mf][r];
                v = fmaxf(v, __shfl_xor(v, 1));
                v = fmaxf(v, __shfl_xor(v, 2));
                v = fmaxf(v, __shfl_xor(v, 4));
                v = fmaxf(v, __shfl_xor(v, 8));
                pm[mf][r] = v;
            }
        if (rl == 0) {
#pragma unroll
            for (int mf = 0; mf < 4; ++mf)
#pragma unroll
                for (int r = 0; r < 4; ++r)
                    red6[0][wn][mf * 16 + kg4 + r] = pm[mf][r];
        }
        __syncthreads();
        float Mx[4][4];
#pragma unroll
        for (int mf = 0; mf < 4; ++mf)
#pragma unroll
            for (int r = 0; r < 4; ++r) {
                const int row = mf * 16 + kg4 + r;
                Mx[mf][r] = fmaxf(fmaxf(red6[0][0][row], red6[0][1][row]),
                                  fmaxf(red6[0][2][row], red6[0][3][row]));
            }
        float ps[4][4];
#pragma unroll
        for (int mf = 0; mf < 4; ++mf)
#pragma unroll
            for (int r = 0; r < 4; ++r) ps[mf][r] = 0.f;
#pragma unroll
        for (int mf = 0; mf < 4; ++mf)
#pragma unroll
            for (int nf = 0; nf < 4; ++nf)
#pragma unroll
                for (int r = 0; r < 4; ++r) {
                    float e = exp2i(C2 * (acc[mf][nf][r] - Mx[mf][r]));
                    acc[mf][nf][r] = e;
                    ps[mf][r] += e;
                }
#pragma unroll
        for (int mf = 0; mf < 4; ++mf)
#pragma unroll
            for (int r = 0; r < 4; ++r) {
                float v = ps[mf][r];
                v += __shfl_xor(v, 1);
                v += __shfl_xor(v, 2);
                v += __shfl_xor(v, 4);
                v += __shfl_xor(v, 8);
                ps[mf][r] = v;
            }
        if (rl == 0) {
#pragma unroll
            for (int mf = 0; mf < 4; ++mf)
#pragma unroll
                for (int r = 0; r < 4; ++r)
                    red6[1][wn][mf * 16 + kg4 + r] = ps[mf][r];
        }
        __syncthreads();
#pragma unroll
        for (int mf = 0; mf < 4; ++mf) {
            float inv[4];
#pragma unroll
            for (int r = 0; r < 4; ++r) {
                const int row = mf * 16 + kg4 + r;
                inv[r] = 1.0f / (red6[1][0][row] + red6[1][1][row] +
                                 red6[1][2][row] + red6[1][3][row]);
            }
#pragma unroll
            for (int nf = 0; nf < 4; ++nf) {
                const int gn = bn + wn * 64 + nf * 16 + rl;
                const int gm = bm + mf * 16 + kg4;
#pragma unroll
                for (int r = 0; r < 4; ++r)
                    Ch[(size_t)(gm + r) * ldc + gn] = f2bf(acc[mf][nf][r] * inv[r]);
            }
        }
    } else {
#pragma unroll
        for (int nf = 0; nf < 4; ++nf) {
            int gn = bn + wn * 64 + nf * 16 + rl;
            float bv = 0.f;
            if constexpr (MODE != 4) bv = bias[gn];
#pragma unroll
            for (int mf = 0; mf < 4; ++mf) {
                int gm = bm + wm * 64 + mf * 16 + kg4;
#pragma unroll
                for (int r = 0; r < 4; ++r) {
                    float x = acc[mf][nf][r] + bv;
                    if constexpr (MODE == 1) x = gelu_tanh(x);
                    Ch[(size_t)(gm + r) * ldc + gn] = f2bf(x);
                }
            }
        }
    }
}

// ---------------- all 6 weight transposes of one layer, one dispatch ----------------
__global__ __launch_bounds__(256) void transpose_all_k(
    const float* __restrict__ Wq, const float* __restrict__ Wk,
    const float* __restrict__ Wv, const float* __restrict__ Wo,
    const float* __restrict__ W1, const float* __restrict__ W2,
    ushortT* __restrict__ wtqkv, ushortT* __restrict__ wto,
    ushortT* __restrict__ wt1, ushortT* __restrict__ wt2)
{
    int idx = blockIdx.x;
    const float* W; ushortT* WT; int R, C, tr, tc;
    if (idx < 2304) {
        int mat = idx / 576, t = idx - mat * 576;
        tr = t / 24; tc = t - tr * 24; R = 768; C = 768;
        W = mat == 0 ? Wq : mat == 1 ? Wk : mat == 2 ? Wv : Wo;
        WT = mat < 3 ? wtqkv + (size_t)mat * 768 * 768 : wto;
    } else if (idx < 4608) {
        int t = idx - 2304; tr = t / 96; tc = t - tr * 96;
        R = 768; C = 3072; W = W1; WT = wt1;
    } else {
        int t = idx - 4608; tr = t / 24; tc = t - tr * 24;
        R = 3072; C = 768; W = W2; WT = wt2;
    }
    int r0 = tr * 32, c0 = tc * 32;
    __shared__ float tl[32][33];
    int trd = threadIdx.x >> 3;
    int tc4 = (threadIdx.x & 7) * 4;
    const float4 v = *(const float4*)(W + (size_t)(r0 + trd) * C + c0 + tc4);
    tl[trd][tc4 + 0] = v.x; tl[trd][tc4 + 1] = v.y;
    tl[trd][tc4 + 2] = v.z; tl[trd][tc4 + 3] = v.w;
    __syncthreads();
    u16x4 o;
#pragma unroll
    for (int q = 0; q < 4; ++q) o[q] = f2bf(tl[tc4 + q][trd]);
    *(u16x4*)(WT + (size_t)(c0 + trd) * R + r0 + tc4) = o;
}

// ---------------- pack qkv biases -> [NLAY][2304] ----------------
__global__ __launch_bounds__(256) void pack_bias_k(
    const float* __restrict__ bq, const float* __restrict__ bk,
    const float* __restrict__ bv, float* __restrict__ out)
{
    int l = blockIdx.x / 3, r = blockIdx.x - (blockIdx.x / 3) * 3;
    const float* src = r == 0 ? bq : r == 1 ? bk : bv;
#pragma unroll
    for (int j = 0; j < 3; ++j) {
        int d = threadIdx.x + 256 * j;
        out[(size_t)l * QKVN + r * H + d] = src[(size_t)l * H + d];
    }
}

// ---------------- embeddings + LN -> bf16 h; 4 tokens/block, 1 wave/token ----------------
__global__ __launch_bounds__(256) void embed_ln_k(
    const int* __restrict__ ids, const int* __restrict__ tts,
    const float* __restrict__ wemb, const float* __restrict__ pemb,
    const float* __restrict__ temb, const float* __restrict__ g,
    const float* __restrict__ bp, ushortT* __restrict__ hb)
{
    const int tok = blockIdx.x * 4 + (threadIdx.x >> 6);
    const int lane = threadIdx.x & 63;
    const int d0 = lane * 12;
    const int spos = tok & (S - 1);
    const int id = ids[tok], tt = tts[tok];
    const float* wr = wemb + (size_t)id * H + d0;
    const float* pr = pemb + (size_t)spos * H + d0;
    const float* tr = temb + (size_t)tt * H + d0;
    float x[12]; float s = 0.f, ss = 0.f;
#pragma unroll
    for (int j = 0; j < 3; ++j) {
        float4 a = *(const float4*)(wr + j * 4);
        float4 b = *(const float4*)(pr + j * 4);
        float4 c = *(const float4*)(tr + j * 4);
        float v0 = a.x + b.x + c.x, v1 = a.y + b.y + c.y;
        float v2 = a.z + b.z + c.z, v3 = a.w + b.w + c.w;
        x[j*4+0] = v0; x[j*4+1] = v1; x[j*4+2] = v2; x[j*4+3] = v3;
        s += v0 + v1 + v2 + v3;
        ss += v0*v0 + v1*v1 + v2*v2 + v3*v3;
    }
#pragma unroll
    for (int m = 32; m; m >>= 1) { s += __shfl_xor(s, m); ss += __shfl_xor(ss, m); }
    float mu = s * (1.f / H);
    float var = ss * (1.f / H) - mu * mu;
    float rs = rsqrtf(var + 1e-12f);
#pragma unroll
    for (int j = 0; j < 3; ++j) {
        float4 gv = *(const float4*)(g + d0 + j * 4);
        float4 bv = *(const float4*)(bp + d0 + j * 4);
        u16x4 o;
        o[0] = f2bf((x[j*4+0] - mu) * rs * gv.x + bv.x);
        o[1] = f2bf((x[j*4+1] - mu) * rs * gv.y + bv.y);
        o[2] = f2bf((x[j*4+2] - mu) * rs * gv.z + bv.z);
        o[3] = f2bf((x[j*4+3] - mu) * rs * gv.w + bv.w);
        *(u16x4*)(hb + (size_t)tok * H + d0 + j * 4) = o;
    }
}

// ---------------- bf16 residual add + LN, in place on hb; 4 tokens/block ----------------
__global__ __launch_bounds__(256) void add_ln_k(
    ushortT* __restrict__ hb, const ushortT* __restrict__ add,
    const float* __restrict__ g, const float* __restrict__ bp)
{
    const int tok = blockIdx.x * 4 + (threadIdx.x >> 6);
    const int lane = threadIdx.x & 63;
    const int d0 = lane * 12;
    const size_t base = (size_t)tok * H + d0;
    float x[12]; float s = 0.f, ss = 0.f;
#pragma unroll
    for (int j = 0; j < 3; ++j) {
        u16x4 hv = *(const u16x4*)(hb + base + j * 4);
        u16x4 av = *(const u16x4*)(add + base + j * 4);
#pragma unroll
        for (int q = 0; q < 4; ++q) {
            float v = bf2f(hv[q]) + bf2f(av[q]);
            x[j*4+q] = v; s += v; ss += v * v;
        }
    }
#pragma unroll
    for (int m = 32; m; m >>= 1) { s += __shfl_xor(s, m); ss += __shfl_xor(ss, m); }
    float mu = s * (1.f / H);
    float var = ss * (1.f / H) - mu * mu;
    float rs = rsqrtf(var + 1e-12f);
#pragma unroll
    for (int j = 0; j < 3; ++j) {
        float4 gv = *(const float4*)(g + d0 + j * 4);
        float4 bv = *(const float4*)(bp + d0 + j * 4);
        u16x4 o;
        o[0] = f2bf((x[j*4+0] - mu) * rs * gv.x + bv.x);
        o[1] = f2bf((x[j*4+1] - mu) * rs * gv.y + bv.y);
        o[2] = f2bf((x[j*4+2] - mu) * rs * gv.z + bv.z);
        o[3] = f2bf((x[j*4+3] - mu) * rs * gv.w + bv.w);
        *(u16x4*)(hb + base + j * 4) = o;
    }
}

// ---------------- logits + log_softmax over 9 labels (bf16 h, f32 math) ----------------
__global__ __launch_bounds__(256) void logits_k(
    const ushortT* __restrict__ hb, const float* __restrict__ fcw,
    float* __restrict__ em)
{
    int tok = blockIdx.x, tid = threadIdx.x;
    float p[LBL];
#pragma unroll
    for (int l = 0; l < LBL; ++l) p[l] = 0.f;
    const ushortT* hr = hb + (size_t)tok * H;
#pragma unroll
    for (int j = 0; j < 3; ++j) {
        int d = tid + 256 * j;
        float hv = bf2f(hr[d]);
        const float* fr = fcw + (size_t)d * LBL;
#pragma unroll
        for (int l = 0; l < LBL; ++l) p[l] = fmaf(hv, fr[l], p[l]);
    }
    __shared__ float ls[4][LBL];
    __shared__ float lg[LBL];
    __shared__ float lse;
#pragma unroll
    for (int l = 0; l < LBL; ++l) {
        float v = p[l];
#pragma unroll
        for (int m = 32; m; m >>= 1) v += __shfl_xor(v, m);
        if ((tid & 63) == 0) ls[tid >> 6][l] = v;
    }
    __syncthreads();
    if (tid < LBL) lg[tid] = ls[0][tid] + ls[1][tid] + ls[2][tid] + ls[3][tid];
    __syncthreads();
    if (tid == 0) {
        float mx = lg[0];
#pragma unroll
        for (int j = 1; j < LBL; ++j) mx = fmaxf(mx, lg[j]);
        float sm = 0.f;
#pragma unroll
        for (int j = 0; j < LBL; ++j) sm += expf(lg[j] - mx);
        lse = mx + logf(sm);
    }
    __syncthreads();
    if (tid < LBL) em[(size_t)tok * LBL + tid] = lg[tid] - lse;
}

// ---------------- CRF: one wave per batch elem, base-2 fast recursion ----------------
__global__ __launch_bounds__(64) void crf_k(
    const float* __restrict__ em, const int* __restrict__ tags,
    const int* __restrict__ mask, const float* __restrict__ sp,
    const float* __restrict__ ep, const float* __restrict__ trans,
    float* __restrict__ partial)
{
    constexpr float LOG2E = 1.4426950408889634f;
    constexpr float LN2   = 0.6931471805599453f;
    int b = blockIdx.x, t = threadIdx.x;
    __shared__ float eml[S * LBL];     // emissions * log2(e)
    __shared__ int mkl[S];
    const float* emb = em + (size_t)b * S * LBL;
    const int* tg = tags + (size_t)b * S;
    const int* mk = mask + (size_t)b * S;

    for (int i = t * 4; i < S * LBL; i += 256) {
        float4 v = *(const float4*)&emb[i];
        v.x *= LOG2E; v.y *= LOG2E; v.z *= LOG2E; v.w *= LOG2E;
        *(float4*)&eml[i] = v;
    }
    *(i32x4*)&mkl[t * 4] = *(const i32x4*)&mk[t * 4];

    int cnt = 0; float ns = 0.f;
    for (int i = t; i < S; i += 64) {
        int m = mk[i];
        cnt += (m != 0);
        if (i >= 1 && m)
            ns += trans[tg[i - 1] * LBL + tg[i]] + emb[(size_t)i * LBL + tg[i]];
    }
#pragma unroll
    for (int m = 32; m; m >>= 1) { cnt += __shfl_xor(cnt, m); ns += __shfl_xor(ns, m); }
    float num = ns + sp[tg[0]] + emb[tg[0]] + ep[tg[cnt - 1]];

    int tt = t < LBL ? t : 0;
    float trc2[LBL];
#pragma unroll
    for (int i = 0; i < LBL; ++i) trc2[i] = trans[i * LBL + tt] * LOG2E;

    __syncthreads();

    float alpha2 = (t < LBL) ? sp[t] * LOG2E + eml[t] : -1e30f;
    for (int step = 1; step < S; ++step) {
        float av[LBL];
#pragma unroll
        for (int i = 0; i < LBL; ++i) av[i] = __shfl(alpha2, i) + trc2[i];
        float mx = av[0];
#pragma unroll
        for (int i = 1; i < LBL; ++i) mx = fmaxf(mx, av[i]);
        float sm = 0.f;
#pragma unroll
        for (int i = 0; i < LBL; ++i) sm += exp2i(av[i] - mx);
        float na = mx + log2i(sm) + eml[step * LBL + tt];
        alpha2 = (mkl[step] && t < LBL) ? na : alpha2;
    }
    float z = (t < LBL) ? alpha2 + ep[t] * LOG2E : -1e30f;
    float mx = z;
#pragma unroll
    for (int m = 8; m; m >>= 1) mx = fmaxf(mx, __shfl_xor(mx, m));
    float sm = exp2i(z - mx);
#pragma unroll
    for (int m = 8; m; m >>= 1) sm += __shfl_xor(sm, m);
    if (t == 0) partial[b] = (mx + log2i(sm)) * LN2 - num;
}

__global__ void finalize_k(const float* __restrict__ partial, float* __restrict__ out) {
    float s = 0.f;
    for (int i = 0; i < BATCH; ++i) s += partial[i];
    out[0] = s;
}

__global__ void sentinel_k(float* out) { out[0] = -12345.0f; }

extern "C" void kernel_launch(void* const* d_in, const int* in_sizes, int n_in,
                              void* d_out, int out_size, void* d_ws, size_t ws_size,
                              hipStream_t stream) {
    (void)in_sizes; (void)n_in; (void)out_size;
    const int* token_ids  = (const int*)d_in[0];
    const int* token_type = (const int*)d_in[1];
    const int* amask      = (const int*)d_in[2];
    const int* y          = (const int*)d_in[3];
    const float* wemb = (const float*)d_in[4];
    const float* pemb = (const float*)d_in[5];
    const float* temb = (const float*)d_in[6];
    const float* eg   = (const float*)d_in[7];
    const float* eb   = (const float*)d_in[8];
    const float* Wq = (const float*)d_in[9];
    const float* bq = (const float*)d_in[10];
    const float* Wk = (const float*)d_in[11];
    const float* bk = (const float*)d_in[12];
    const float* Wv = (const float*)d_in[13];
    const float* bv = (const float*)d_in[14];
    const float* Wo = (const float*)d_in[15];
    const float* bo = (const float*)d_in[16];
    const float* ln1g = (const float*)d_in[17];
    const float* ln1b = (const float*)d_in[18];
    const float* W1 = (const float*)d_in[19];
    const float* b1 = (const float*)d_in[20];
    const float* W2 = (const float*)d_in[21];
    const float* b2 = (const float*)d_in[22];
    const float* ln2g = (const float*)d_in[23];
    const float* ln2b = (const float*)d_in[24];
    const float* fcw = (const float*)d_in[25];
    const float* crf_s = (const float*)d_in[26];
    const float* crf_e = (const float*)d_in[27];
    const float* crf_t = (const float*)d_in[28];

    if (ws_size < WS_FLOATS * sizeof(float)) {
        sentinel_k<<<1, 1, 0, stream>>>((float*)d_out);
        return;
    }

    float* ws = (float*)d_ws;
    ushortT* hb   = (ushortT*)(ws + HB_OFF);
    ushortT* qb   = (ushortT*)(ws + QB_OFF);   // q base; k = +TOKENS*H; vt = +2*TOKENS*H
    ushortT* kb   = (ushortT*)(ws + KB_OFF);
    ushortT* vt   = (ushortT*)(ws + VT_OFF);
    ushortT* big  = (ushortT*)(ws + BIG_OFF);
    ushortT* wtq  = (ushortT*)(ws + WTQ_OFF);  // [2304][768]
    ushortT* wto  = (ushortT*)(ws + WTO_OFF);
    ushortT* wt1  = (ushortT*)(ws + WT1_OFF);
    ushortT* wt2  = (ushortT*)(ws + WT2_OFF);
    float*   embuf = ws + EM_OFF;
    float*   part  = ws + PART_OFF;
    float*   bqkv  = ws + BQKV_OFF;

    pack_bias_k<<<NLAY * 3, 256, 0, stream>>>(bq, bk, bv, bqkv);
    embed_ln_k<<<TOKENS / 4, 256, 0, stream>>>(token_ids, token_type, wemb, pemb,
                                               temb, eg, eb, hb);

    constexpr long long HH = (long long)H * H;
    constexpr long long HF = (long long)H * FF;
    constexpr long long TOKH = (long long)S * H;        // 196608
    constexpr long long ATT_B = (long long)NHD * S * S; // 786432
    constexpr long long ATT_H = (long long)S * S;       // 65536
    constexpr long long VT_B = (long long)NHD * DH * S; // 196608
    constexpr long long VT_H = (long long)DH * S;       // 16384

    dim3 gQKV(QKVN / 256, TOKENS / 128, 1);       // 9 x 64 = 576 (%8==0)
    dim3 gProj(H / 256, TOKENS / 128, 1);         // 3 x 64 = 192
    dim3 gFF1(FF / 256, TOKENS / 128, 1);         // 12 x 64 = 768
    dim3 gScores(1, S / 64, BATCH * NHD);         // (N/256, M/64, 384) = 1x4x384
    dim3 gPV(1, 1, BATCH * NHD);                  // 256x64 tile covers head

    for (int l = 0; l < NLAY; ++l) {
        transpose_all_k<<<6912, 256, 0, stream>>>(
            Wq + l * HH, Wk + l * HH, Wv + l * HH, Wo + l * HH,
            W1 + l * HF, W2 + l * HF, wtq, wto, wt1, wt2);

        // fused q,k,v projections (wide 128x256 tile with routing epilogue)
        gemm_wide<5><<<gQKV, 256, 0, stream>>>(
            hb, H, wtq, H, bqkv + (size_t)l * QKVN, qb, H, H);

        // probs = softmax(mask(q @ k^T)) per (b,h), fused epilogue -> bf16
        gemm_mfma<1,4,6><<<gScores, 256, 0, stream>>>(
            qb, H, TOKH, DH, kb, H, TOKH, DH, (const float*)amask,
            big, S, ATT_B, ATT_H, DH, NHD);

        // ctx = probs @ v  (per b,h) -> qb as [B,S,NH,DH] bf16
        gemm_mfma<4,1,4><<<gPV, 256, 0, stream>>>(
            big, S, ATT_B, ATT_H, vt, S, VT_B, VT_H, nullptr,
            qb, H, TOKH, DH, S, NHD);

        // attention output projection -> kb (bf16)
        gemm_wide<0><<<gProj, 256, 0, stream>>>(
            qb, H, wto, H, bo + l * H, kb, H, H);

        add_ln_k<<<TOKENS / 4, 256, 0, stream>>>(hb, kb, ln1g + l * H, ln1b + l * H);

        // ff1 = gelu(h @ W1 + b1) -> big bf16
        gemm_wide<1><<<gFF1, 256, 0, stream>>>(
            hb, H, wt1, H, b1 + (long long)l * FF, big, FF, H);

        // ff2 -> qb (bf16)
        gemm_wide<0><<<gProj, 256, 0, stream>>>(
            big, FF, wt2, FF, b2 + l * H, qb, H, FF);

        add_ln_k<<<TOKENS / 4, 256, 0, stream>>>(hb, qb, ln2g + l * H, ln2b + l * H);
    }

    logits_k<<<TOKENS, 256, 0, stream>>>(hb, fcw, embuf);
    crf_k<<<BATCH, 64, 0, stream>>>(embuf, y, amask, crf_s, crf_e, crf_t, part);
    finalize_k<<<1, 1, 0, stream>>>(part, (float*)d_out);
}

// Round 14
// 3076.242 us; speedup vs baseline: 1.3991x; 1.3991x over previous
//
#include <hip/hip_runtime.h>
#include <math.h>

typedef unsigned short ushortT;
typedef __attribute__((ext_vector_type(4))) float f32x4;
typedef __attribute__((ext_vector_type(4))) unsigned int u32x4;
typedef __attribute__((ext_vector_type(4))) unsigned short u16x4;
typedef __attribute__((ext_vector_type(4))) int i32x4;
typedef __attribute__((ext_vector_type(8))) __bf16 bf16x8;

namespace {
constexpr int S = 256;
constexpr int H = 768;
constexpr int NLAY = 12;
constexpr int NHD = 12;
constexpr int FF = 3072;
constexpr int LBL = 9;
constexpr int DH = 64;
constexpr int BATCH = 32;
constexpr int TOKENS = BATCH * S;      // 8192
constexpr int QKVN = 3 * H;            // 2304
// softmax scale folded into exponent: p = exp2(C2*(s_raw - m_raw)), C2 = 0.125*log2(e)
constexpr float C2 = 0.18033688011112042f;

// workspace layout (float-slot units)
constexpr size_t HB_OFF  = 0;                            // h bf16 (half slots)
constexpr size_t QB_OFF  = HB_OFF + (size_t)TOKENS*H/2;  // q / ctx / ff2out bf16
constexpr size_t KB_OFF  = QB_OFF + (size_t)TOKENS*H/2;  // k / attn-out bf16
constexpr size_t VT_OFF  = KB_OFF + (size_t)TOKENS*H/2;  // v^T bf16 [B*NH*DH][S]
constexpr size_t BIG_OFF = VT_OFF + (size_t)TOKENS*H/2;  // probs bf16 == ff1 bf16
constexpr size_t WTQ_OFF = BIG_OFF + (size_t)TOKENS*FF/2;  // Wq^T,Wk^T,Wv^T contiguous
constexpr size_t WTO_OFF = WTQ_OFF + 3*(size_t)H*H/2;
constexpr size_t WT1_OFF = WTO_OFF + (size_t)H*H/2;      // W1^T [3072][768]
constexpr size_t WT2_OFF = WT1_OFF + (size_t)H*FF/2;     // W2^T [768][3072]
constexpr size_t EM_OFF  = WT2_OFF + (size_t)H*FF/2;
constexpr size_t PART_OFF= EM_OFF + (size_t)TOKENS*LBL;
constexpr size_t BQKV_OFF= PART_OFF + 64;                // packed qkv bias [12][2304]
constexpr size_t WS_FLOATS = BQKV_OFF + (size_t)NLAY*QKVN;
}

__device__ __forceinline__ ushortT f2bf(float x) {
    unsigned u = __builtin_bit_cast(unsigned, x);
    u += 0x7fffu + ((u >> 16) & 1u);
    return (ushortT)(u >> 16);
}
__device__ __forceinline__ float bf2f(ushortT h) {
    unsigned u = ((unsigned)h) << 16;
    return __builtin_bit_cast(float, u);
}

__device__ __forceinline__ float exp2i(float x) {
    float r; asm("v_exp_f32 %0, %1" : "=v"(r) : "v"(x)); return r;
}
__device__ __forceinline__ float log2i(float x) {
    float r; asm("v_log_f32 %0, %1" : "=v"(r) : "v"(x)); return r;
}

// tanh-gelu in sigmoid form: 0.5x(1+tanh(u)) == x*sigmoid(2u) == x/(1+exp2(-2u*log2e))
__device__ __forceinline__ float gelu_tanh(float x) {
    float u = 0.7978845608028654f * (x + 0.044715f * x * x * x);
    float t = exp2i(-2.8853900817779268f * u);
    return x / (1.0f + t);
}

__device__ __forceinline__ f32x4 mfma16(u32x4 a, u32x4 b, f32x4 c) {
    return __builtin_amdgcn_mfma_f32_16x16x32_bf16(
        __builtin_bit_cast(bf16x8, a), __builtin_bit_cast(bf16x8, b), c, 0, 0, 0);
}

__device__ __forceinline__ void gload_lds16(const ushortT* g, ushortT* l) {
    __builtin_amdgcn_global_load_lds(
        (const __attribute__((address_space(1))) unsigned int*)g,
        (__attribute__((address_space(3))) unsigned int*)l,
        16, 0, 0);
}

// ---------------- bf16 MFMA GEMM, 3-buffer counted-vmcnt pipeline ----------------
// C[m,n] = epi( sum_k A[m,k]*Bt[n,k] + bias[n] )
// K-loop (T3/T4 minimal form): 3 LDS buffers; per iter t:
//   { vmcnt(WM+WN); s_barrier; ds_read buf[t%3]; stage tile t+2; MFMA }.
// FIFO invariant: each wave's stage() issues exactly WM+WN loads, so
// vmcnt(WM+WN) permits ONE group (tile t+1) outstanding and certifies tile t
// landed; the barrier publishes all waves' tile-t writes. Tail iters
// re-stage the last tile into the dead buffer keeping the count exact.
// 64x64 wave tile: 144 unified regs/wave -> 3 waves/SIMD (the wide 64x128
// variant hit 280 regs -> 1 wave/SIMD and regressed 72->98 us; R13).
// LDS rows are 64B; bank-conflict fix (T2, both-sides): 16B slot XOR-swizzled
// with (row>>1)&3 on the GLOBAL source chunk and the ds_read.
// MODE: 0 = bf16 + bias | 1 = bf16 + bias + gelu | 4 = bf16, no bias
//       | 5 = fused-QKV routing (Cv = q base; k at +TOKENS*H; v^T at +2*TOKENS*H)
//       | 6 = fused mask+row-softmax (WM==1,WN==4, BN==256==S spans full rows;
//             `bias` carries the int mask pointer; ob indexes batch)
// 2D grids (gridDim.z==1) get the XCD-aware block swizzle (T1); grids are %8==0.
template<int WM, int WN, int MODE>
__global__ __launch_bounds__(256) void gemm_mfma(
    const ushortT* __restrict__ A, int lda, long long sAo, long long sAi,
    const ushortT* __restrict__ Bt, int ldb, long long sBo, long long sBi,
    const float* __restrict__ bias,
    void* __restrict__ Cv, int ldc, long long sCo, long long sCi,
    int K, int innerN)
{
    constexpr int BM = WM * 64, BN = WN * 64;
    __shared__ __align__(16) ushortT As[3][BM * 32];
    __shared__ __align__(16) ushortT Bs[3][BN * 32];
    const int tid = threadIdx.x;
    const int wave = tid >> 6, lane = tid & 63;
    const int ob = blockIdx.z / innerN, ib = blockIdx.z - ob * innerN;

    int bxi = blockIdx.x, byi = blockIdx.y;
    if (gridDim.z == 1) {
        const int nwg = gridDim.x * gridDim.y;
        const int lin = byi * gridDim.x + bxi;
        const int cpx = nwg >> 3;
        const int sw = (lin & 7) * cpx + (lin >> 3);
        byi = sw / gridDim.x; bxi = sw - byi * gridDim.x;
    }
    const int bm = byi * BM, bn = bxi * BN;
    const ushortT* Ab = A + ob * sAo + ib * sAi + (size_t)bm * lda;
    const ushortT* Bb = Bt + ob * sBo + ib * sBi + (size_t)bn * ldb;
    const int wm = wave / WN, wn = wave - wm * WN;

    const int lrow = lane >> 2;                             // row within 16-row chunk
    const int lsw16 = ((lane & 3) ^ ((lrow >> 1) & 3)) * 8; // swizzled SRC chunk (elems)
    const int rl = lane & 15;
    const int kg4 = (lane >> 4) << 2;
    const int ksw = ((lane >> 4) ^ ((rl >> 1) & 3)) << 3;   // swizzled LDS read (elems)

    f32x4 acc[4][4];
#pragma unroll
    for (int i = 0; i < 4; ++i)
#pragma unroll
        for (int j = 0; j < 4; ++j) acc[i][j] = (f32x4){0.f, 0.f, 0.f, 0.f};

    auto stage = [&](int buf, int k0) {
#pragma unroll
        for (int j = 0; j < WM; ++j) {
            int chunk = j * 4 + wave;
            gload_lds16(Ab + (size_t)(chunk * 16 + lrow) * lda + k0 + lsw16,
                        &As[buf][chunk * 512]);
        }
#pragma unroll
        for (int j = 0; j < WN; ++j) {
            int chunk = j * 4 + wave;
            gload_lds16(Bb + (size_t)(chunk * 16 + lrow) * ldb + k0 + lsw16,
                        &Bs[buf][chunk * 512]);
        }
    };

    const int nt = K >> 5;
    stage(0, 0);
    stage(1, ((nt > 1) ? 1 : 0) << 5);
    int cur = 0;
    for (int t = 0; t < nt; ++t) {
        if constexpr (WM + WN == 4)
            asm volatile("s_waitcnt vmcnt(4)" ::: "memory");
        else
            asm volatile("s_waitcnt vmcnt(5)" ::: "memory");
        __builtin_amdgcn_s_barrier();
        __builtin_amdgcn_sched_barrier(0);
        u32x4 a[4], b[4];
#pragma unroll
        for (int mf = 0; mf < 4; ++mf)
            a[mf] = *(const u32x4*)&As[cur][(wm * 64 + mf * 16 + rl) * 32 + ksw];
#pragma unroll
        for (int nf = 0; nf < 4; ++nf)
            b[nf] = *(const u32x4*)&Bs[cur][(wn * 64 + nf * 16 + rl) * 32 + ksw];
        {
            const int nx = (t + 2 < nt) ? t + 2 : nt - 1;
            int nb = cur + 2; if (nb >= 3) nb -= 3;
            stage(nb, nx << 5);
        }
#pragma unroll
        for (int mf = 0; mf < 4; ++mf)
#pragma unroll
            for (int nf = 0; nf < 4; ++nf)
                acc[mf][nf] = mfma16(a[mf], b[nf], acc[mf][nf]);
        cur = (cur + 1 == 3) ? 0 : cur + 1;
    }
    asm volatile("s_waitcnt vmcnt(0)" ::: "memory");

    ushortT* Ch = (ushortT*)Cv + ob * sCo + ib * sCi;
    if constexpr (MODE == 6) {
        __shared__ float red6[2][4][64];
        const int* mrow = (const int*)bias + ob * S;
        float mb[4];
#pragma unroll
        for (int nf = 0; nf < 4; ++nf)
            mb[nf] = mrow[bn + wn * 64 + nf * 16 + rl] ? 0.f : -8e9f;
        float pm[4][4];
#pragma unroll
        for (int mf = 0; mf < 4; ++mf)
#pragma unroll
            for (int r = 0; r < 4; ++r) pm[mf][r] = -1e30f;
#pragma unroll
        for (int mf = 0; mf < 4; ++mf)
#pragma unroll
            for (int nf = 0; nf < 4; ++nf)
#pragma unroll
                for (int r = 0; r < 4; ++r) {
                    acc[mf][nf][r] += mb[nf];
                    pm[mf][r] = fmaxf(pm[mf][r], acc[mf][nf][r]);
                }
#pragma unroll
        for (int mf = 0; mf < 4; ++mf)
#pragma unroll
            for (int r = 0; r < 4; ++r) {
                float v = pm[mf][r];
                v = fmaxf(v, __shfl_xor(v, 1));
                v = fmaxf(v, __shfl_xor(v, 2));
                v = fmaxf(v, __shfl_xor(v, 4));
                v = fmaxf(v, __shfl_xor(v, 8));
                pm[mf][r] = v;
            }
        if (rl == 0) {
#pragma unroll
            for (int mf = 0; mf < 4; ++mf)
#pragma unroll
                for (int r = 0; r < 4; ++r)
                    red6[0][wn][mf * 16 + kg4 + r] = pm[mf][r];
        }
        __syncthreads();
        float Mx[4][4];
#pragma unroll
        for (int mf = 0; mf < 4; ++mf)
#pragma unroll
            for (int r = 0; r < 4; ++r) {
                const int row = mf * 16 + kg4 + r;
                Mx[mf][r] = fmaxf(fmaxf(red6[0][0][row], red6[0][1][row]),
                                  fmaxf(red6[0][2][row], red6[0][3][row]));
            }
        float ps[4][4];
#pragma unroll
        for (int mf = 0; mf < 4; ++mf)
#pragma unroll
            for (int r = 0; r < 4; ++r) ps[mf][r] = 0.f;
#pragma unroll
        for (int mf = 0; mf < 4; ++mf)
#pragma unroll
            for (int nf = 0; nf < 4; ++nf)
#pragma unroll
                for (int r = 0; r < 4; ++r) {
                    float e = exp2i(C2 * (acc[mf][nf][r] - Mx[mf][r]));
                    acc[mf][nf][r] = e;
                    ps[mf][r] += e;
                }
#pragma unroll
        for (int mf = 0; mf < 4; ++mf)
#pragma unroll
            for (int r = 0; r < 4; ++r) {
                float v = ps[mf][r];
                v += __shfl_xor(v, 1);
                v += __shfl_xor(v, 2);
                v += __shfl_xor(v, 4);
                v += __shfl_xor(v, 8);
                ps[mf][r] = v;
            }
        if (rl == 0) {
#pragma unroll
            for (int mf = 0; mf < 4; ++mf)
#pragma unroll
                for (int r = 0; r < 4; ++r)
                    red6[1][wn][mf * 16 + kg4 + r] = ps[mf][r];
        }
        __syncthreads();
#pragma unroll
        for (int mf = 0; mf < 4; ++mf) {
            float inv[4];
#pragma unroll
            for (int r = 0; r < 4; ++r) {
                const int row = mf * 16 + kg4 + r;
                inv[r] = 1.0f / (red6[1][0][row] + red6[1][1][row] +
                                 red6[1][2][row] + red6[1][3][row]);
            }
#pragma unroll
            for (int nf = 0; nf < 4; ++nf) {
                const int gn = bn + wn * 64 + nf * 16 + rl;
                const int gm = bm + mf * 16 + kg4;
#pragma unroll
                for (int r = 0; r < 4; ++r)
                    Ch[(size_t)(gm + r) * ldc + gn] = f2bf(acc[mf][nf][r] * inv[r]);
            }
        }
    } else {
#pragma unroll
        for (int nf = 0; nf < 4; ++nf) {
            int gn = bn + wn * 64 + nf * 16 + rl;
            float bv = 0.f;
            if constexpr (MODE != 4) bv = bias[gn];
#pragma unroll
            for (int mf = 0; mf < 4; ++mf) {
                int gm = bm + wm * 64 + mf * 16 + kg4;
                if constexpr (MODE == 5) {
                    const int region = gn / H;          // 0=q,1=k,2=v
                    const int col = gn - region * H;
                    if (region < 2) {
                        ushortT* o = (ushortT*)Cv + (size_t)region * TOKENS * H;
#pragma unroll
                        for (int r = 0; r < 4; ++r)
                            o[(size_t)(gm + r) * H + col] = f2bf(acc[mf][nf][r] + bv);
                    } else {
                        u16x4 o;
#pragma unroll
                        for (int r = 0; r < 4; ++r) o[r] = f2bf(acc[mf][nf][r] + bv);
                        const int b_ = gm >> 8, s0 = gm & 255;
                        const int h_ = col >> 6, dh = col & 63;
                        *(u16x4*)((ushortT*)Cv + 2 * (size_t)TOKENS * H +
                                  (((size_t)(b_ * NHD + h_) * DH + dh) << 8) + s0) = o;
                    }
                } else {
#pragma unroll
                    for (int r = 0; r < 4; ++r) {
                        float x = acc[mf][nf][r] + bv;
                        if constexpr (MODE == 1) x = gelu_tanh(x);
                        Ch[(size_t)(gm + r) * ldc + gn] = f2bf(x);
                    }
                }
            }
        }
    }
}

// ---------------- all 6 weight transposes of one layer, one dispatch ----------------
__global__ __launch_bounds__(256) void transpose_all_k(
    const float* __restrict__ Wq, const float* __restrict__ Wk,
    const float* __restrict__ Wv, const float* __restrict__ Wo,
    const float* __restrict__ W1, const float* __restrict__ W2,
    ushortT* __restrict__ wtqkv, ushortT* __restrict__ wto,
    ushortT* __restrict__ wt1, ushortT* __restrict__ wt2)
{
    int idx = blockIdx.x;
    const float* W; ushortT* WT; int R, C, tr, tc;
    if (idx < 2304) {
        int mat = idx / 576, t = idx - mat * 576;
        tr = t / 24; tc = t - tr * 24; R = 768; C = 768;
        W = mat == 0 ? Wq : mat == 1 ? Wk : mat == 2 ? Wv : Wo;
        WT = mat < 3 ? wtqkv + (size_t)mat * 768 * 768 : wto;
    } else if (idx < 4608) {
        int t = idx - 2304; tr = t / 96; tc = t - tr * 96;
        R = 768; C = 3072; W = W1; WT = wt1;
    } else {
        int t = idx - 4608; tr = t / 24; tc = t - tr * 24;
        R = 3072; C = 768; W = W2; WT = wt2;
    }
    int r0 = tr * 32, c0 = tc * 32;
    __shared__ float tl[32][33];
    int trd = threadIdx.x >> 3;
    int tc4 = (threadIdx.x & 7) * 4;
    const float4 v = *(const float4*)(W + (size_t)(r0 + trd) * C + c0 + tc4);
    tl[trd][tc4 + 0] = v.x; tl[trd][tc4 + 1] = v.y;
    tl[trd][tc4 + 2] = v.z; tl[trd][tc4 + 3] = v.w;
    __syncthreads();
    u16x4 o;
#pragma unroll
    for (int q = 0; q < 4; ++q) o[q] = f2bf(tl[tc4 + q][trd]);
    *(u16x4*)(WT + (size_t)(c0 + trd) * R + r0 + tc4) = o;
}

// ---------------- pack qkv biases -> [NLAY][2304] ----------------
__global__ __launch_bounds__(256) void pack_bias_k(
    const float* __restrict__ bq, const float* __restrict__ bk,
    const float* __restrict__ bv, float* __restrict__ out)
{
    int l = blockIdx.x / 3, r = blockIdx.x - (blockIdx.x / 3) * 3;
    const float* src = r == 0 ? bq : r == 1 ? bk : bv;
#pragma unroll
    for (int j = 0; j < 3; ++j) {
        int d = threadIdx.x + 256 * j;
        out[(size_t)l * QKVN + r * H + d] = src[(size_t)l * H + d];
    }
}

// ---------------- embeddings + LN -> bf16 h; 4 tokens/block, 1 wave/token ----------------
__global__ __launch_bounds__(256) void embed_ln_k(
    const int* __restrict__ ids, const int* __restrict__ tts,
    const float* __restrict__ wemb, const float* __restrict__ pemb,
    const float* __restrict__ temb, const float* __restrict__ g,
    const float* __restrict__ bp, ushortT* __restrict__ hb)
{
    const int tok = blockIdx.x * 4 + (threadIdx.x >> 6);
    const int lane = threadIdx.x & 63;
    const int d0 = lane * 12;
    const int spos = tok & (S - 1);
    const int id = ids[tok], tt = tts[tok];
    const float* wr = wemb + (size_t)id * H + d0;
    const float* pr = pemb + (size_t)spos * H + d0;
    const float* tr = temb + (size_t)tt * H + d0;
    float x[12]; float s = 0.f, ss = 0.f;
#pragma unroll
    for (int j = 0; j < 3; ++j) {
        float4 a = *(const float4*)(wr + j * 4);
        float4 b = *(const float4*)(pr + j * 4);
        float4 c = *(const float4*)(tr + j * 4);
        float v0 = a.x + b.x + c.x, v1 = a.y + b.y + c.y;
        float v2 = a.z + b.z + c.z, v3 = a.w + b.w + c.w;
        x[j*4+0] = v0; x[j*4+1] = v1; x[j*4+2] = v2; x[j*4+3] = v3;
        s += v0 + v1 + v2 + v3;
        ss += v0*v0 + v1*v1 + v2*v2 + v3*v3;
    }
#pragma unroll
    for (int m = 32; m; m >>= 1) { s += __shfl_xor(s, m); ss += __shfl_xor(ss, m); }
    float mu = s * (1.f / H);
    float var = ss * (1.f / H) - mu * mu;
    float rs = rsqrtf(var + 1e-12f);
#pragma unroll
    for (int j = 0; j < 3; ++j) {
        float4 gv = *(const float4*)(g + d0 + j * 4);
        float4 bv = *(const float4*)(bp + d0 + j * 4);
        u16x4 o;
        o[0] = f2bf((x[j*4+0] - mu) * rs * gv.x + bv.x);
        o[1] = f2bf((x[j*4+1] - mu) * rs * gv.y + bv.y);
        o[2] = f2bf((x[j*4+2] - mu) * rs * gv.z + bv.z);
        o[3] = f2bf((x[j*4+3] - mu) * rs * gv.w + bv.w);
        *(u16x4*)(hb + (size_t)tok * H + d0 + j * 4) = o;
    }
}

// ---------------- bf16 residual add + LN, in place on hb; 4 tokens/block ----------------
__global__ __launch_bounds__(256) void add_ln_k(
    ushortT* __restrict__ hb, const ushortT* __restrict__ add,
    const float* __restrict__ g, const float* __restrict__ bp)
{
    const int tok = blockIdx.x * 4 + (threadIdx.x >> 6);
    const int lane = threadIdx.x & 63;
    const int d0 = lane * 12;
    const size_t base = (size_t)tok * H + d0;
    float x[12]; float s = 0.f, ss = 0.f;
#pragma unroll
    for (int j = 0; j < 3; ++j) {
        u16x4 hv = *(const u16x4*)(hb + base + j * 4);
        u16x4 av = *(const u16x4*)(add + base + j * 4);
#pragma unroll
        for (int q = 0; q < 4; ++q) {
            float v = bf2f(hv[q]) + bf2f(av[q]);
            x[j*4+q] = v; s += v; ss += v * v;
        }
    }
#pragma unroll
    for (int m = 32; m; m >>= 1) { s += __shfl_xor(s, m); ss += __shfl_xor(ss, m); }
    float mu = s * (1.f / H);
    float var = ss * (1.f / H) - mu * mu;
    float rs = rsqrtf(var + 1e-12f);
#pragma unroll
    for (int j = 0; j < 3; ++j) {
        float4 gv = *(const float4*)(g + d0 + j * 4);
        float4 bv = *(const float4*)(bp + d0 + j * 4);
        u16x4 o;
        o[0] = f2bf((x[j*4+0] - mu) * rs * gv.x + bv.x);
        o[1] = f2bf((x[j*4+1] - mu) * rs * gv.y + bv.y);
        o[2] = f2bf((x[j*4+2] - mu) * rs * gv.z + bv.z);
        o[3] = f2bf((x[j*4+3] - mu) * rs * gv.w + bv.w);
        *(u16x4*)(hb + base + j * 4) = o;
    }
}

// ---------------- logits + log_softmax over 9 labels (bf16 h, f32 math) ----------------
__global__ __launch_bounds__(256) void logits_k(
    const ushortT* __restrict__ hb, const float* __restrict__ fcw,
    float* __restrict__ em)
{
    int tok = blockIdx.x, tid = threadIdx.x;
    float p[LBL];
#pragma unroll
    for (int l = 0; l < LBL; ++l) p[l] = 0.f;
    const ushortT* hr = hb + (size_t)tok * H;
#pragma unroll
    for (int j = 0; j < 3; ++j) {
        int d = tid + 256 * j;
        float hv = bf2f(hr[d]);
        const float* fr = fcw + (size_t)d * LBL;
#pragma unroll
        for (int l = 0; l < LBL; ++l) p[l] = fmaf(hv, fr[l], p[l]);
    }
    __shared__ float ls[4][LBL];
    __shared__ float lg[LBL];
    __shared__ float lse;
#pragma unroll
    for (int l = 0; l < LBL; ++l) {
        float v = p[l];
#pragma unroll
        for (int m = 32; m; m >>= 1) v += __shfl_xor(v, m);
        if ((tid & 63) == 0) ls[tid >> 6][l] = v;
    }
    __syncthreads();
    if (tid < LBL) lg[tid] = ls[0][tid] + ls[1][tid] + ls[2][tid] + ls[3][tid];
    __syncthreads();
    if (tid == 0) {
        float mx = lg[0];
#pragma unroll
        for (int j = 1; j < LBL; ++j) mx = fmaxf(mx, lg[j]);
        float sm = 0.f;
#pragma unroll
        for (int j = 0; j < LBL; ++j) sm += expf(lg[j] - mx);
        lse = mx + logf(sm);
    }
    __syncthreads();
    if (tid < LBL) em[(size_t)tok * LBL + tid] = lg[tid] - lse;
}

// ---------------- CRF: one wave per batch elem, base-2 fast recursion ----------------
__global__ __launch_bounds__(64) void crf_k(
    const float* __restrict__ em, const int* __restrict__ tags,
    const int* __restrict__ mask, const float* __restrict__ sp,
    const float* __restrict__ ep, const float* __restrict__ trans,
    float* __restrict__ partial)
{
    constexpr float LOG2E = 1.4426950408889634f;
    constexpr float LN2   = 0.6931471805599453f;
    int b = blockIdx.x, t = threadIdx.x;
    __shared__ float eml[S * LBL];     // emissions * log2(e)
    __shared__ int mkl[S];
    const float* emb = em + (size_t)b * S * LBL;
    const int* tg = tags + (size_t)b * S;
    const int* mk = mask + (size_t)b * S;

    for (int i = t * 4; i < S * LBL; i += 256) {
        float4 v = *(const float4*)&emb[i];
        v.x *= LOG2E; v.y *= LOG2E; v.z *= LOG2E; v.w *= LOG2E;
        *(float4*)&eml[i] = v;
    }
    *(i32x4*)&mkl[t * 4] = *(const i32x4*)&mk[t * 4];

    int cnt = 0; float ns = 0.f;
    for (int i = t; i < S; i += 64) {
        int m = mk[i];
        cnt += (m != 0);
        if (i >= 1 && m)
            ns += trans[tg[i - 1] * LBL + tg[i]] + emb[(size_t)i * LBL + tg[i]];
    }
#pragma unroll
    for (int m = 32; m; m >>= 1) { cnt += __shfl_xor(cnt, m); ns += __shfl_xor(ns, m); }
    float num = ns + sp[tg[0]] + emb[tg[0]] + ep[tg[cnt - 1]];

    int tt = t < LBL ? t : 0;
    float trc2[LBL];
#pragma unroll
    for (int i = 0; i < LBL; ++i) trc2[i] = trans[i * LBL + tt] * LOG2E;

    __syncthreads();

    float alpha2 = (t < LBL) ? sp[t] * LOG2E + eml[t] : -1e30f;
    for (int step = 1; step < S; ++step) {
        float av[LBL];
#pragma unroll
        for (int i = 0; i < LBL; ++i) av[i] = __shfl(alpha2, i) + trc2[i];
        float mx = av[0];
#pragma unroll
        for (int i = 1; i < LBL; ++i) mx = fmaxf(mx, av[i]);
        float sm = 0.f;
#pragma unroll
        for (int i = 0; i < LBL; ++i) sm += exp2i(av[i] - mx);
        float na = mx + log2i(sm) + eml[step * LBL + tt];
        alpha2 = (mkl[step] && t < LBL) ? na : alpha2;
    }
    float z = (t < LBL) ? alpha2 + ep[t] * LOG2E : -1e30f;
    float mx = z;
#pragma unroll
    for (int m = 8; m; m >>= 1) mx = fmaxf(mx, __shfl_xor(mx, m));
    float sm = exp2i(z - mx);
#pragma unroll
    for (int m = 8; m; m >>= 1) sm += __shfl_xor(sm, m);
    if (t == 0) partial[b] = (mx + log2i(sm)) * LN2 - num;
}

__global__ void finalize_k(const float* __restrict__ partial, float* __restrict__ out) {
    float s = 0.f;
    for (int i = 0; i < BATCH; ++i) s += partial[i];
    out[0] = s;
}

__global__ void sentinel_k(float* out) { out[0] = -12345.0f; }

extern "C" void kernel_launch(void* const* d_in, const int* in_sizes, int n_in,
                              void* d_out, int out_size, void* d_ws, size_t ws_size,
                              hipStream_t stream) {
    (void)in_sizes; (void)n_in; (void)out_size;
    const int* token_ids  = (const int*)d_in[0];
    const int* token_type = (const int*)d_in[1];
    const int* amask      = (const int*)d_in[2];
    const int* y          = (const int*)d_in[3];
    const float* wemb = (const float*)d_in[4];
    const float* pemb = (const float*)d_in[5];
    const float* temb = (const float*)d_in[6];
    const float* eg   = (const float*)d_in[7];
    const float* eb   = (const float*)d_in[8];
    const float* Wq = (const float*)d_in[9];
    const float* bq = (const float*)d_in[10];
    const float* Wk = (const float*)d_in[11];
    const float* bk = (const float*)d_in[12];
    const float* Wv = (const float*)d_in[13];
    const float* bv = (const float*)d_in[14];
    const float* Wo = (const float*)d_in[15];
    const float* bo = (const float*)d_in[16];
    const float* ln1g = (const float*)d_in[17];
    const float* ln1b = (const float*)d_in[18];
    const float* W1 = (const float*)d_in[19];
    const float* b1 = (const float*)d_in[20];
    const float* W2 = (const float*)d_in[21];
    const float* b2 = (const float*)d_in[22];
    const float* ln2g = (const float*)d_in[23];
    const float* ln2b = (const float*)d_in[24];
    const float* fcw = (const float*)d_in[25];
    const float* crf_s = (const float*)d_in[26];
    const float* crf_e = (const float*)d_in[27];
    const float* crf_t = (const float*)d_in[28];

    if (ws_size < WS_FLOATS * sizeof(float)) {
        sentinel_k<<<1, 1, 0, stream>>>((float*)d_out);
        return;
    }

    float* ws = (float*)d_ws;
    ushortT* hb   = (ushortT*)(ws + HB_OFF);
    ushortT* qb   = (ushortT*)(ws + QB_OFF);   // q base; k = +TOKENS*H; vt = +2*TOKENS*H
    ushortT* kb   = (ushortT*)(ws + KB_OFF);
    ushortT* vt   = (ushortT*)(ws + VT_OFF);
    ushortT* big  = (ushortT*)(ws + BIG_OFF);
    ushortT* wtq  = (ushortT*)(ws + WTQ_OFF);  // [2304][768]
    ushortT* wto  = (ushortT*)(ws + WTO_OFF);
    ushortT* wt1  = (ushortT*)(ws + WT1_OFF);
    ushortT* wt2  = (ushortT*)(ws + WT2_OFF);
    float*   embuf = ws + EM_OFF;
    float*   part  = ws + PART_OFF;
    float*   bqkv  = ws + BQKV_OFF;

    pack_bias_k<<<NLAY * 3, 256, 0, stream>>>(bq, bk, bv, bqkv);
    embed_ln_k<<<TOKENS / 4, 256, 0, stream>>>(token_ids, token_type, wemb, pemb,
                                               temb, eg, eb, hb);

    constexpr long long HH = (long long)H * H;
    constexpr long long HF = (long long)H * FF;
    constexpr long long TOKH = (long long)S * H;        // 196608
    constexpr long long ATT_B = (long long)NHD * S * S; // 786432
    constexpr long long ATT_H = (long long)S * S;       // 65536
    constexpr long long VT_B = (long long)NHD * DH * S; // 196608
    constexpr long long VT_H = (long long)DH * S;       // 16384

    dim3 gQKV(QKVN / 128, TOKENS / 128, 1);       // 18 x 64 = 1152 (%8==0)
    dim3 gProj(H / 128, TOKENS / 128, 1);         // 6 x 64 = 384
    dim3 gFF1(FF / 128, TOKENS / 128, 1);         // 24 x 64 = 1536
    dim3 gScores(1, S / 64, BATCH * NHD);         // (N/256, M/64, 384) = 1x4x384
    dim3 gPV(1, 1, BATCH * NHD);                  // 256x64 tile covers head

    for (int l = 0; l < NLAY; ++l) {
        transpose_all_k<<<6912, 256, 0, stream>>>(
            Wq + l * HH, Wk + l * HH, Wv + l * HH, Wo + l * HH,
            W1 + l * HF, W2 + l * HF, wtq, wto, wt1, wt2);

        // fused q,k,v projections (3-buffer pipelined 128^2 with routing epilogue)
        gemm_mfma<2,2,5><<<gQKV, 256, 0, stream>>>(
            hb, H, 0, 0, wtq, H, 0, 0, bqkv + (size_t)l * QKVN,
            qb, H, 0, 0, H, 1);

        // probs = softmax(mask(q @ k^T)) per (b,h), fused epilogue -> bf16
        gemm_mfma<1,4,6><<<gScores, 256, 0, stream>>>(
            qb, H, TOKH, DH, kb, H, TOKH, DH, (const float*)amask,
            big, S, ATT_B, ATT_H, DH, NHD);

        // ctx = probs @ v  (per b,h) -> qb as [B,S,NH,DH] bf16
        gemm_mfma<4,1,4><<<gPV, 256, 0, stream>>>(
            big, S, ATT_B, ATT_H, vt, S, VT_B, VT_H, nullptr,
            qb, H, TOKH, DH, S, NHD);

        // attention output projection -> kb (bf16)
        gemm_mfma<2,2,0><<<gProj, 256, 0, stream>>>(
            qb, H, 0, 0, wto, H, 0, 0, bo + l * H, kb, H, 0, 0, H, 1);

        add_ln_k<<<TOKENS / 4, 256, 0, stream>>>(hb, kb, ln1g + l * H, ln1b + l * H);

        // ff1 = gelu(h @ W1 + b1) -> big bf16
        gemm_mfma<2,2,1><<<gFF1, 256, 0, stream>>>(
            hb, H, 0, 0, wt1, H, 0, 0, b1 + (long long)l * FF, big, FF, 0, 0, H, 1);

        // ff2 -> qb (bf16)
        gemm_mfma<2,2,0><<<gProj, 256, 0, stream>>>(
            big, FF, 0, 0, wt2, FF, 0, 0, b2 + l * H, qb, H, 0, 0, FF, 1);

        add_ln_k<<<TOKENS / 4, 256, 0, stream>>>(hb, qb, ln2g + l * H, ln2b + l * H);
    }

    logits_k<<<TOKENS, 256, 0, stream>>>(hb, fcw, embuf);
    crf_k<<<BATCH, 64, 0, stream>>>(embuf, y, amask, crf_s, crf_e, crf_t, part);
    finalize_k<<<1, 1, 0, stream>>>(part, (float*)d_out);
}

// Round 15
// 2766.933 us; speedup vs baseline: 1.5555x; 1.1118x over previous
//
#include <hip/hip_runtime.h>
#include <math.h>

typedef unsigned short ushortT;
typedef unsigned char u8;
typedef __attribute__((ext_vector_type(4))) float f32x4;
typedef __attribute__((ext_vector_type(4))) unsigned int u32x4;
typedef __attribute__((ext_vector_type(4))) unsigned short u16x4;
typedef __attribute__((ext_vector_type(4))) int i32x4;
typedef __attribute__((ext_vector_type(8))) __bf16 bf16x8;

namespace {
constexpr int S = 256;
constexpr int H = 768;
constexpr int NLAY = 12;
constexpr int NHD = 12;
constexpr int FF = 3072;
constexpr int LBL = 9;
constexpr int DH = 64;
constexpr int BATCH = 32;
constexpr int TOKENS = BATCH * S;      // 8192
constexpr int QKVN = 3 * H;            // 2304
// softmax scale folded into exponent: p = exp2(C2*(s_raw - m_raw)), C2 = 0.125*log2(e)
constexpr float C2 = 0.18033688011112042f;

// workspace layout (float-slot units)
constexpr size_t HB_OFF  = 0;                            // h bf16 (half slots)
constexpr size_t QB_OFF  = HB_OFF + (size_t)TOKENS*H/2;  // q / ctx / ff2out bf16
constexpr size_t KB_OFF  = QB_OFF + (size_t)TOKENS*H/2;  // k / attn-out bf16
constexpr size_t VT_OFF  = KB_OFF + (size_t)TOKENS*H/2;  // v^T bf16 [B*NH*DH][S]
constexpr size_t BIG_OFF = VT_OFF + (size_t)TOKENS*H/2;  // probs bf16 == ff1 fp8
constexpr size_t WTQ_OFF = BIG_OFF + (size_t)TOKENS*FF/2;  // Wq^T,Wk^T,Wv^T bf16
constexpr size_t WTO_OFF = WTQ_OFF + 3*(size_t)H*H/2;
constexpr size_t WT1_OFF = WTO_OFF + (size_t)H*H/2;      // W1^T fp8 [3072][768]
constexpr size_t WT2_OFF = WT1_OFF + (size_t)H*FF/2;     // W2^T fp8 [768][3072]
constexpr size_t EM_OFF  = WT2_OFF + (size_t)H*FF/2;
constexpr size_t PART_OFF= EM_OFF + (size_t)TOKENS*LBL;
constexpr size_t BQKV_OFF= PART_OFF + 64;                // packed qkv bias [12][2304]
constexpr size_t H8_OFF  = BQKV_OFF + (size_t)NLAY*QKVN; // h fp8 copy [8192][768]
constexpr size_t WS_FLOATS = H8_OFF + (size_t)TOKENS*H/4;
}

__device__ __forceinline__ ushortT f2bf(float x) {
    unsigned u = __builtin_bit_cast(unsigned, x);
    u += 0x7fffu + ((u >> 16) & 1u);
    return (ushortT)(u >> 16);
}
__device__ __forceinline__ float bf2f(ushortT h) {
    unsigned u = ((unsigned)h) << 16;
    return __builtin_bit_cast(float, u);
}
__device__ __forceinline__ u8 f2fp8(float x) {
    return (u8)(__builtin_amdgcn_cvt_pk_fp8_f32(x, x, 0, false) & 0xff);
}
__device__ __forceinline__ unsigned f2fp8x4(float a, float b, float c, float d) {
    int p = __builtin_amdgcn_cvt_pk_fp8_f32(a, b, 0, false);
    p = __builtin_amdgcn_cvt_pk_fp8_f32(c, d, p, true);
    return (unsigned)p;
}

__device__ __forceinline__ float exp2i(float x) {
    float r; asm("v_exp_f32 %0, %1" : "=v"(r) : "v"(x)); return r;
}
__device__ __forceinline__ float log2i(float x) {
    float r; asm("v_log_f32 %0, %1" : "=v"(r) : "v"(x)); return r;
}

// tanh-gelu in sigmoid form: 0.5x(1+tanh(u)) == x*sigmoid(2u) == x/(1+exp2(-2u*log2e))
__device__ __forceinline__ float gelu_tanh(float x) {
    float u = 0.7978845608028654f * (x + 0.044715f * x * x * x);
    float t = exp2i(-2.8853900817779268f * u);
    return x / (1.0f + t);
}

__device__ __forceinline__ f32x4 mfma16(u32x4 a, u32x4 b, f32x4 c) {
    return __builtin_amdgcn_mfma_f32_16x16x32_bf16(
        __builtin_bit_cast(bf16x8, a), __builtin_bit_cast(bf16x8, b), c, 0, 0, 0);
}

__device__ __forceinline__ void gload_lds16(const ushortT* g, ushortT* l) {
    __builtin_amdgcn_global_load_lds(
        (const __attribute__((address_space(1))) unsigned int*)g,
        (__attribute__((address_space(3))) unsigned int*)l,
        16, 0, 0);
}
__device__ __forceinline__ void gload_lds16b(const u8* g, u8* l) {
    __builtin_amdgcn_global_load_lds(
        (const __attribute__((address_space(1))) unsigned int*)g,
        (__attribute__((address_space(3))) unsigned int*)l,
        16, 0, 0);
}

// =====================================================================
// FP8 e4m3 MFMA GEMM (FFN only): BM=BN=128, 4 waves, wave 64x64, K-step 64.
// LDS rows are 64 B (64 fp8) — identical geometry to the bf16 kernel, so the
// verified (row>>1)&3 16B-chunk both-sides swizzle carries over. Fragment
// reads are ds_read_b64 (8 fp8/lane); bank landing is 2-way = free (m136).
// Halves LDS bytes per FLOP vs bf16 (the measured binding resource) at the
// same MFMA rate (non-scaled fp8 = bf16 rate, m11). 3-buffer counted-vmcnt
// pipeline; stage group = 4 loads/thread -> vmcnt(4); 32 MFMAs/iter.
// MODE: 7 = bias+gelu -> fp8 out (FF1) | 8 = bias -> bf16 out (FF2)
// =====================================================================
template<int MODE>
__global__ __launch_bounds__(256) void gemm_fp8(
    const u8* __restrict__ A, int lda,
    const u8* __restrict__ Bt, int ldb,
    const float* __restrict__ bias,
    void* __restrict__ Cv, int ldc, int K)
{
    __shared__ __align__(16) u8 As[3][128 * 64];   // 8 KB each
    __shared__ __align__(16) u8 Bs[3][128 * 64];
    const int tid = threadIdx.x;
    const int wave = tid >> 6, lane = tid & 63;

    int bxi = blockIdx.x, byi = blockIdx.y;
    {
        const int nwg = gridDim.x * gridDim.y;
        const int lin = byi * gridDim.x + bxi;
        const int cpx = nwg >> 3;
        const int sw = (lin & 7) * cpx + (lin >> 3);
        byi = sw / gridDim.x; bxi = sw - byi * gridDim.x;
    }
    const int bm = byi * 128, bn = bxi * 128;
    const u8* Ab = A + (size_t)bm * lda;
    const u8* Bb = Bt + (size_t)bn * ldb;
    const int wm = wave >> 1, wn = wave & 1;

    const int lrow = lane >> 2;                              // row within 16-row chunk
    const int lswb = ((lane & 3) ^ ((lrow >> 1) & 3)) * 16;  // swizzled SRC byte off
    const int rl = lane & 15;
    const int kg = lane >> 4;                                // 0..3
    const int kg4 = kg << 2;
    const int key = (rl >> 1) & 3;                           // read-side swizzle key
    const int kgh = kg >> 1, kgl8 = (kg & 1) * 8;

    f32x4 acc[4][4];
#pragma unroll
    for (int i = 0; i < 4; ++i)
#pragma unroll
        for (int j = 0; j < 4; ++j) acc[i][j] = (f32x4){0.f, 0.f, 0.f, 0.f};

    auto stage = [&](int buf, int kt) {
#pragma unroll
        for (int j = 0; j < 2; ++j) {
            int chunk = j * 4 + wave;        // 8 chunks x 16 rows = 128 rows
            gload_lds16b(Ab + (size_t)(chunk * 16 + lrow) * lda + kt * 64 + lswb,
                         &As[buf][chunk * 1024]);
        }
#pragma unroll
        for (int j = 0; j < 2; ++j) {
            int chunk = j * 4 + wave;
            gload_lds16b(Bb + (size_t)(chunk * 16 + lrow) * ldb + kt * 64 + lswb,
                         &Bs[buf][chunk * 1024]);
        }
    };

    const int nt = K >> 6;
    stage(0, 0);
    stage(1, (nt > 1) ? 1 : 0);
    int cur = 0;
    for (int t = 0; t < nt; ++t) {
        asm volatile("s_waitcnt vmcnt(4)" ::: "memory");  // tile t landed (1 group out)
        __builtin_amdgcn_s_barrier();
        __builtin_amdgcn_sched_barrier(0);
#pragma unroll
        for (int ks = 0; ks < 2; ++ks) {
            long a[4], b[4];
#pragma unroll
            for (int mf = 0; mf < 4; ++mf)
                a[mf] = *(const long*)&As[cur][(wm * 64 + mf * 16 + rl) * 64 +
                                               (((ks * 2 + kgh) ^ key) << 4) + kgl8];
#pragma unroll
            for (int nf = 0; nf < 4; ++nf)
                b[nf] = *(const long*)&Bs[cur][(wn * 64 + nf * 16 + rl) * 64 +
                                               (((ks * 2 + kgh) ^ key) << 4) + kgl8];
            if (ks == 0) {   // stage tile t+2 once per iter (keeps FIFO count exact)
                const int nx = (t + 2 < nt) ? t + 2 : nt - 1;
                int nb = cur + 2; if (nb >= 3) nb -= 3;
                stage(nb, nx);
            }
#pragma unroll
            for (int mf = 0; mf < 4; ++mf)
#pragma unroll
                for (int nf = 0; nf < 4; ++nf)
                    acc[mf][nf] = __builtin_amdgcn_mfma_f32_16x16x32_fp8_fp8(
                        a[mf], b[nf], acc[mf][nf], 0, 0, 0);
        }
        cur = (cur + 1 == 3) ? 0 : cur + 1;
    }
    asm volatile("s_waitcnt vmcnt(0)" ::: "memory");

#pragma unroll
    for (int nf = 0; nf < 4; ++nf) {
        const int gn = bn + wn * 64 + nf * 16 + rl;
        const float bv = bias[gn];
#pragma unroll
        for (int mf = 0; mf < 4; ++mf) {
            const int gm = bm + wm * 64 + mf * 16 + kg4;
            if constexpr (MODE == 7) {
                u8* C8 = (u8*)Cv;
#pragma unroll
                for (int r = 0; r < 4; ++r)
                    C8[(size_t)(gm + r) * ldc + gn] = f2fp8(gelu_tanh(acc[mf][nf][r] + bv));
            } else {
                ushortT* Ch = (ushortT*)Cv;
#pragma unroll
                for (int r = 0; r < 4; ++r)
                    Ch[(size_t)(gm + r) * ldc + gn] = f2bf(acc[mf][nf][r] + bv);
            }
        }
    }
}

// ---------------- bf16 MFMA GEMM, 3-buffer counted-vmcnt pipeline ----------------
// (unchanged R12/R14 kernel; used for QKV/scores/PV/Wo)
// MODE: 0 bias | 4 no bias | 5 fused-QKV routing | 6 fused mask+softmax
template<int WM, int WN, int MODE>
__global__ __launch_bounds__(256) void gemm_mfma(
    const ushortT* __restrict__ A, int lda, long long sAo, long long sAi,
    const ushortT* __restrict__ Bt, int ldb, long long sBo, long long sBi,
    const float* __restrict__ bias,
    void* __restrict__ Cv, int ldc, long long sCo, long long sCi,
    int K, int innerN)
{
    constexpr int BM = WM * 64, BN = WN * 64;
    __shared__ __align__(16) ushortT As[3][BM * 32];
    __shared__ __align__(16) ushortT Bs[3][BN * 32];
    const int tid = threadIdx.x;
    const int wave = tid >> 6, lane = tid & 63;
    const int ob = blockIdx.z / innerN, ib = blockIdx.z - ob * innerN;

    int bxi = blockIdx.x, byi = blockIdx.y;
    if (gridDim.z == 1) {
        const int nwg = gridDim.x * gridDim.y;
        const int lin = byi * gridDim.x + bxi;
        const int cpx = nwg >> 3;
        const int sw = (lin & 7) * cpx + (lin >> 3);
        byi = sw / gridDim.x; bxi = sw - byi * gridDim.x;
    }
    const int bm = byi * BM, bn = bxi * BN;
    const ushortT* Ab = A + ob * sAo + ib * sAi + (size_t)bm * lda;
    const ushortT* Bb = Bt + ob * sBo + ib * sBi + (size_t)bn * ldb;
    const int wm = wave / WN, wn = wave - wm * WN;

    const int lrow = lane >> 2;
    const int lsw16 = ((lane & 3) ^ ((lrow >> 1) & 3)) * 8;
    const int rl = lane & 15;
    const int kg4 = (lane >> 4) << 2;
    const int ksw = ((lane >> 4) ^ ((rl >> 1) & 3)) << 3;

    f32x4 acc[4][4];
#pragma unroll
    for (int i = 0; i < 4; ++i)
#pragma unroll
        for (int j = 0; j < 4; ++j) acc[i][j] = (f32x4){0.f, 0.f, 0.f, 0.f};

    auto stage = [&](int buf, int k0) {
#pragma unroll
        for (int j = 0; j < WM; ++j) {
            int chunk = j * 4 + wave;
            gload_lds16(Ab + (size_t)(chunk * 16 + lrow) * lda + k0 + lsw16,
                        &As[buf][chunk * 512]);
        }
#pragma unroll
        for (int j = 0; j < WN; ++j) {
            int chunk = j * 4 + wave;
            gload_lds16(Bb + (size_t)(chunk * 16 + lrow) * ldb + k0 + lsw16,
                        &Bs[buf][chunk * 512]);
        }
    };

    const int nt = K >> 5;
    stage(0, 0);
    stage(1, ((nt > 1) ? 1 : 0) << 5);
    int cur = 0;
    for (int t = 0; t < nt; ++t) {
        if constexpr (WM + WN == 4)
            asm volatile("s_waitcnt vmcnt(4)" ::: "memory");
        else
            asm volatile("s_waitcnt vmcnt(5)" ::: "memory");
        __builtin_amdgcn_s_barrier();
        __builtin_amdgcn_sched_barrier(0);
        u32x4 a[4], b[4];
#pragma unroll
        for (int mf = 0; mf < 4; ++mf)
            a[mf] = *(const u32x4*)&As[cur][(wm * 64 + mf * 16 + rl) * 32 + ksw];
#pragma unroll
        for (int nf = 0; nf < 4; ++nf)
            b[nf] = *(const u32x4*)&Bs[cur][(wn * 64 + nf * 16 + rl) * 32 + ksw];
        {
            const int nx = (t + 2 < nt) ? t + 2 : nt - 1;
            int nb = cur + 2; if (nb >= 3) nb -= 3;
            stage(nb, nx << 5);
        }
#pragma unroll
        for (int mf = 0; mf < 4; ++mf)
#pragma unroll
            for (int nf = 0; nf < 4; ++nf)
                acc[mf][nf] = mfma16(a[mf], b[nf], acc[mf][nf]);
        cur = (cur + 1 == 3) ? 0 : cur + 1;
    }
    asm volatile("s_waitcnt vmcnt(0)" ::: "memory");

    ushortT* Ch = (ushortT*)Cv + ob * sCo + ib * sCi;
    if constexpr (MODE == 6) {
        __shared__ float red6[2][4][64];
        const int* mrow = (const int*)bias + ob * S;
        float mb[4];
#pragma unroll
        for (int nf = 0; nf < 4; ++nf)
            mb[nf] = mrow[bn + wn * 64 + nf * 16 + rl] ? 0.f : -8e9f;
        float pm[4][4];
#pragma unroll
        for (int mf = 0; mf < 4; ++mf)
#pragma unroll
            for (int r = 0; r < 4; ++r) pm[mf][r] = -1e30f;
#pragma unroll
        for (int mf = 0; mf < 4; ++mf)
#pragma unroll
            for (int nf = 0; nf < 4; ++nf)
#pragma unroll
                for (int r = 0; r < 4; ++r) {
                    acc[mf][nf][r] += mb[nf];
                    pm[mf][r] = fmaxf(pm[mf][r], acc[mf][nf][r]);
                }
#pragma unroll
        for (int mf = 0; mf < 4; ++mf)
#pragma unroll
            for (int r = 0; r < 4; ++r) {
                float v = pm[mf][r];
                v = fmaxf(v, __shfl_xor(v, 1));
                v = fmaxf(v, __shfl_xor(v, 2));
                v = fmaxf(v, __shfl_xor(v, 4));
                v = fmaxf(v, __shfl_xor(v, 8));
                pm[mf][r] = v;
            }
        if (rl == 0) {
#pragma unroll
            for (int mf = 0; mf < 4; ++mf)
#pragma unroll
                for (int r = 0; r < 4; ++r)
                    red6[0][wn][mf * 16 + kg4 + r] = pm[mf][r];
        }
        __syncthreads();
        float Mx[4][4];
#pragma unroll
        for (int mf = 0; mf < 4; ++mf)
#pragma unroll
            for (int r = 0; r < 4; ++r) {
                const int row = mf * 16 + kg4 + r;
                Mx[mf][r] = fmaxf(fmaxf(red6[0][0][row], red6[0][1][row]),
                                  fmaxf(red6[0][2][row], red6[0][3][row]));
            }
        float ps[4][4];
#pragma unroll
        for (int mf = 0; mf < 4; ++mf)
#pragma unroll
            for (int r = 0; r < 4; ++r) ps[mf][r] = 0.f;
#pragma unroll
        for (int mf = 0; mf < 4; ++mf)
#pragma unroll
            for (int nf = 0; nf < 4; ++nf)
#pragma unroll
                for (int r = 0; r < 4; ++r) {
                    float e = exp2i(C2 * (acc[mf][nf][r] - Mx[mf][r]));
                    acc[mf][nf][r] = e;
                    ps[mf][r] += e;
                }
#pragma unroll
        for (int mf = 0; mf < 4; ++mf)
#pragma unroll
            for (int r = 0; r < 4; ++r) {
                float v = ps[mf][r];
                v += __shfl_xor(v, 1);
                v += __shfl_xor(v, 2);
                v += __shfl_xor(v, 4);
                v += __shfl_xor(v, 8);
                ps[mf][r] = v;
            }
        if (rl == 0) {
#pragma unroll
            for (int mf = 0; mf < 4; ++mf)
#pragma unroll
                for (int r = 0; r < 4; ++r)
                    red6[1][wn][mf * 16 + kg4 + r] = ps[mf][r];
        }
        __syncthreads();
#pragma unroll
        for (int mf = 0; mf < 4; ++mf) {
            float inv[4];
#pragma unroll
            for (int r = 0; r < 4; ++r) {
                const int row = mf * 16 + kg4 + r;
                inv[r] = 1.0f / (red6[1][0][row] + red6[1][1][row] +
                                 red6[1][2][row] + red6[1][3][row]);
            }
#pragma unroll
            for (int nf = 0; nf < 4; ++nf) {
                const int gn = bn + wn * 64 + nf * 16 + rl;
                const int gm = bm + mf * 16 + kg4;
#pragma unroll
                for (int r = 0; r < 4; ++r)
                    Ch[(size_t)(gm + r) * ldc + gn] = f2bf(acc[mf][nf][r] * inv[r]);
            }
        }
    } else {
#pragma unroll
        for (int nf = 0; nf < 4; ++nf) {
            int gn = bn + wn * 64 + nf * 16 + rl;
            float bv = 0.f;
            if constexpr (MODE != 4) bv = bias[gn];
#pragma unroll
            for (int mf = 0; mf < 4; ++mf) {
                int gm = bm + wm * 64 + mf * 16 + kg4;
                if constexpr (MODE == 5) {
                    const int region = gn / H;          // 0=q,1=k,2=v
                    const int col = gn - region * H;
                    if (region < 2) {
                        ushortT* o = (ushortT*)Cv + (size_t)region * TOKENS * H;
#pragma unroll
                        for (int r = 0; r < 4; ++r)
                            o[(size_t)(gm + r) * H + col] = f2bf(acc[mf][nf][r] + bv);
                    } else {
                        u16x4 o;
#pragma unroll
                        for (int r = 0; r < 4; ++r) o[r] = f2bf(acc[mf][nf][r] + bv);
                        const int b_ = gm >> 8, s0 = gm & 255;
                        const int h_ = col >> 6, dh = col & 63;
                        *(u16x4*)((ushortT*)Cv + 2 * (size_t)TOKENS * H +
                                  (((size_t)(b_ * NHD + h_) * DH + dh) << 8) + s0) = o;
                    }
                } else {
#pragma unroll
                    for (int r = 0; r < 4; ++r) {
                        float x = acc[mf][nf][r] + bv;
                        Ch[(size_t)(gm + r) * ldc + gn] = f2bf(x);
                    }
                }
            }
        }
    }
}

// ---------------- all 6 weight transposes of one layer, one dispatch ----------------
// QKV/Wo -> bf16; W1/W2 -> fp8 e4m3
__global__ __launch_bounds__(256) void transpose_all_k(
    const float* __restrict__ Wq, const float* __restrict__ Wk,
    const float* __restrict__ Wv, const float* __restrict__ Wo,
    const float* __restrict__ W1, const float* __restrict__ W2,
    ushortT* __restrict__ wtqkv, ushortT* __restrict__ wto,
    u8* __restrict__ wt1, u8* __restrict__ wt2)
{
    int idx = blockIdx.x;
    const float* W; int R, C, tr, tc; int kind; // 0 bf16, 1 fp8
    ushortT* WTb = nullptr; u8* WT8 = nullptr;
    if (idx < 2304) {
        int mat = idx / 576, t = idx - mat * 576;
        tr = t / 24; tc = t - tr * 24; R = 768; C = 768; kind = 0;
        W = mat == 0 ? Wq : mat == 1 ? Wk : mat == 2 ? Wv : Wo;
        WTb = mat < 3 ? wtqkv + (size_t)mat * 768 * 768 : wto;
    } else if (idx < 4608) {
        int t = idx - 2304; tr = t / 96; tc = t - tr * 96;
        R = 768; C = 3072; W = W1; WT8 = wt1; kind = 1;
    } else {
        int t = idx - 4608; tr = t / 24; tc = t - tr * 24;
        R = 3072; C = 768; W = W2; WT8 = wt2; kind = 1;
    }
    int r0 = tr * 32, c0 = tc * 32;
    __shared__ float tl[32][33];
    int trd = threadIdx.x >> 3;
    int tc4 = (threadIdx.x & 7) * 4;
    const float4 v = *(const float4*)(W + (size_t)(r0 + trd) * C + c0 + tc4);
    tl[trd][tc4 + 0] = v.x; tl[trd][tc4 + 1] = v.y;
    tl[trd][tc4 + 2] = v.z; tl[trd][tc4 + 3] = v.w;
    __syncthreads();
    if (kind == 0) {
        u16x4 o;
#pragma unroll
        for (int q = 0; q < 4; ++q) o[q] = f2bf(tl[tc4 + q][trd]);
        *(u16x4*)(WTb + (size_t)(c0 + trd) * R + r0 + tc4) = o;
    } else {
        unsigned p = f2fp8x4(tl[tc4 + 0][trd], tl[tc4 + 1][trd],
                             tl[tc4 + 2][trd], tl[tc4 + 3][trd]);
        *(unsigned*)(WT8 + (size_t)(c0 + trd) * R + r0 + tc4) = p;
    }
}

// ---------------- pack qkv biases -> [NLAY][2304] ----------------
__global__ __launch_bounds__(256) void pack_bias_k(
    const float* __restrict__ bq, const float* __restrict__ bk,
    const float* __restrict__ bv, float* __restrict__ out)
{
    int l = blockIdx.x / 3, r = blockIdx.x - (blockIdx.x / 3) * 3;
    const float* src = r == 0 ? bq : r == 1 ? bk : bv;
#pragma unroll
    for (int j = 0; j < 3; ++j) {
        int d = threadIdx.x + 256 * j;
        out[(size_t)l * QKVN + r * H + d] = src[(size_t)l * H + d];
    }
}

// ---------------- embeddings + LN -> bf16 h; 4 tokens/block, 1 wave/token ----------------
__global__ __launch_bounds__(256) void embed_ln_k(
    const int* __restrict__ ids, const int* __restrict__ tts,
    const float* __restrict__ wemb, const float* __restrict__ pemb,
    const float* __restrict__ temb, const float* __restrict__ g,
    const float* __restrict__ bp, ushortT* __restrict__ hb)
{
    const int tok = blockIdx.x * 4 + (threadIdx.x >> 6);
    const int lane = threadIdx.x & 63;
    const int d0 = lane * 12;
    const int spos = tok & (S - 1);
    const int id = ids[tok], tt = tts[tok];
    const float* wr = wemb + (size_t)id * H + d0;
    const float* pr = pemb + (size_t)spos * H + d0;
    const float* tr = temb + (size_t)tt * H + d0;
    float x[12]; float s = 0.f, ss = 0.f;
#pragma unroll
    for (int j = 0; j < 3; ++j) {
        float4 a = *(const float4*)(wr + j * 4);
        float4 b = *(const float4*)(pr + j * 4);
        float4 c = *(const float4*)(tr + j * 4);
        float v0 = a.x + b.x + c.x, v1 = a.y + b.y + c.y;
        float v2 = a.z + b.z + c.z, v3 = a.w + b.w + c.w;
        x[j*4+0] = v0; x[j*4+1] = v1; x[j*4+2] = v2; x[j*4+3] = v3;
        s += v0 + v1 + v2 + v3;
        ss += v0*v0 + v1*v1 + v2*v2 + v3*v3;
    }
#pragma unroll
    for (int m = 32; m; m >>= 1) { s += __shfl_xor(s, m); ss += __shfl_xor(ss, m); }
    float mu = s * (1.f / H);
    float var = ss * (1.f / H) - mu * mu;
    float rs = rsqrtf(var + 1e-12f);
#pragma unroll
    for (int j = 0; j < 3; ++j) {
        float4 gv = *(const float4*)(g + d0 + j * 4);
        float4 bv = *(const float4*)(bp + d0 + j * 4);
        u16x4 o;
        o[0] = f2bf((x[j*4+0] - mu) * rs * gv.x + bv.x);
        o[1] = f2bf((x[j*4+1] - mu) * rs * gv.y + bv.y);
        o[2] = f2bf((x[j*4+2] - mu) * rs * gv.z + bv.z);
        o[3] = f2bf((x[j*4+3] - mu) * rs * gv.w + bv.w);
        *(u16x4*)(hb + (size_t)tok * H + d0 + j * 4) = o;
    }
}

// ---------------- bf16 residual add + LN, in place on hb; emits fp8 copy ----------------
__global__ __launch_bounds__(256) void add_ln_k(
    ushortT* __restrict__ hb, const ushortT* __restrict__ add,
    const float* __restrict__ g, const float* __restrict__ bp,
    u8* __restrict__ h8)
{
    const int tok = blockIdx.x * 4 + (threadIdx.x >> 6);
    const int lane = threadIdx.x & 63;
    const int d0 = lane * 12;
    const size_t base = (size_t)tok * H + d0;
    float x[12]; float s = 0.f, ss = 0.f;
#pragma unroll
    for (int j = 0; j < 3; ++j) {
        u16x4 hv = *(const u16x4*)(hb + base + j * 4);
        u16x4 av = *(const u16x4*)(add + base + j * 4);
#pragma unroll
        for (int q = 0; q < 4; ++q) {
            float v = bf2f(hv[q]) + bf2f(av[q]);
            x[j*4+q] = v; s += v; ss += v * v;
        }
    }
#pragma unroll
    for (int m = 32; m; m >>= 1) { s += __shfl_xor(s, m); ss += __shfl_xor(ss, m); }
    float mu = s * (1.f / H);
    float var = ss * (1.f / H) - mu * mu;
    float rs = rsqrtf(var + 1e-12f);
#pragma unroll
    for (int j = 0; j < 3; ++j) {
        float4 gv = *(const float4*)(g + d0 + j * 4);
        float4 bv = *(const float4*)(bp + d0 + j * 4);
        float y0 = (x[j*4+0] - mu) * rs * gv.x + bv.x;
        float y1 = (x[j*4+1] - mu) * rs * gv.y + bv.y;
        float y2 = (x[j*4+2] - mu) * rs * gv.z + bv.z;
        float y3 = (x[j*4+3] - mu) * rs * gv.w + bv.w;
        u16x4 o;
        o[0] = f2bf(y0); o[1] = f2bf(y1); o[2] = f2bf(y2); o[3] = f2bf(y3);
        *(u16x4*)(hb + base + j * 4) = o;
        *(unsigned*)(h8 + base + j * 4) = f2fp8x4(y0, y1, y2, y3);
    }
}

// ---------------- logits + log_softmax over 9 labels (bf16 h, f32 math) ----------------
__global__ __launch_bounds__(256) void logits_k(
    const ushortT* __restrict__ hb, const float* __restrict__ fcw,
    float* __restrict__ em)
{
    int tok = blockIdx.x, tid = threadIdx.x;
    float p[LBL];
#pragma unroll
    for (int l = 0; l < LBL; ++l) p[l] = 0.f;
    const ushortT* hr = hb + (size_t)tok * H;
#pragma unroll
    for (int j = 0; j < 3; ++j) {
        int d = tid + 256 * j;
        float hv = bf2f(hr[d]);
        const float* fr = fcw + (size_t)d * LBL;
#pragma unroll
        for (int l = 0; l < LBL; ++l) p[l] = fmaf(hv, fr[l], p[l]);
    }
    __shared__ float ls[4][LBL];
    __shared__ float lg[LBL];
    __shared__ float lse;
#pragma unroll
    for (int l = 0; l < LBL; ++l) {
        float v = p[l];
#pragma unroll
        for (int m = 32; m; m >>= 1) v += __shfl_xor(v, m);
        if ((tid & 63) == 0) ls[tid >> 6][l] = v;
    }
    __syncthreads();
    if (tid < LBL) lg[tid] = ls[0][tid] + ls[1][tid] + ls[2][tid] + ls[3][tid];
    __syncthreads();
    if (tid == 0) {
        float mx = lg[0];
#pragma unroll
        for (int j = 1; j < LBL; ++j) mx = fmaxf(mx, lg[j]);
        float sm = 0.f;
#pragma unroll
        for (int j = 0; j < LBL; ++j) sm += expf(lg[j] - mx);
        lse = mx + logf(sm);
    }
    __syncthreads();
    if (tid < LBL) em[(size_t)tok * LBL + tid] = lg[tid] - lse;
}

// ---------------- CRF: one wave per batch elem, base-2 fast recursion ----------------
__global__ __launch_bounds__(64) void crf_k(
    const float* __restrict__ em, const int* __restrict__ tags,
    const int* __restrict__ mask, const float* __restrict__ sp,
    const float* __restrict__ ep, const float* __restrict__ trans,
    float* __restrict__ partial)
{
    constexpr float LOG2E = 1.4426950408889634f;
    constexpr float LN2   = 0.6931471805599453f;
    int b = blockIdx.x, t = threadIdx.x;
    __shared__ float eml[S * LBL];     // emissions * log2(e)
    __shared__ int mkl[S];
    const float* emb = em + (size_t)b * S * LBL;
    const int* tg = tags + (size_t)b * S;
    const int* mk = mask + (size_t)b * S;

    for (int i = t * 4; i < S * LBL; i += 256) {
        float4 v = *(const float4*)&emb[i];
        v.x *= LOG2E; v.y *= LOG2E; v.z *= LOG2E; v.w *= LOG2E;
        *(float4*)&eml[i] = v;
    }
    *(i32x4*)&mkl[t * 4] = *(const i32x4*)&mk[t * 4];

    int cnt = 0; float ns = 0.f;
    for (int i = t; i < S; i += 64) {
        int m = mk[i];
        cnt += (m != 0);
        if (i >= 1 && m)
            ns += trans[tg[i - 1] * LBL + tg[i]] + emb[(size_t)i * LBL + tg[i]];
    }
#pragma unroll
    for (int m = 32; m; m >>= 1) { cnt += __shfl_xor(cnt, m); ns += __shfl_xor(ns, m); }
    float num = ns + sp[tg[0]] + emb[tg[0]] + ep[tg[cnt - 1]];

    int tt = t < LBL ? t : 0;
    float trc2[LBL];
#pragma unroll
    for (int i = 0; i < LBL; ++i) trc2[i] = trans[i * LBL + tt] * LOG2E;

    __syncthreads();

    float alpha2 = (t < LBL) ? sp[t] * LOG2E + eml[t] : -1e30f;
    for (int step = 1; step < S; ++step) {
        float av[LBL];
#pragma unroll
        for (int i = 0; i < LBL; ++i) av[i] = __shfl(alpha2, i) + trc2[i];
        float mx = av[0];
#pragma unroll
        for (int i = 1; i < LBL; ++i) mx = fmaxf(mx, av[i]);
        float sm = 0.f;
#pragma unroll
        for (int i = 0; i < LBL; ++i) sm += exp2i(av[i] - mx);
        float na = mx + log2i(sm) + eml[step * LBL + tt];
        alpha2 = (mkl[step] && t < LBL) ? na : alpha2;
    }
    float z = (t < LBL) ? alpha2 + ep[t] * LOG2E : -1e30f;
    float mx = z;
#pragma unroll
    for (int m = 8; m; m >>= 1) mx = fmaxf(mx, __shfl_xor(mx, m));
    float sm = exp2i(z - mx);
#pragma unroll
    for (int m = 8; m; m >>= 1) sm += __shfl_xor(sm, m);
    if (t == 0) partial[b] = (mx + log2i(sm)) * LN2 - num;
}

__global__ void finalize_k(const float* __restrict__ partial, float* __restrict__ out) {
    float s = 0.f;
    for (int i = 0; i < BATCH; ++i) s += partial[i];
    out[0] = s;
}

__global__ void sentinel_k(float* out) { out[0] = -12345.0f; }

extern "C" void kernel_launch(void* const* d_in, const int* in_sizes, int n_in,
                              void* d_out, int out_size, void* d_ws, size_t ws_size,
                              hipStream_t stream) {
    (void)in_sizes; (void)n_in; (void)out_size;
    const int* token_ids  = (const int*)d_in[0];
    const int* token_type = (const int*)d_in[1];
    const int* amask      = (const int*)d_in[2];
    const int* y          = (const int*)d_in[3];
    const float* wemb = (const float*)d_in[4];
    const float* pemb = (const float*)d_in[5];
    const float* temb = (const float*)d_in[6];
    const float* eg   = (const float*)d_in[7];
    const float* eb   = (const float*)d_in[8];
    const float* Wq = (const float*)d_in[9];
    const float* bq = (const float*)d_in[10];
    const float* Wk = (const float*)d_in[11];
    const float* bk = (const float*)d_in[12];
    const float* Wv = (const float*)d_in[13];
    const float* bv = (const float*)d_in[14];
    const float* Wo = (const float*)d_in[15];
    const float* bo = (const float*)d_in[16];
    const float* ln1g = (const float*)d_in[17];
    const float* ln1b = (const float*)d_in[18];
    const float* W1 = (const float*)d_in[19];
    const float* b1 = (const float*)d_in[20];
    const float* W2 = (const float*)d_in[21];
    const float* b2 = (const float*)d_in[22];
    const float* ln2g = (const float*)d_in[23];
    const float* ln2b = (const float*)d_in[24];
    const float* fcw = (const float*)d_in[25];
    const float* crf_s = (const float*)d_in[26];
    const float* crf_e = (const float*)d_in[27];
    const float* crf_t = (const float*)d_in[28];

    if (ws_size < WS_FLOATS * sizeof(float)) {
        sentinel_k<<<1, 1, 0, stream>>>((float*)d_out);
        return;
    }

    float* ws = (float*)d_ws;
    ushortT* hb   = (ushortT*)(ws + HB_OFF);
    ushortT* qb   = (ushortT*)(ws + QB_OFF);   // q base; k = +TOKENS*H; vt = +2*TOKENS*H
    ushortT* kb   = (ushortT*)(ws + KB_OFF);
    ushortT* vt   = (ushortT*)(ws + VT_OFF);
    ushortT* big  = (ushortT*)(ws + BIG_OFF);  // probs bf16; also ff1 fp8 (aliased)
    u8*      big8 = (u8*)(ws + BIG_OFF);
    ushortT* wtq  = (ushortT*)(ws + WTQ_OFF);  // [2304][768] bf16
    ushortT* wto  = (ushortT*)(ws + WTO_OFF);
    u8*      wt1  = (u8*)(ws + WT1_OFF);       // [3072][768] fp8
    u8*      wt2  = (u8*)(ws + WT2_OFF);       // [768][3072] fp8
    float*   embuf = ws + EM_OFF;
    float*   part  = ws + PART_OFF;
    float*   bqkv  = ws + BQKV_OFF;
    u8*      h8    = (u8*)(ws + H8_OFF);       // [8192][768] fp8

    pack_bias_k<<<NLAY * 3, 256, 0, stream>>>(bq, bk, bv, bqkv);
    embed_ln_k<<<TOKENS / 4, 256, 0, stream>>>(token_ids, token_type, wemb, pemb,
                                               temb, eg, eb, hb);

    constexpr long long HH = (long long)H * H;
    constexpr long long HF = (long long)H * FF;
    constexpr long long TOKH = (long long)S * H;        // 196608
    constexpr long long ATT_B = (long long)NHD * S * S; // 786432
    constexpr long long ATT_H = (long long)S * S;       // 65536
    constexpr long long VT_B = (long long)NHD * DH * S; // 196608
    constexpr long long VT_H = (long long)DH * S;       // 16384

    dim3 gQKV(QKVN / 128, TOKENS / 128, 1);       // 18 x 64 = 1152 (%8==0)
    dim3 gProj(H / 128, TOKENS / 128, 1);         // 6 x 64 = 384
    dim3 gFF1(FF / 128, TOKENS / 128, 1);         // 24 x 64 = 1536
    dim3 gScores(1, S / 64, BATCH * NHD);         // 1 x 4 x 384
    dim3 gPV(1, 1, BATCH * NHD);                  // 256x64 tile covers head

    for (int l = 0; l < NLAY; ++l) {
        transpose_all_k<<<6912, 256, 0, stream>>>(
            Wq + l * HH, Wk + l * HH, Wv + l * HH, Wo + l * HH,
            W1 + l * HF, W2 + l * HF, wtq, wto, wt1, wt2);

        // fused q,k,v projections (3-buffer pipelined 128^2 with routing epilogue)
        gemm_mfma<2,2,5><<<gQKV, 256, 0, stream>>>(
            hb, H, 0, 0, wtq, H, 0, 0, bqkv + (size_t)l * QKVN,
            qb, H, 0, 0, H, 1);

        // probs = softmax(mask(q @ k^T)) per (b,h), fused epilogue -> bf16
        gemm_mfma<1,4,6><<<gScores, 256, 0, stream>>>(
            qb, H, TOKH, DH, kb, H, TOKH, DH, (const float*)amask,
            big, S, ATT_B, ATT_H, DH, NHD);

        // ctx = probs @ v  (per b,h) -> qb as [B,S,NH,DH] bf16
        gemm_mfma<4,1,4><<<gPV, 256, 0, stream>>>(
            big, S, ATT_B, ATT_H, vt, S, VT_B, VT_H, nullptr,
            qb, H, TOKH, DH, S, NHD);

        // attention output projection -> kb (bf16)
        gemm_mfma<2,2,0><<<gProj, 256, 0, stream>>>(
            qb, H, 0, 0, wto, H, 0, 0, bo + l * H, kb, H, 0, 0, H, 1);

        add_ln_k<<<TOKENS / 4, 256, 0, stream>>>(hb, kb, ln1g + l * H, ln1b + l * H, h8);

        // ff1 = gelu(h @ W1 + b1) -> big8 fp8  (FP8 GEMM, K=768)
        gemm_fp8<7><<<gFF1, 256, 0, stream>>>(
            h8, H, wt1, H, b1 + (long long)l * FF, big8, FF, H);

        // ff2 = big8 @ W2 + b2 -> qb bf16  (FP8 GEMM, K=3072)
        gemm_fp8<8><<<gProj, 256, 0, stream>>>(
            big8, FF, wt2, FF, b2 + l * H, qb, H, FF);

        add_ln_k<<<TOKENS / 4, 256, 0, stream>>>(hb, qb, ln2g + l * H, ln2b + l * H, h8);
    }

    logits_k<<<TOKENS, 256, 0, stream>>>(hb, fcw, embuf);
    crf_k<<<BATCH, 64, 0, stream>>>(embuf, y, amask, crf_s, crf_e, crf_t, part);
    finalize_k<<<1, 1, 0, stream>>>(part, (float*)d_out);
}

// Round 16
// 2585.295 us; speedup vs baseline: 1.6648x; 1.0703x over previous
//
#include <hip/hip_runtime.h>
#include <math.h>

typedef unsigned short ushortT;
typedef unsigned char u8;
typedef __attribute__((ext_vector_type(4))) float f32x4;
typedef __attribute__((ext_vector_type(4))) unsigned int u32x4;
typedef __attribute__((ext_vector_type(4))) unsigned short u16x4;
typedef __attribute__((ext_vector_type(4))) int i32x4;
typedef __attribute__((ext_vector_type(8))) __bf16 bf16x8;

namespace {
constexpr int S = 256;
constexpr int H = 768;
constexpr int NLAY = 12;
constexpr int NHD = 12;
constexpr int FF = 3072;
constexpr int LBL = 9;
constexpr int DH = 64;
constexpr int BATCH = 32;
constexpr int TOKENS = BATCH * S;      // 8192
constexpr int QKVN = 3 * H;            // 2304
// softmax scale folded into exponent: p = exp2(C2*(s_raw - m_raw)), C2 = 0.125*log2(e)
constexpr float C2 = 0.18033688011112042f;

// workspace layout (float-slot units)
constexpr size_t HB_OFF  = 0;                            // h bf16 (half slots)
constexpr size_t QB_OFF  = HB_OFF + (size_t)TOKENS*H/2;  // q / ff2out bf16
constexpr size_t KB_OFF  = QB_OFF + (size_t)TOKENS*H/2;  // k / attn-out bf16
constexpr size_t VT_OFF  = KB_OFF + (size_t)TOKENS*H/2;  // v^T bf16 [B*NH*DH][S]
constexpr size_t BIG_OFF = VT_OFF + (size_t)TOKENS*H/2;  // probs bf16 == ff1 fp8
constexpr size_t WTQ_OFF = BIG_OFF + (size_t)TOKENS*FF/2;  // Wq^T,Wk^T,Wv^T fp8 [2304][768]
constexpr size_t WTO_OFF = WTQ_OFF + 3*(size_t)H*H/4;    // Wo^T fp8 [768][768]
constexpr size_t WT1_OFF = WTO_OFF + (size_t)H*H/4;      // W1^T fp8 [3072][768]
constexpr size_t WT2_OFF = WT1_OFF + (size_t)H*FF/4;     // W2^T fp8 [768][3072]
constexpr size_t EM_OFF  = WT2_OFF + (size_t)H*FF/4;
constexpr size_t PART_OFF= EM_OFF + (size_t)TOKENS*LBL;
constexpr size_t BQKV_OFF= PART_OFF + 64;                // packed qkv bias [12][2304]
constexpr size_t H8_OFF  = BQKV_OFF + (size_t)NLAY*QKVN; // h fp8 copy [8192][768]
constexpr size_t CT8_OFF = H8_OFF + (size_t)TOKENS*H/4;  // ctx fp8 [8192][768]
constexpr size_t WS_FLOATS = CT8_OFF + (size_t)TOKENS*H/4;
}

__device__ __forceinline__ ushortT f2bf(float x) {
    unsigned u = __builtin_bit_cast(unsigned, x);
    u += 0x7fffu + ((u >> 16) & 1u);
    return (ushortT)(u >> 16);
}
__device__ __forceinline__ float bf2f(ushortT h) {
    unsigned u = ((unsigned)h) << 16;
    return __builtin_bit_cast(float, u);
}
__device__ __forceinline__ u8 f2fp8(float x) {
    return (u8)(__builtin_amdgcn_cvt_pk_fp8_f32(x, x, 0, false) & 0xff);
}
__device__ __forceinline__ unsigned f2fp8x4(float a, float b, float c, float d) {
    int p = __builtin_amdgcn_cvt_pk_fp8_f32(a, b, 0, false);
    p = __builtin_amdgcn_cvt_pk_fp8_f32(c, d, p, true);
    return (unsigned)p;
}

__device__ __forceinline__ float exp2i(float x) {
    float r; asm("v_exp_f32 %0, %1" : "=v"(r) : "v"(x)); return r;
}
__device__ __forceinline__ float log2i(float x) {
    float r; asm("v_log_f32 %0, %1" : "=v"(r) : "v"(x)); return r;
}

// tanh-gelu in sigmoid form: 0.5x(1+tanh(u)) == x*sigmoid(2u) == x/(1+exp2(-2u*log2e))
__device__ __forceinline__ float gelu_tanh(float x) {
    float u = 0.7978845608028654f * (x + 0.044715f * x * x * x);
    float t = exp2i(-2.8853900817779268f * u);
    return x / (1.0f + t);
}

__device__ __forceinline__ f32x4 mfma16(u32x4 a, u32x4 b, f32x4 c) {
    return __builtin_amdgcn_mfma_f32_16x16x32_bf16(
        __builtin_bit_cast(bf16x8, a), __builtin_bit_cast(bf16x8, b), c, 0, 0, 0);
}

__device__ __forceinline__ void gload_lds16(const ushortT* g, ushortT* l) {
    __builtin_amdgcn_global_load_lds(
        (const __attribute__((address_space(1))) unsigned int*)g,
        (__attribute__((address_space(3))) unsigned int*)l,
        16, 0, 0);
}
__device__ __forceinline__ void gload_lds16b(const u8* g, u8* l) {
    __builtin_amdgcn_global_load_lds(
        (const __attribute__((address_space(1))) unsigned int*)g,
        (__attribute__((address_space(3))) unsigned int*)l,
        16, 0, 0);
}

// =====================================================================
// FP8 e4m3 MFMA GEMM: BM=BN=128, 4 waves, wave 64x64, K-step 64.
// Same geometry/swizzle/pipeline as the bf16 kernel (64B LDS rows,
// (row>>1)&3 16B-chunk both-sides swizzle, 3-buffer counted-vmcnt,
// stage group = 4 loads/thread -> vmcnt(4)); 32 MFMAs/iter at the same
// MFMA rate as bf16 but HALF the LDS bytes per FLOP (the binding resource).
// MODE: 7 = bias+gelu -> fp8 (FF1) | 8 = bias -> bf16 (FF2/Wo)
//       | 9 = fused-QKV routing (bf16 q/k/v^T outputs)
// =====================================================================
template<int MODE>
__global__ __launch_bounds__(256) void gemm_fp8(
    const u8* __restrict__ A, int lda,
    const u8* __restrict__ Bt, int ldb,
    const float* __restrict__ bias,
    void* __restrict__ Cv, int ldc, int K)
{
    __shared__ __align__(16) u8 As[3][128 * 64];   // 8 KB each
    __shared__ __align__(16) u8 Bs[3][128 * 64];
    const int tid = threadIdx.x;
    const int wave = tid >> 6, lane = tid & 63;

    int bxi = blockIdx.x, byi = blockIdx.y;
    {
        const int nwg = gridDim.x * gridDim.y;
        const int lin = byi * gridDim.x + bxi;
        const int cpx = nwg >> 3;
        const int sw = (lin & 7) * cpx + (lin >> 3);
        byi = sw / gridDim.x; bxi = sw - byi * gridDim.x;
    }
    const int bm = byi * 128, bn = bxi * 128;
    const u8* Ab = A + (size_t)bm * lda;
    const u8* Bb = Bt + (size_t)bn * ldb;
    const int wm = wave >> 1, wn = wave & 1;

    const int lrow = lane >> 2;                              // row within 16-row chunk
    const int lswb = ((lane & 3) ^ ((lrow >> 1) & 3)) * 16;  // swizzled SRC byte off
    const int rl = lane & 15;
    const int kg = lane >> 4;                                // 0..3
    const int kg4 = kg << 2;
    const int key = (rl >> 1) & 3;                           // read-side swizzle key
    const int kgh = kg >> 1, kgl8 = (kg & 1) * 8;

    f32x4 acc[4][4];
#pragma unroll
    for (int i = 0; i < 4; ++i)
#pragma unroll
        for (int j = 0; j < 4; ++j) acc[i][j] = (f32x4){0.f, 0.f, 0.f, 0.f};

    auto stage = [&](int buf, int kt) {
#pragma unroll
        for (int j = 0; j < 2; ++j) {
            int chunk = j * 4 + wave;        // 8 chunks x 16 rows = 128 rows
            gload_lds16b(Ab + (size_t)(chunk * 16 + lrow) * lda + kt * 64 + lswb,
                         &As[buf][chunk * 1024]);
        }
#pragma unroll
        for (int j = 0; j < 2; ++j) {
            int chunk = j * 4 + wave;
            gload_lds16b(Bb + (size_t)(chunk * 16 + lrow) * ldb + kt * 64 + lswb,
                         &Bs[buf][chunk * 1024]);
        }
    };

    const int nt = K >> 6;
    stage(0, 0);
    stage(1, (nt > 1) ? 1 : 0);
    int cur = 0;
    for (int t = 0; t < nt; ++t) {
        asm volatile("s_waitcnt vmcnt(4)" ::: "memory");  // tile t landed (1 group out)
        __builtin_amdgcn_s_barrier();
        __builtin_amdgcn_sched_barrier(0);
#pragma unroll
        for (int ks = 0; ks < 2; ++ks) {
            long a[4], b[4];
#pragma unroll
            for (int mf = 0; mf < 4; ++mf)
                a[mf] = *(const long*)&As[cur][(wm * 64 + mf * 16 + rl) * 64 +
                                               (((ks * 2 + kgh) ^ key) << 4) + kgl8];
#pragma unroll
            for (int nf = 0; nf < 4; ++nf)
                b[nf] = *(const long*)&Bs[cur][(wn * 64 + nf * 16 + rl) * 64 +
                                               (((ks * 2 + kgh) ^ key) << 4) + kgl8];
            if (ks == 0) {   // stage tile t+2 once per iter (keeps FIFO count exact)
                const int nx = (t + 2 < nt) ? t + 2 : nt - 1;
                int nb = cur + 2; if (nb >= 3) nb -= 3;
                stage(nb, nx);
            }
#pragma unroll
            for (int mf = 0; mf < 4; ++mf)
#pragma unroll
                for (int nf = 0; nf < 4; ++nf)
                    acc[mf][nf] = __builtin_amdgcn_mfma_f32_16x16x32_fp8_fp8(
                        a[mf], b[nf], acc[mf][nf], 0, 0, 0);
        }
        cur = (cur + 1 == 3) ? 0 : cur + 1;
    }
    asm volatile("s_waitcnt vmcnt(0)" ::: "memory");

#pragma unroll
    for (int nf = 0; nf < 4; ++nf) {
        const int gn = bn + wn * 64 + nf * 16 + rl;
        const float bv = bias[gn];
#pragma unroll
        for (int mf = 0; mf < 4; ++mf) {
            const int gm = bm + wm * 64 + mf * 16 + kg4;
            if constexpr (MODE == 7) {
                u8* C8 = (u8*)Cv;
#pragma unroll
                for (int r = 0; r < 4; ++r)
                    C8[(size_t)(gm + r) * ldc + gn] = f2fp8(gelu_tanh(acc[mf][nf][r] + bv));
            } else if constexpr (MODE == 9) {
                const int region = gn / H;          // 0=q,1=k,2=v
                const int col = gn - region * H;
                if (region < 2) {
                    ushortT* o = (ushortT*)Cv + (size_t)region * TOKENS * H;
#pragma unroll
                    for (int r = 0; r < 4; ++r)
                        o[(size_t)(gm + r) * H + col] = f2bf(acc[mf][nf][r] + bv);
                } else {
                    u16x4 o;
#pragma unroll
                    for (int r = 0; r < 4; ++r) o[r] = f2bf(acc[mf][nf][r] + bv);
                    const int b_ = gm >> 8, s0 = gm & 255;
                    const int h_ = col >> 6, dh = col & 63;
                    *(u16x4*)((ushortT*)Cv + 2 * (size_t)TOKENS * H +
                              (((size_t)(b_ * NHD + h_) * DH + dh) << 8) + s0) = o;
                }
            } else {
                ushortT* Ch = (ushortT*)Cv;
#pragma unroll
                for (int r = 0; r < 4; ++r)
                    Ch[(size_t)(gm + r) * ldc + gn] = f2bf(acc[mf][nf][r] + bv);
            }
        }
    }
}

// ---------------- bf16 MFMA GEMM, 3-buffer counted-vmcnt pipeline ----------------
// Used for attention: scores (MODE 6) and PV (MODE 10 -> fp8 ctx).
// MODE: 6 fused mask+softmax | 10 no bias, fp8 out
template<int WM, int WN, int MODE>
__global__ __launch_bounds__(256) void gemm_mfma(
    const ushortT* __restrict__ A, int lda, long long sAo, long long sAi,
    const ushortT* __restrict__ Bt, int ldb, long long sBo, long long sBi,
    const float* __restrict__ bias,
    void* __restrict__ Cv, int ldc, long long sCo, long long sCi,
    int K, int innerN)
{
    constexpr int BM = WM * 64, BN = WN * 64;
    __shared__ __align__(16) ushortT As[3][BM * 32];
    __shared__ __align__(16) ushortT Bs[3][BN * 32];
    const int tid = threadIdx.x;
    const int wave = tid >> 6, lane = tid & 63;
    const int ob = blockIdx.z / innerN, ib = blockIdx.z - ob * innerN;

    const int bm = blockIdx.y * BM, bn = blockIdx.x * BN;
    const ushortT* Ab = A + ob * sAo + ib * sAi + (size_t)bm * lda;
    const ushortT* Bb = Bt + ob * sBo + ib * sBi + (size_t)bn * ldb;
    const int wm = wave / WN, wn = wave - wm * WN;

    const int lrow = lane >> 2;
    const int lsw16 = ((lane & 3) ^ ((lrow >> 1) & 3)) * 8;
    const int rl = lane & 15;
    const int kg4 = (lane >> 4) << 2;
    const int ksw = ((lane >> 4) ^ ((rl >> 1) & 3)) << 3;

    f32x4 acc[4][4];
#pragma unroll
    for (int i = 0; i < 4; ++i)
#pragma unroll
        for (int j = 0; j < 4; ++j) acc[i][j] = (f32x4){0.f, 0.f, 0.f, 0.f};

    auto stage = [&](int buf, int k0) {
#pragma unroll
        for (int j = 0; j < WM; ++j) {
            int chunk = j * 4 + wave;
            gload_lds16(Ab + (size_t)(chunk * 16 + lrow) * lda + k0 + lsw16,
                        &As[buf][chunk * 512]);
        }
#pragma unroll
        for (int j = 0; j < WN; ++j) {
            int chunk = j * 4 + wave;
            gload_lds16(Bb + (size_t)(chunk * 16 + lrow) * ldb + k0 + lsw16,
                        &Bs[buf][chunk * 512]);
        }
    };

    const int nt = K >> 5;
    stage(0, 0);
    stage(1, ((nt > 1) ? 1 : 0) << 5);
    int cur = 0;
    for (int t = 0; t < nt; ++t) {
        if constexpr (WM + WN == 4)
            asm volatile("s_waitcnt vmcnt(4)" ::: "memory");
        else
            asm volatile("s_waitcnt vmcnt(5)" ::: "memory");
        __builtin_amdgcn_s_barrier();
        __builtin_amdgcn_sched_barrier(0);
        u32x4 a[4], b[4];
#pragma unroll
        for (int mf = 0; mf < 4; ++mf)
            a[mf] = *(const u32x4*)&As[cur][(wm * 64 + mf * 16 + rl) * 32 + ksw];
#pragma unroll
        for (int nf = 0; nf < 4; ++nf)
            b[nf] = *(const u32x4*)&Bs[cur][(wn * 64 + nf * 16 + rl) * 32 + ksw];
        {
            const int nx = (t + 2 < nt) ? t + 2 : nt - 1;
            int nb = cur + 2; if (nb >= 3) nb -= 3;
            stage(nb, nx << 5);
        }
#pragma unroll
        for (int mf = 0; mf < 4; ++mf)
#pragma unroll
            for (int nf = 0; nf < 4; ++nf)
                acc[mf][nf] = mfma16(a[mf], b[nf], acc[mf][nf]);
        cur = (cur + 1 == 3) ? 0 : cur + 1;
    }
    asm volatile("s_waitcnt vmcnt(0)" ::: "memory");

    if constexpr (MODE == 6) {
        ushortT* Ch = (ushortT*)Cv + ob * sCo + ib * sCi;
        __shared__ float red6[2][4][64];
        const int* mrow = (const int*)bias + ob * S;
        float mb[4];
#pragma unroll
        for (int nf = 0; nf < 4; ++nf)
            mb[nf] = mrow[bn + wn * 64 + nf * 16 + rl] ? 0.f : -8e9f;
        float pm[4][4];
#pragma unroll
        for (int mf = 0; mf < 4; ++mf)
#pragma unroll
            for (int r = 0; r < 4; ++r) pm[mf][r] = -1e30f;
#pragma unroll
        for (int mf = 0; mf < 4; ++mf)
#pragma unroll
            for (int nf = 0; nf < 4; ++nf)
#pragma unroll
                for (int r = 0; r < 4; ++r) {
                    acc[mf][nf][r] += mb[nf];
                    pm[mf][r] = fmaxf(pm[mf][r], acc[mf][nf][r]);
                }
#pragma unroll
        for (int mf = 0; mf < 4; ++mf)
#pragma unroll
            for (int r = 0; r < 4; ++r) {
                float v = pm[mf][r];
                v = fmaxf(v, __shfl_xor(v, 1));
                v = fmaxf(v, __shfl_xor(v, 2));
                v = fmaxf(v, __shfl_xor(v, 4));
                v = fmaxf(v, __shfl_xor(v, 8));
                pm[mf][r] = v;
            }
        if (rl == 0) {
#pragma unroll
            for (int mf = 0; mf < 4; ++mf)
#pragma unroll
                for (int r = 0; r < 4; ++r)
                    red6[0][wn][mf * 16 + kg4 + r] = pm[mf][r];
        }
        __syncthreads();
        float Mx[4][4];
#pragma unroll
        for (int mf = 0; mf < 4; ++mf)
#pragma unroll
            for (int r = 0; r < 4; ++r) {
                const int row = mf * 16 + kg4 + r;
                Mx[mf][r] = fmaxf(fmaxf(red6[0][0][row], red6[0][1][row]),
                                  fmaxf(red6[0][2][row], red6[0][3][row]));
            }
        float ps[4][4];
#pragma unroll
        for (int mf = 0; mf < 4; ++mf)
#pragma unroll
            for (int r = 0; r < 4; ++r) ps[mf][r] = 0.f;
#pragma unroll
        for (int mf = 0; mf < 4; ++mf)
#pragma unroll
            for (int nf = 0; nf < 4; ++nf)
#pragma unroll
                for (int r = 0; r < 4; ++r) {
                    float e = exp2i(C2 * (acc[mf][nf][r] - Mx[mf][r]));
                    acc[mf][nf][r] = e;
                    ps[mf][r] += e;
                }
#pragma unroll
        for (int mf = 0; mf < 4; ++mf)
#pragma unroll
            for (int r = 0; r < 4; ++r) {
                float v = ps[mf][r];
                v += __shfl_xor(v, 1);
                v += __shfl_xor(v, 2);
                v += __shfl_xor(v, 4);
                v += __shfl_xor(v, 8);
                ps[mf][r] = v;
            }
        if (rl == 0) {
#pragma unroll
            for (int mf = 0; mf < 4; ++mf)
#pragma unroll
                for (int r = 0; r < 4; ++r)
                    red6[1][wn][mf * 16 + kg4 + r] = ps[mf][r];
        }
        __syncthreads();
#pragma unroll
        for (int mf = 0; mf < 4; ++mf) {
            float inv[4];
#pragma unroll
            for (int r = 0; r < 4; ++r) {
                const int row = mf * 16 + kg4 + r;
                inv[r] = 1.0f / (red6[1][0][row] + red6[1][1][row] +
                                 red6[1][2][row] + red6[1][3][row]);
            }
#pragma unroll
            for (int nf = 0; nf < 4; ++nf) {
                const int gn = bn + wn * 64 + nf * 16 + rl;
                const int gm = bm + mf * 16 + kg4;
#pragma unroll
                for (int r = 0; r < 4; ++r)
                    Ch[(size_t)(gm + r) * ldc + gn] = f2bf(acc[mf][nf][r] * inv[r]);
            }
        }
    } else {   // MODE 10: no bias, fp8 out (PV -> ctx8)
        u8* C8 = (u8*)Cv + ob * sCo + ib * sCi;
#pragma unroll
        for (int nf = 0; nf < 4; ++nf) {
            int gn = bn + wn * 64 + nf * 16 + rl;
#pragma unroll
            for (int mf = 0; mf < 4; ++mf) {
                int gm = bm + wm * 64 + mf * 16 + kg4;
#pragma unroll
                for (int r = 0; r < 4; ++r)
                    C8[(size_t)(gm + r) * ldc + gn] = f2fp8(acc[mf][nf][r]);
            }
        }
    }
}

// ---------------- all 6 weight transposes of one layer -> fp8 ----------------
__global__ __launch_bounds__(256) void transpose_all_k(
    const float* __restrict__ Wq, const float* __restrict__ Wk,
    const float* __restrict__ Wv, const float* __restrict__ Wo,
    const float* __restrict__ W1, const float* __restrict__ W2,
    u8* __restrict__ wtqkv8, u8* __restrict__ wto8,
    u8* __restrict__ wt1, u8* __restrict__ wt2)
{
    int idx = blockIdx.x;
    const float* W; int R, C, tr, tc; u8* WT8;
    if (idx < 2304) {
        int mat = idx / 576, t = idx - mat * 576;
        tr = t / 24; tc = t - tr * 24; R = 768; C = 768;
        W = mat == 0 ? Wq : mat == 1 ? Wk : mat == 2 ? Wv : Wo;
        WT8 = mat < 3 ? wtqkv8 + (size_t)mat * 768 * 768 : wto8;
    } else if (idx < 4608) {
        int t = idx - 2304; tr = t / 96; tc = t - tr * 96;
        R = 768; C = 3072; W = W1; WT8 = wt1;
    } else {
        int t = idx - 4608; tr = t / 24; tc = t - tr * 24;
        R = 3072; C = 768; W = W2; WT8 = wt2;
    }
    int r0 = tr * 32, c0 = tc * 32;
    __shared__ float tl[32][33];
    int trd = threadIdx.x >> 3;
    int tc4 = (threadIdx.x & 7) * 4;
    const float4 v = *(const float4*)(W + (size_t)(r0 + trd) * C + c0 + tc4);
    tl[trd][tc4 + 0] = v.x; tl[trd][tc4 + 1] = v.y;
    tl[trd][tc4 + 2] = v.z; tl[trd][tc4 + 3] = v.w;
    __syncthreads();
    unsigned p = f2fp8x4(tl[tc4 + 0][trd], tl[tc4 + 1][trd],
                         tl[tc4 + 2][trd], tl[tc4 + 3][trd]);
    *(unsigned*)(WT8 + (size_t)(c0 + trd) * R + r0 + tc4) = p;
}

// ---------------- pack qkv biases -> [NLAY][2304] ----------------
__global__ __launch_bounds__(256) void pack_bias_k(
    const float* __restrict__ bq, const float* __restrict__ bk,
    const float* __restrict__ bv, float* __restrict__ out)
{
    int l = blockIdx.x / 3, r = blockIdx.x - (blockIdx.x / 3) * 3;
    const float* src = r == 0 ? bq : r == 1 ? bk : bv;
#pragma unroll
    for (int j = 0; j < 3; ++j) {
        int d = threadIdx.x + 256 * j;
        out[(size_t)l * QKVN + r * H + d] = src[(size_t)l * H + d];
    }
}

// ---------------- embeddings + LN -> bf16 h + fp8 copy; 4 tokens/block ----------------
__global__ __launch_bounds__(256) void embed_ln_k(
    const int* __restrict__ ids, const int* __restrict__ tts,
    const float* __restrict__ wemb, const float* __restrict__ pemb,
    const float* __restrict__ temb, const float* __restrict__ g,
    const float* __restrict__ bp, ushortT* __restrict__ hb, u8* __restrict__ h8)
{
    const int tok = blockIdx.x * 4 + (threadIdx.x >> 6);
    const int lane = threadIdx.x & 63;
    const int d0 = lane * 12;
    const int spos = tok & (S - 1);
    const int id = ids[tok], tt = tts[tok];
    const float* wr = wemb + (size_t)id * H + d0;
    const float* pr = pemb + (size_t)spos * H + d0;
    const float* tr = temb + (size_t)tt * H + d0;
    float x[12]; float s = 0.f, ss = 0.f;
#pragma unroll
    for (int j = 0; j < 3; ++j) {
        float4 a = *(const float4*)(wr + j * 4);
        float4 b = *(const float4*)(pr + j * 4);
        float4 c = *(const float4*)(tr + j * 4);
        float v0 = a.x + b.x + c.x, v1 = a.y + b.y + c.y;
        float v2 = a.z + b.z + c.z, v3 = a.w + b.w + c.w;
        x[j*4+0] = v0; x[j*4+1] = v1; x[j*4+2] = v2; x[j*4+3] = v3;
        s += v0 + v1 + v2 + v3;
        ss += v0*v0 + v1*v1 + v2*v2 + v3*v3;
    }
#pragma unroll
    for (int m = 32; m; m >>= 1) { s += __shfl_xor(s, m); ss += __shfl_xor(ss, m); }
    float mu = s * (1.f / H);
    float var = ss * (1.f / H) - mu * mu;
    float rs = rsqrtf(var + 1e-12f);
#pragma unroll
    for (int j = 0; j < 3; ++j) {
        float4 gv = *(const float4*)(g + d0 + j * 4);
        float4 bv = *(const float4*)(bp + d0 + j * 4);
        float y0 = (x[j*4+0] - mu) * rs * gv.x + bv.x;
        float y1 = (x[j*4+1] - mu) * rs * gv.y + bv.y;
        float y2 = (x[j*4+2] - mu) * rs * gv.z + bv.z;
        float y3 = (x[j*4+3] - mu) * rs * gv.w + bv.w;
        u16x4 o;
        o[0] = f2bf(y0); o[1] = f2bf(y1); o[2] = f2bf(y2); o[3] = f2bf(y3);
        *(u16x4*)(hb + (size_t)tok * H + d0 + j * 4) = o;
        *(unsigned*)(h8 + (size_t)tok * H + d0 + j * 4) = f2fp8x4(y0, y1, y2, y3);
    }
}

// ---------------- bf16 residual add + LN, in place on hb; emits fp8 copy ----------------
__global__ __launch_bounds__(256) void add_ln_k(
    ushortT* __restrict__ hb, const ushortT* __restrict__ add,
    const float* __restrict__ g, const float* __restrict__ bp,
    u8* __restrict__ h8)
{
    const int tok = blockIdx.x * 4 + (threadIdx.x >> 6);
    const int lane = threadIdx.x & 63;
    const int d0 = lane * 12;
    const size_t base = (size_t)tok * H + d0;
    float x[12]; float s = 0.f, ss = 0.f;
#pragma unroll
    for (int j = 0; j < 3; ++j) {
        u16x4 hv = *(const u16x4*)(hb + base + j * 4);
        u16x4 av = *(const u16x4*)(add + base + j * 4);
#pragma unroll
        for (int q = 0; q < 4; ++q) {
            float v = bf2f(hv[q]) + bf2f(av[q]);
            x[j*4+q] = v; s += v; ss += v * v;
        }
    }
#pragma unroll
    for (int m = 32; m; m >>= 1) { s += __shfl_xor(s, m); ss += __shfl_xor(ss, m); }
    float mu = s * (1.f / H);
    float var = ss * (1.f / H) - mu * mu;
    float rs = rsqrtf(var + 1e-12f);
#pragma unroll
    for (int j = 0; j < 3; ++j) {
        float4 gv = *(const float4*)(g + d0 + j * 4);
        float4 bv = *(const float4*)(bp + d0 + j * 4);
        float y0 = (x[j*4+0] - mu) * rs * gv.x + bv.x;
        float y1 = (x[j*4+1] - mu) * rs * gv.y + bv.y;
        float y2 = (x[j*4+2] - mu) * rs * gv.z + bv.z;
        float y3 = (x[j*4+3] - mu) * rs * gv.w + bv.w;
        u16x4 o;
        o[0] = f2bf(y0); o[1] = f2bf(y1); o[2] = f2bf(y2); o[3] = f2bf(y3);
        *(u16x4*)(hb + base + j * 4) = o;
        *(unsigned*)(h8 + base + j * 4) = f2fp8x4(y0, y1, y2, y3);
    }
}

// ---------------- logits + log_softmax over 9 labels (bf16 h, f32 math) ----------------
__global__ __launch_bounds__(256) void logits_k(
    const ushortT* __restrict__ hb, const float* __restrict__ fcw,
    float* __restrict__ em)
{
    int tok = blockIdx.x, tid = threadIdx.x;
    float p[LBL];
#pragma unroll
    for (int l = 0; l < LBL; ++l) p[l] = 0.f;
    const ushortT* hr = hb + (size_t)tok * H;
#pragma unroll
    for (int j = 0; j < 3; ++j) {
        int d = tid + 256 * j;
        float hv = bf2f(hr[d]);
        const float* fr = fcw + (size_t)d * LBL;
#pragma unroll
        for (int l = 0; l < LBL; ++l) p[l] = fmaf(hv, fr[l], p[l]);
    }
    __shared__ float ls[4][LBL];
    __shared__ float lg[LBL];
    __shared__ float lse;
#pragma unroll
    for (int l = 0; l < LBL; ++l) {
        float v = p[l];
#pragma unroll
        for (int m = 32; m; m >>= 1) v += __shfl_xor(v, m);
        if ((tid & 63) == 0) ls[tid >> 6][l] = v;
    }
    __syncthreads();
    if (tid < LBL) lg[tid] = ls[0][tid] + ls[1][tid] + ls[2][tid] + ls[3][tid];
    __syncthreads();
    if (tid == 0) {
        float mx = lg[0];
#pragma unroll
        for (int j = 1; j < LBL; ++j) mx = fmaxf(mx, lg[j]);
        float sm = 0.f;
#pragma unroll
        for (int j = 0; j < LBL; ++j) sm += expf(lg[j] - mx);
        lse = mx + logf(sm);
    }
    __syncthreads();
    if (tid < LBL) em[(size_t)tok * LBL + tid] = lg[tid] - lse;
}

// ---------------- CRF: one wave per batch elem, base-2 fast recursion ----------------
__global__ __launch_bounds__(64) void crf_k(
    const float* __restrict__ em, const int* __restrict__ tags,
    const int* __restrict__ mask, const float* __restrict__ sp,
    const float* __restrict__ ep, const float* __restrict__ trans,
    float* __restrict__ partial)
{
    constexpr float LOG2E = 1.4426950408889634f;
    constexpr float LN2   = 0.6931471805599453f;
    int b = blockIdx.x, t = threadIdx.x;
    __shared__ float eml[S * LBL];     // emissions * log2(e)
    __shared__ int mkl[S];
    const float* emb = em + (size_t)b * S * LBL;
    const int* tg = tags + (size_t)b * S;
    const int* mk = mask + (size_t)b * S;

    for (int i = t * 4; i < S * LBL; i += 256) {
        float4 v = *(const float4*)&emb[i];
        v.x *= LOG2E; v.y *= LOG2E; v.z *= LOG2E; v.w *= LOG2E;
        *(float4*)&eml[i] = v;
    }
    *(i32x4*)&mkl[t * 4] = *(const i32x4*)&mk[t * 4];

    int cnt = 0; float ns = 0.f;
    for (int i = t; i < S; i += 64) {
        int m = mk[i];
        cnt += (m != 0);
        if (i >= 1 && m)
            ns += trans[tg[i - 1] * LBL + tg[i]] + emb[(size_t)i * LBL + tg[i]];
    }
#pragma unroll
    for (int m = 32; m; m >>= 1) { cnt += __shfl_xor(cnt, m); ns += __shfl_xor(ns, m); }
    float num = ns + sp[tg[0]] + emb[tg[0]] + ep[tg[cnt - 1]];

    int tt = t < LBL ? t : 0;
    float trc2[LBL];
#pragma unroll
    for (int i = 0; i < LBL; ++i) trc2[i] = trans[i * LBL + tt] * LOG2E;

    __syncthreads();

    float alpha2 = (t < LBL) ? sp[t] * LOG2E + eml[t] : -1e30f;
    for (int step = 1; step < S; ++step) {
        float av[LBL];
#pragma unroll
        for (int i = 0; i < LBL; ++i) av[i] = __shfl(alpha2, i) + trc2[i];
        float mx = av[0];
#pragma unroll
        for (int i = 1; i < LBL; ++i) mx = fmaxf(mx, av[i]);
        float sm = 0.f;
#pragma unroll
        for (int i = 0; i < LBL; ++i) sm += exp2i(av[i] - mx);
        float na = mx + log2i(sm) + eml[step * LBL + tt];
        alpha2 = (mkl[step] && t < LBL) ? na : alpha2;
    }
    float z = (t < LBL) ? alpha2 + ep[t] * LOG2E : -1e30f;
    float mx = z;
#pragma unroll
    for (int m = 8; m; m >>= 1) mx = fmaxf(mx, __shfl_xor(mx, m));
    float sm = exp2i(z - mx);
#pragma unroll
    for (int m = 8; m; m >>= 1) sm += __shfl_xor(sm, m);
    if (t == 0) partial[b] = (mx + log2i(sm)) * LN2 - num;
}

__global__ void finalize_k(const float* __restrict__ partial, float* __restrict__ out) {
    float s = 0.f;
    for (int i = 0; i < BATCH; ++i) s += partial[i];
    out[0] = s;
}

__global__ void sentinel_k(float* out) { out[0] = -12345.0f; }

extern "C" void kernel_launch(void* const* d_in, const int* in_sizes, int n_in,
                              void* d_out, int out_size, void* d_ws, size_t ws_size,
                              hipStream_t stream) {
    (void)in_sizes; (void)n_in; (void)out_size;
    const int* token_ids  = (const int*)d_in[0];
    const int* token_type = (const int*)d_in[1];
    const int* amask      = (const int*)d_in[2];
    const int* y          = (const int*)d_in[3];
    const float* wemb = (const float*)d_in[4];
    const float* pemb = (const float*)d_in[5];
    const float* temb = (const float*)d_in[6];
    const float* eg   = (const float*)d_in[7];
    const float* eb   = (const float*)d_in[8];
    const float* Wq = (const float*)d_in[9];
    const float* bq = (const float*)d_in[10];
    const float* Wk = (const float*)d_in[11];
    const float* bk = (const float*)d_in[12];
    const float* Wv = (const float*)d_in[13];
    const float* bv = (const float*)d_in[14];
    const float* Wo = (const float*)d_in[15];
    const float* bo = (const float*)d_in[16];
    const float* ln1g = (const float*)d_in[17];
    const float* ln1b = (const float*)d_in[18];
    const float* W1 = (const float*)d_in[19];
    const float* b1 = (const float*)d_in[20];
    const float* W2 = (const float*)d_in[21];
    const float* b2 = (const float*)d_in[22];
    const float* ln2g = (const float*)d_in[23];
    const float* ln2b = (const float*)d_in[24];
    const float* fcw = (const float*)d_in[25];
    const float* crf_s = (const float*)d_in[26];
    const float* crf_e = (const float*)d_in[27];
    const float* crf_t = (const float*)d_in[28];

    if (ws_size < WS_FLOATS * sizeof(float)) {
        sentinel_k<<<1, 1, 0, stream>>>((float*)d_out);
        return;
    }

    float* ws = (float*)d_ws;
    ushortT* hb    = (ushortT*)(ws + HB_OFF);
    ushortT* qb    = (ushortT*)(ws + QB_OFF);  // q base; k = +TOKENS*H; vt = +2*TOKENS*H
    ushortT* kb    = (ushortT*)(ws + KB_OFF);
    ushortT* vt    = (ushortT*)(ws + VT_OFF);
    ushortT* big   = (ushortT*)(ws + BIG_OFF); // probs bf16; also ff1 fp8 (aliased)
    u8*      big8  = (u8*)(ws + BIG_OFF);
    u8*      wtq8  = (u8*)(ws + WTQ_OFF);      // [2304][768] fp8
    u8*      wto8  = (u8*)(ws + WTO_OFF);      // [768][768] fp8
    u8*      wt1   = (u8*)(ws + WT1_OFF);      // [3072][768] fp8
    u8*      wt2   = (u8*)(ws + WT2_OFF);      // [768][3072] fp8
    float*   embuf = ws + EM_OFF;
    float*   part  = ws + PART_OFF;
    float*   bqkv  = ws + BQKV_OFF;
    u8*      h8    = (u8*)(ws + H8_OFF);       // [8192][768] fp8
    u8*      ctx8  = (u8*)(ws + CT8_OFF);      // [8192][768] fp8 (per-head interleaved)

    pack_bias_k<<<NLAY * 3, 256, 0, stream>>>(bq, bk, bv, bqkv);
    embed_ln_k<<<TOKENS / 4, 256, 0, stream>>>(token_ids, token_type, wemb, pemb,
                                               temb, eg, eb, hb, h8);

    constexpr long long HH = (long long)H * H;
    constexpr long long HF = (long long)H * FF;
    constexpr long long TOKH = (long long)S * H;        // 196608
    constexpr long long ATT_B = (long long)NHD * S * S; // 786432
    constexpr long long ATT_H = (long long)S * S;       // 65536
    constexpr long long VT_B = (long long)NHD * DH * S; // 196608
    constexpr long long VT_H = (long long)DH * S;       // 16384

    dim3 gQKV(QKVN / 128, TOKENS / 128, 1);       // 18 x 64 = 1152 (%8==0)
    dim3 gProj(H / 128, TOKENS / 128, 1);         // 6 x 64 = 384
    dim3 gFF1(FF / 128, TOKENS / 128, 1);         // 24 x 64 = 1536
    dim3 gScores(1, S / 64, BATCH * NHD);         // 1 x 4 x 384
    dim3 gPV(1, 1, BATCH * NHD);                  // 256x64 tile covers head

    for (int l = 0; l < NLAY; ++l) {
        transpose_all_k<<<6912, 256, 0, stream>>>(
            Wq + l * HH, Wk + l * HH, Wv + l * HH, Wo + l * HH,
            W1 + l * HF, W2 + l * HF, wtq8, wto8, wt1, wt2);

        // fused q,k,v projections (FP8 GEMM, routing epilogue -> bf16 q/k/v^T)
        gemm_fp8<9><<<gQKV, 256, 0, stream>>>(
            h8, H, wtq8, H, bqkv + (size_t)l * QKVN, qb, H, H);

        // probs = softmax(mask(q @ k^T)) per (b,h), fused epilogue -> bf16
        gemm_mfma<1,4,6><<<gScores, 256, 0, stream>>>(
            qb, H, TOKH, DH, kb, H, TOKH, DH, (const float*)amask,
            big, S, ATT_B, ATT_H, DH, NHD);

        // ctx = probs @ v  (per b,h) -> ctx8 fp8 as [B,S,NH,DH]
        gemm_mfma<4,1,10><<<gPV, 256, 0, stream>>>(
            big, S, ATT_B, ATT_H, vt, S, VT_B, VT_H, nullptr,
            ctx8, H, TOKH, DH, S, NHD);

        // attention output projection (FP8 GEMM) -> kb bf16
        gemm_fp8<8><<<gProj, 256, 0, stream>>>(
            ctx8, H, wto8, H, bo + l * H, kb, H, H);

        add_ln_k<<<TOKENS / 4, 256, 0, stream>>>(hb, kb, ln1g + l * H, ln1b + l * H, h8);

        // ff1 = gelu(h @ W1 + b1) -> big8 fp8  (FP8 GEMM, K=768)
        gemm_fp8<7><<<gFF1, 256, 0, stream>>>(
            h8, H, wt1, H, b1 + (long long)l * FF, big8, FF, H);

        // ff2 = big8 @ W2 + b2 -> qb bf16  (FP8 GEMM, K=3072)
        gemm_fp8<8><<<gProj, 256, 0, stream>>>(
            big8, FF, wt2, FF, b2 + l * H, qb, H, FF);

        add_ln_k<<<TOKENS / 4, 256, 0, stream>>>(hb, qb, ln2g + l * H, ln2b + l * H, h8);
    }

    logits_k<<<TOKENS, 256, 0, stream>>>(hb, fcw, embuf);
    crf_k<<<BATCH, 64, 0, stream>>>(embuf, y, amask, crf_s, crf_e, crf_t, part);
    finalize_k<<<1, 1, 0, stream>>>(part, (float*)d_out);
}

// Round 17
// 2535.393 us; speedup vs baseline: 1.6976x; 1.0197x over previous
//
#include <hip/hip_runtime.h>
#include <math.h>

typedef unsigned short ushortT;
typedef unsigned char u8;
typedef __attribute__((ext_vector_type(4))) float f32x4;
typedef __attribute__((ext_vector_type(4))) unsigned int u32x4;
typedef __attribute__((ext_vector_type(4))) unsigned short u16x4;
typedef __attribute__((ext_vector_type(4))) int i32x4;

namespace {
constexpr int S = 256;
constexpr int H = 768;
constexpr int NLAY = 12;
constexpr int NHD = 12;
constexpr int FF = 3072;
constexpr int LBL = 9;
constexpr int DH = 64;
constexpr int BATCH = 32;
constexpr int TOKENS = BATCH * S;      // 8192
constexpr int QKVN = 3 * H;            // 2304
// softmax scale folded into exponent: p = exp2(C2*(s_raw - m_raw)), C2 = 0.125*log2(e)
constexpr float C2 = 0.18033688011112042f;

// workspace layout (float-slot units)
constexpr size_t HB_OFF  = 0;                            // h bf16 [8192][768]
constexpr size_t OB_OFF  = HB_OFF + (size_t)TOKENS*H/2;  // bf16 scratch (attn-out / ff2-out)
constexpr size_t Q8_OFF  = OB_OFF + (size_t)TOKENS*H/2;  // fp8 q; k at +TH bytes; v^T at +2TH
constexpr size_t BIG_OFF = Q8_OFF + 3*(size_t)TOKENS*H/4; // probs fp8 [B,NH,S,S] == ff1 fp8
constexpr size_t WTQ_OFF = BIG_OFF + (size_t)TOKENS*FF/4; // Wq^T,Wk^T,Wv^T fp8 [2304][768]
constexpr size_t WTO_OFF = WTQ_OFF + 3*(size_t)H*H/4;    // Wo^T fp8
constexpr size_t WT1_OFF = WTO_OFF + (size_t)H*H/4;      // W1^T fp8 [3072][768]
constexpr size_t WT2_OFF = WT1_OFF + (size_t)H*FF/4;     // W2^T fp8 [768][3072]
constexpr size_t EM_OFF  = WT2_OFF + (size_t)H*FF/4;
constexpr size_t PART_OFF= EM_OFF + (size_t)TOKENS*LBL;
constexpr size_t BQKV_OFF= PART_OFF + 64;                // packed qkv bias [12][2304]
constexpr size_t H8_OFF  = BQKV_OFF + (size_t)NLAY*QKVN; // h fp8 copy
constexpr size_t CT8_OFF = H8_OFF + (size_t)TOKENS*H/4;  // ctx fp8 [8192][768]
constexpr size_t WS_FLOATS = CT8_OFF + (size_t)TOKENS*H/4;
}

__device__ __forceinline__ ushortT f2bf(float x) {
    unsigned u = __builtin_bit_cast(unsigned, x);
    u += 0x7fffu + ((u >> 16) & 1u);
    return (ushortT)(u >> 16);
}
__device__ __forceinline__ float bf2f(ushortT h) {
    unsigned u = ((unsigned)h) << 16;
    return __builtin_bit_cast(float, u);
}
__device__ __forceinline__ u8 f2fp8(float x) {
    return (u8)(__builtin_amdgcn_cvt_pk_fp8_f32(x, x, 0, false) & 0xff);
}
__device__ __forceinline__ unsigned f2fp8x4(float a, float b, float c, float d) {
    int p = __builtin_amdgcn_cvt_pk_fp8_f32(a, b, 0, false);
    p = __builtin_amdgcn_cvt_pk_fp8_f32(c, d, p, true);
    return (unsigned)p;
}

__device__ __forceinline__ float exp2i(float x) {
    float r; asm("v_exp_f32 %0, %1" : "=v"(r) : "v"(x)); return r;
}
__device__ __forceinline__ float log2i(float x) {
    float r; asm("v_log_f32 %0, %1" : "=v"(r) : "v"(x)); return r;
}

// tanh-gelu in sigmoid form: 0.5x(1+tanh(u)) == x*sigmoid(2u) == x/(1+exp2(-2u*log2e))
__device__ __forceinline__ float gelu_tanh(float x) {
    float u = 0.7978845608028654f * (x + 0.044715f * x * x * x);
    float t = exp2i(-2.8853900817779268f * u);
    return x / (1.0f + t);
}

__device__ __forceinline__ void gload_lds16b(const u8* g, u8* l) {
    __builtin_amdgcn_global_load_lds(
        (const __attribute__((address_space(1))) unsigned int*)g,
        (__attribute__((address_space(3))) unsigned int*)l,
        16, 0, 0);
}

// =====================================================================
// Unified FP8 e4m3 MFMA GEMM: BM=WM*64 x BN=WN*64 (WM*WN==4 waves of 64x64),
// K-step 64, 64B LDS rows, (row>>1)&3 16B-chunk both-sides swizzle,
// 3-buffer counted-vmcnt pipeline (stage group = WM+WN loads/thread ->
// vmcnt(WM+WN) certifies tile t with one group outstanding; tail re-stages
// keep the FIFO exact). 32 MFMAs/iter at bf16 MFMA rate with HALF the LDS
// bytes per FLOP (the measured binding resource).
// MODE: 6  = fused mask+row-softmax -> fp8 probs (WM=1,WN=4; BN==256==S;
//            `bias` carries the int mask pointer; ob indexes batch)
//       7  = bias+gelu -> fp8 (FF1)
//       8  = bias -> bf16 (Wo/FF2)
//       9  = fused-QKV routing -> fp8 q/k/v^T (Cv = q8; k8 +TH; vt8 +2TH bytes)
//       10 = no bias -> fp8 (PV -> ctx8)
// 2D grids (gridDim.z==1) get the XCD-aware block swizzle; grids are %8==0.
// =====================================================================
template<int WM, int WN, int MODE>
__global__ __launch_bounds__(256) void gemm_fp8b(
    const u8* __restrict__ A, int lda, long long sAo, long long sAi,
    const u8* __restrict__ Bt, int ldb, long long sBo, long long sBi,
    const float* __restrict__ bias,
    void* __restrict__ Cv, int ldc, long long sCo, long long sCi,
    int K, int innerN)
{
    constexpr int BM = WM * 64, BN = WN * 64;
    __shared__ __align__(16) u8 As[3][BM * 64];
    __shared__ __align__(16) u8 Bs[3][BN * 64];
    const int tid = threadIdx.x;
    const int wave = tid >> 6, lane = tid & 63;
    const int ob = blockIdx.z / innerN, ib = blockIdx.z - ob * innerN;

    int bxi = blockIdx.x, byi = blockIdx.y;
    if (gridDim.z == 1) {
        const int nwg = gridDim.x * gridDim.y;
        const int lin = byi * gridDim.x + bxi;
        const int cpx = nwg >> 3;
        const int sw = (lin & 7) * cpx + (lin >> 3);
        byi = sw / gridDim.x; bxi = sw - byi * gridDim.x;
    }
    const int bm = byi * BM, bn = bxi * BN;
    const u8* Ab = A + ob * sAo + ib * sAi + (size_t)bm * lda;
    const u8* Bb = Bt + ob * sBo + ib * sBi + (size_t)bn * ldb;
    const int wm = wave / WN, wn = wave - wm * WN;

    const int lrow = lane >> 2;                              // row within 16-row chunk
    const int lswb = ((lane & 3) ^ ((lrow >> 1) & 3)) * 16;  // swizzled SRC byte off
    const int rl = lane & 15;
    const int kg = lane >> 4;                                // 0..3
    const int kg4 = kg << 2;
    const int key = (rl >> 1) & 3;                           // read-side swizzle key
    const int kgh = kg >> 1, kgl8 = (kg & 1) * 8;

    f32x4 acc[4][4];
#pragma unroll
    for (int i = 0; i < 4; ++i)
#pragma unroll
        for (int j = 0; j < 4; ++j) acc[i][j] = (f32x4){0.f, 0.f, 0.f, 0.f};

    auto stage = [&](int buf, int kt) {
#pragma unroll
        for (int j = 0; j < WM; ++j) {
            int chunk = j * 4 + wave;
            gload_lds16b(Ab + (size_t)(chunk * 16 + lrow) * lda + kt * 64 + lswb,
                         &As[buf][chunk * 1024]);
        }
#pragma unroll
        for (int j = 0; j < WN; ++j) {
            int chunk = j * 4 + wave;
            gload_lds16b(Bb + (size_t)(chunk * 16 + lrow) * ldb + kt * 64 + lswb,
                         &Bs[buf][chunk * 1024]);
        }
    };

    const int nt = K >> 6;
    stage(0, 0);
    stage(1, (nt > 1) ? 1 : 0);
    int cur = 0;
    for (int t = 0; t < nt; ++t) {
        if constexpr (WM + WN == 4)
            asm volatile("s_waitcnt vmcnt(4)" ::: "memory");
        else
            asm volatile("s_waitcnt vmcnt(5)" ::: "memory");
        __builtin_amdgcn_s_barrier();
        __builtin_amdgcn_sched_barrier(0);
#pragma unroll
        for (int ks = 0; ks < 2; ++ks) {
            long a[4], b[4];
#pragma unroll
            for (int mf = 0; mf < 4; ++mf)
                a[mf] = *(const long*)&As[cur][(wm * 64 + mf * 16 + rl) * 64 +
                                               (((ks * 2 + kgh) ^ key) << 4) + kgl8];
#pragma unroll
            for (int nf = 0; nf < 4; ++nf)
                b[nf] = *(const long*)&Bs[cur][(wn * 64 + nf * 16 + rl) * 64 +
                                               (((ks * 2 + kgh) ^ key) << 4) + kgl8];
            if (ks == 0) {   // stage tile t+2 once per iter (keeps FIFO count exact)
                const int nx = (t + 2 < nt) ? t + 2 : nt - 1;
                int nb = cur + 2; if (nb >= 3) nb -= 3;
                stage(nb, nx);
            }
#pragma unroll
            for (int mf = 0; mf < 4; ++mf)
#pragma unroll
                for (int nf = 0; nf < 4; ++nf)
                    acc[mf][nf] = __builtin_amdgcn_mfma_f32_16x16x32_fp8_fp8(
                        a[mf], b[nf], acc[mf][nf], 0, 0, 0);
        }
        cur = (cur + 1 == 3) ? 0 : cur + 1;
    }
    asm volatile("s_waitcnt vmcnt(0)" ::: "memory");

    if constexpr (MODE == 6) {
        // ---- fused mask + row softmax epilogue (WM=1: all waves share rows) ----
        u8* C8 = (u8*)Cv + ob * sCo + ib * sCi;
        __shared__ float red6[2][4][64];
        const int* mrow = (const int*)bias + ob * S;
        float mb[4];
#pragma unroll
        for (int nf = 0; nf < 4; ++nf)
            mb[nf] = mrow[bn + wn * 64 + nf * 16 + rl] ? 0.f : -8e9f;
        float pm[4][4];
#pragma unroll
        for (int mf = 0; mf < 4; ++mf)
#pragma unroll
            for (int r = 0; r < 4; ++r) pm[mf][r] = -1e30f;
#pragma unroll
        for (int mf = 0; mf < 4; ++mf)
#pragma unroll
            for (int nf = 0; nf < 4; ++nf)
#pragma unroll
                for (int r = 0; r < 4; ++r) {
                    acc[mf][nf][r] += mb[nf];
                    pm[mf][r] = fmaxf(pm[mf][r], acc[mf][nf][r]);
                }
#pragma unroll
        for (int mf = 0; mf < 4; ++mf)
#pragma unroll
            for (int r = 0; r < 4; ++r) {
                float v = pm[mf][r];
                v = fmaxf(v, __shfl_xor(v, 1));
                v = fmaxf(v, __shfl_xor(v, 2));
                v = fmaxf(v, __shfl_xor(v, 4));
                v = fmaxf(v, __shfl_xor(v, 8));
                pm[mf][r] = v;
            }
        if (rl == 0) {
#pragma unroll
            for (int mf = 0; mf < 4; ++mf)
#pragma unroll
                for (int r = 0; r < 4; ++r)
                    red6[0][wn][mf * 16 + kg4 + r] = pm[mf][r];
        }
        __syncthreads();
        float Mx[4][4];
#pragma unroll
        for (int mf = 0; mf < 4; ++mf)
#pragma unroll
            for (int r = 0; r < 4; ++r) {
                const int row = mf * 16 + kg4 + r;
                Mx[mf][r] = fmaxf(fmaxf(red6[0][0][row], red6[0][1][row]),
                                  fmaxf(red6[0][2][row], red6[0][3][row]));
            }
        float ps[4][4];
#pragma unroll
        for (int mf = 0; mf < 4; ++mf)
#pragma unroll
            for (int r = 0; r < 4; ++r) ps[mf][r] = 0.f;
#pragma unroll
        for (int mf = 0; mf < 4; ++mf)
#pragma unroll
            for (int nf = 0; nf < 4; ++nf)
#pragma unroll
                for (int r = 0; r < 4; ++r) {
                    float e = exp2i(C2 * (acc[mf][nf][r] - Mx[mf][r]));
                    acc[mf][nf][r] = e;
                    ps[mf][r] += e;
                }
#pragma unroll
        for (int mf = 0; mf < 4; ++mf)
#pragma unroll
            for (int r = 0; r < 4; ++r) {
                float v = ps[mf][r];
                v += __shfl_xor(v, 1);
                v += __shfl_xor(v, 2);
                v += __shfl_xor(v, 4);
                v += __shfl_xor(v, 8);
                ps[mf][r] = v;
            }
        if (rl == 0) {
#pragma unroll
            for (int mf = 0; mf < 4; ++mf)
#pragma unroll
                for (int r = 0; r < 4; ++r)
                    red6[1][wn][mf * 16 + kg4 + r] = ps[mf][r];
        }
        __syncthreads();
#pragma unroll
        for (int mf = 0; mf < 4; ++mf) {
            float inv[4];
#pragma unroll
            for (int r = 0; r < 4; ++r) {
                const int row = mf * 16 + kg4 + r;
                inv[r] = 1.0f / (red6[1][0][row] + red6[1][1][row] +
                                 red6[1][2][row] + red6[1][3][row]);
            }
#pragma unroll
            for (int nf = 0; nf < 4; ++nf) {
                const int gn = bn + wn * 64 + nf * 16 + rl;
                const int gm = bm + mf * 16 + kg4;
#pragma unroll
                for (int r = 0; r < 4; ++r)
                    C8[(size_t)(gm + r) * ldc + gn] = f2fp8(acc[mf][nf][r] * inv[r]);
            }
        }
    } else {
#pragma unroll
        for (int nf = 0; nf < 4; ++nf) {
            const int gn = bn + wn * 64 + nf * 16 + rl;
            float bv = 0.f;
            if constexpr (MODE != 10) bv = bias[gn];
#pragma unroll
            for (int mf = 0; mf < 4; ++mf) {
                const int gm = bm + wm * 64 + mf * 16 + kg4;
                if constexpr (MODE == 7) {
                    u8* C8 = (u8*)Cv;
#pragma unroll
                    for (int r = 0; r < 4; ++r)
                        C8[(size_t)(gm + r) * ldc + gn] =
                            f2fp8(gelu_tanh(acc[mf][nf][r] + bv));
                } else if constexpr (MODE == 8) {
                    ushortT* Ch = (ushortT*)Cv;
#pragma unroll
                    for (int r = 0; r < 4; ++r)
                        Ch[(size_t)(gm + r) * ldc + gn] = f2bf(acc[mf][nf][r] + bv);
                } else if constexpr (MODE == 9) {
                    const int region = gn / H;          // 0=q,1=k,2=v
                    const int col = gn - region * H;
                    if (region < 2) {
                        u8* o = (u8*)Cv + (size_t)region * TOKENS * H;
#pragma unroll
                        for (int r = 0; r < 4; ++r)
                            o[(size_t)(gm + r) * H + col] = f2fp8(acc[mf][nf][r] + bv);
                    } else {
                        const int b_ = gm >> 8, s0 = gm & 255;
                        const int h_ = col >> 6, dh = col & 63;
                        *(unsigned*)((u8*)Cv + 2 * (size_t)TOKENS * H +
                                     (((size_t)(b_ * NHD + h_) * DH + dh) << 8) + s0) =
                            f2fp8x4(acc[mf][nf][0] + bv, acc[mf][nf][1] + bv,
                                    acc[mf][nf][2] + bv, acc[mf][nf][3] + bv);
                    }
                } else {   // MODE 10: no bias, fp8 out (PV -> ctx8)
                    u8* C8 = (u8*)Cv + ob * sCo + ib * sCi;
#pragma unroll
                    for (int r = 0; r < 4; ++r)
                        C8[(size_t)(gm + r) * ldc + gn] = f2fp8(acc[mf][nf][r]);
                }
            }
        }
    }
}

// ---------------- all 6 weight transposes of one layer -> fp8 ----------------
__global__ __launch_bounds__(256) void transpose_all_k(
    const float* __restrict__ Wq, const float* __restrict__ Wk,
    const float* __restrict__ Wv, const float* __restrict__ Wo,
    const float* __restrict__ W1, const float* __restrict__ W2,
    u8* __restrict__ wtqkv8, u8* __restrict__ wto8,
    u8* __restrict__ wt1, u8* __restrict__ wt2)
{
    int idx = blockIdx.x;
    const float* W; int R, C, tr, tc; u8* WT8;
    if (idx < 2304) {
        int mat = idx / 576, t = idx - mat * 576;
        tr = t / 24; tc = t - tr * 24; R = 768; C = 768;
        W = mat == 0 ? Wq : mat == 1 ? Wk : mat == 2 ? Wv : Wo;
        WT8 = mat < 3 ? wtqkv8 + (size_t)mat * 768 * 768 : wto8;
    } else if (idx < 4608) {
        int t = idx - 2304; tr = t / 96; tc = t - tr * 96;
        R = 768; C = 3072; W = W1; WT8 = wt1;
    } else {
        int t = idx - 4608; tr = t / 24; tc = t - tr * 24;
        R = 3072; C = 768; W = W2; WT8 = wt2;
    }
    int r0 = tr * 32, c0 = tc * 32;
    __shared__ float tl[32][33];
    int trd = threadIdx.x >> 3;
    int tc4 = (threadIdx.x & 7) * 4;
    const float4 v = *(const float4*)(W + (size_t)(r0 + trd) * C + c0 + tc4);
    tl[trd][tc4 + 0] = v.x; tl[trd][tc4 + 1] = v.y;
    tl[trd][tc4 + 2] = v.z; tl[trd][tc4 + 3] = v.w;
    __syncthreads();
    unsigned p = f2fp8x4(tl[tc4 + 0][trd], tl[tc4 + 1][trd],
                         tl[tc4 + 2][trd], tl[tc4 + 3][trd]);
    *(unsigned*)(WT8 + (size_t)(c0 + trd) * R + r0 + tc4) = p;
}

// ---------------- pack qkv biases -> [NLAY][2304] ----------------
__global__ __launch_bounds__(256) void pack_bias_k(
    const float* __restrict__ bq, const float* __restrict__ bk,
    const float* __restrict__ bv, float* __restrict__ out)
{
    int l = blockIdx.x / 3, r = blockIdx.x - (blockIdx.x / 3) * 3;
    const float* src = r == 0 ? bq : r == 1 ? bk : bv;
#pragma unroll
    for (int j = 0; j < 3; ++j) {
        int d = threadIdx.x + 256 * j;
        out[(size_t)l * QKVN + r * H + d] = src[(size_t)l * H + d];
    }
}

// ---------------- embeddings + LN -> bf16 h + fp8 copy; 4 tokens/block ----------------
__global__ __launch_bounds__(256) void embed_ln_k(
    const int* __restrict__ ids, const int* __restrict__ tts,
    const float* __restrict__ wemb, const float* __restrict__ pemb,
    const float* __restrict__ temb, const float* __restrict__ g,
    const float* __restrict__ bp, ushortT* __restrict__ hb, u8* __restrict__ h8)
{
    const int tok = blockIdx.x * 4 + (threadIdx.x >> 6);
    const int lane = threadIdx.x & 63;
    const int d0 = lane * 12;
    const int spos = tok & (S - 1);
    const int id = ids[tok], tt = tts[tok];
    const float* wr = wemb + (size_t)id * H + d0;
    const float* pr = pemb + (size_t)spos * H + d0;
    const float* tr = temb + (size_t)tt * H + d0;
    float x[12]; float s = 0.f, ss = 0.f;
#pragma unroll
    for (int j = 0; j < 3; ++j) {
        float4 a = *(const float4*)(wr + j * 4);
        float4 b = *(const float4*)(pr + j * 4);
        float4 c = *(const float4*)(tr + j * 4);
        float v0 = a.x + b.x + c.x, v1 = a.y + b.y + c.y;
        float v2 = a.z + b.z + c.z, v3 = a.w + b.w + c.w;
        x[j*4+0] = v0; x[j*4+1] = v1; x[j*4+2] = v2; x[j*4+3] = v3;
        s += v0 + v1 + v2 + v3;
        ss += v0*v0 + v1*v1 + v2*v2 + v3*v3;
    }
#pragma unroll
    for (int m = 32; m; m >>= 1) { s += __shfl_xor(s, m); ss += __shfl_xor(ss, m); }
    float mu = s * (1.f / H);
    float var = ss * (1.f / H) - mu * mu;
    float rs = rsqrtf(var + 1e-12f);
#pragma unroll
    for (int j = 0; j < 3; ++j) {
        float4 gv = *(const float4*)(g + d0 + j * 4);
        float4 bv = *(const float4*)(bp + d0 + j * 4);
        float y0 = (x[j*4+0] - mu) * rs * gv.x + bv.x;
        float y1 = (x[j*4+1] - mu) * rs * gv.y + bv.y;
        float y2 = (x[j*4+2] - mu) * rs * gv.z + bv.z;
        float y3 = (x[j*4+3] - mu) * rs * gv.w + bv.w;
        u16x4 o;
        o[0] = f2bf(y0); o[1] = f2bf(y1); o[2] = f2bf(y2); o[3] = f2bf(y3);
        *(u16x4*)(hb + (size_t)tok * H + d0 + j * 4) = o;
        *(unsigned*)(h8 + (size_t)tok * H + d0 + j * 4) = f2fp8x4(y0, y1, y2, y3);
    }
}

// ---------------- bf16 residual add + LN, in place on hb; emits fp8 copy ----------------
__global__ __launch_bounds__(256) void add_ln_k(
    ushortT* __restrict__ hb, const ushortT* __restrict__ add,
    const float* __restrict__ g, const float* __restrict__ bp,
    u8* __restrict__ h8)
{
    const int tok = blockIdx.x * 4 + (threadIdx.x >> 6);
    const int lane = threadIdx.x & 63;
    const int d0 = lane * 12;
    const size_t base = (size_t)tok * H + d0;
    float x[12]; float s = 0.f, ss = 0.f;
#pragma unroll
    for (int j = 0; j < 3; ++j) {
        u16x4 hv = *(const u16x4*)(hb + base + j * 4);
        u16x4 av = *(const u16x4*)(add + base + j * 4);
#pragma unroll
        for (int q = 0; q < 4; ++q) {
            float v = bf2f(hv[q]) + bf2f(av[q]);
            x[j*4+q] = v; s += v; ss += v * v;
        }
    }
#pragma unroll
    for (int m = 32; m; m >>= 1) { s += __shfl_xor(s, m); ss += __shfl_xor(ss, m); }
    float mu = s * (1.f / H);
    float var = ss * (1.f / H) - mu * mu;
    float rs = rsqrtf(var + 1e-12f);
#pragma unroll
    for (int j = 0; j < 3; ++j) {
        float4 gv = *(const float4*)(g + d0 + j * 4);
        float4 bv = *(const float4*)(bp + d0 + j * 4);
        float y0 = (x[j*4+0] - mu) * rs * gv.x + bv.x;
        float y1 = (x[j*4+1] - mu) * rs * gv.y + bv.y;
        float y2 = (x[j*4+2] - mu) * rs * gv.z + bv.z;
        float y3 = (x[j*4+3] - mu) * rs * gv.w + bv.w;
        u16x4 o;
        o[0] = f2bf(y0); o[1] = f2bf(y1); o[2] = f2bf(y2); o[3] = f2bf(y3);
        *(u16x4*)(hb + base + j * 4) = o;
        *(unsigned*)(h8 + base + j * 4) = f2fp8x4(y0, y1, y2, y3);
    }
}

// ---------------- logits + log_softmax over 9 labels (bf16 h, f32 math) ----------------
__global__ __launch_bounds__(256) void logits_k(
    const ushortT* __restrict__ hb, const float* __restrict__ fcw,
    float* __restrict__ em)
{
    int tok = blockIdx.x, tid = threadIdx.x;
    float p[LBL];
#pragma unroll
    for (int l = 0; l < LBL; ++l) p[l] = 0.f;
    const ushortT* hr = hb + (size_t)tok * H;
#pragma unroll
    for (int j = 0; j < 3; ++j) {
        int d = tid + 256 * j;
        float hv = bf2f(hr[d]);
        const float* fr = fcw + (size_t)d * LBL;
#pragma unroll
        for (int l = 0; l < LBL; ++l) p[l] = fmaf(hv, fr[l], p[l]);
    }
    __shared__ float ls[4][LBL];
    __shared__ float lg[LBL];
    __shared__ float lse;
#pragma unroll
    for (int l = 0; l < LBL; ++l) {
        float v = p[l];
#pragma unroll
        for (int m = 32; m; m >>= 1) v += __shfl_xor(v, m);
        if ((tid & 63) == 0) ls[tid >> 6][l] = v;
    }
    __syncthreads();
    if (tid < LBL) lg[tid] = ls[0][tid] + ls[1][tid] + ls[2][tid] + ls[3][tid];
    __syncthreads();
    if (tid == 0) {
        float mx = lg[0];
#pragma unroll
        for (int j = 1; j < LBL; ++j) mx = fmaxf(mx, lg[j]);
        float sm = 0.f;
#pragma unroll
        for (int j = 0; j < LBL; ++j) sm += expf(lg[j] - mx);
        lse = mx + logf(sm);
    }
    __syncthreads();
    if (tid < LBL) em[(size_t)tok * LBL + tid] = lg[tid] - lse;
}

// ---------------- CRF: one wave per batch elem, base-2 fast recursion ----------------
__global__ __launch_bounds__(64) void crf_k(
    const float* __restrict__ em, const int* __restrict__ tags,
    const int* __restrict__ mask, const float* __restrict__ sp,
    const float* __restrict__ ep, const float* __restrict__ trans,
    float* __restrict__ partial)
{
    constexpr float LOG2E = 1.4426950408889634f;
    constexpr float LN2   = 0.6931471805599453f;
    int b = blockIdx.x, t = threadIdx.x;
    __shared__ float eml[S * LBL];     // emissions * log2(e)
    __shared__ int mkl[S];
    const float* emb = em + (size_t)b * S * LBL;
    const int* tg = tags + (size_t)b * S;
    const int* mk = mask + (size_t)b * S;

    for (int i = t * 4; i < S * LBL; i += 256) {
        float4 v = *(const float4*)&emb[i];
        v.x *= LOG2E; v.y *= LOG2E; v.z *= LOG2E; v.w *= LOG2E;
        *(float4*)&eml[i] = v;
    }
    *(i32x4*)&mkl[t * 4] = *(const i32x4*)&mk[t * 4];

    int cnt = 0; float ns = 0.f;
    for (int i = t; i < S; i += 64) {
        int m = mk[i];
        cnt += (m != 0);
        if (i >= 1 && m)
            ns += trans[tg[i - 1] * LBL + tg[i]] + emb[(size_t)i * LBL + tg[i]];
    }
#pragma unroll
    for (int m = 32; m; m >>= 1) { cnt += __shfl_xor(cnt, m); ns += __shfl_xor(ns, m); }
    float num = ns + sp[tg[0]] + emb[tg[0]] + ep[tg[cnt - 1]];

    int tt = t < LBL ? t : 0;
    float trc2[LBL];
#pragma unroll
    for (int i = 0; i < LBL; ++i) trc2[i] = trans[i * LBL + tt] * LOG2E;

    __syncthreads();

    float alpha2 = (t < LBL) ? sp[t] * LOG2E + eml[t] : -1e30f;
    for (int step = 1; step < S; ++step) {
        float av[LBL];
#pragma unroll
        for (int i = 0; i < LBL; ++i) av[i] = __shfl(alpha2, i) + trc2[i];
        float mx = av[0];
#pragma unroll
        for (int i = 1; i < LBL; ++i) mx = fmaxf(mx, av[i]);
        float sm = 0.f;
#pragma unroll
        for (int i = 0; i < LBL; ++i) sm += exp2i(av[i] - mx);
        float na = mx + log2i(sm) + eml[step * LBL + tt];
        alpha2 = (mkl[step] && t < LBL) ? na : alpha2;
    }
    float z = (t < LBL) ? alpha2 + ep[t] * LOG2E : -1e30f;
    float mx = z;
#pragma unroll
    for (int m = 8; m; m >>= 1) mx = fmaxf(mx, __shfl_xor(mx, m));
    float sm = exp2i(z - mx);
#pragma unroll
    for (int m = 8; m; m >>= 1) sm += __shfl_xor(sm, m);
    if (t == 0) partial[b] = (mx + log2i(sm)) * LN2 - num;
}

__global__ void finalize_k(const float* __restrict__ partial, float* __restrict__ out) {
    float s = 0.f;
    for (int i = 0; i < BATCH; ++i) s += partial[i];
    out[0] = s;
}

__global__ void sentinel_k(float* out) { out[0] = -12345.0f; }

extern "C" void kernel_launch(void* const* d_in, const int* in_sizes, int n_in,
                              void* d_out, int out_size, void* d_ws, size_t ws_size,
                              hipStream_t stream) {
    (void)in_sizes; (void)n_in; (void)out_size;
    const int* token_ids  = (const int*)d_in[0];
    const int* token_type = (const int*)d_in[1];
    const int* amask      = (const int*)d_in[2];
    const int* y          = (const int*)d_in[3];
    const float* wemb = (const float*)d_in[4];
    const float* pemb = (const float*)d_in[5];
    const float* temb = (const float*)d_in[6];
    const float* eg   = (const float*)d_in[7];
    const float* eb   = (const float*)d_in[8];
    const float* Wq = (const float*)d_in[9];
    const float* bq = (const float*)d_in[10];
    const float* Wk = (const float*)d_in[11];
    const float* bk = (const float*)d_in[12];
    const float* Wv = (const float*)d_in[13];
    const float* bv = (const float*)d_in[14];
    const float* Wo = (const float*)d_in[15];
    const float* bo = (const float*)d_in[16];
    const float* ln1g = (const float*)d_in[17];
    const float* ln1b = (const float*)d_in[18];
    const float* W1 = (const float*)d_in[19];
    const float* b1 = (const float*)d_in[20];
    const float* W2 = (const float*)d_in[21];
    const float* b2 = (const float*)d_in[22];
    const float* ln2g = (const float*)d_in[23];
    const float* ln2b = (const float*)d_in[24];
    const float* fcw = (const float*)d_in[25];
    const float* crf_s = (const float*)d_in[26];
    const float* crf_e = (const float*)d_in[27];
    const float* crf_t = (const float*)d_in[28];

    if (ws_size < WS_FLOATS * sizeof(float)) {
        sentinel_k<<<1, 1, 0, stream>>>((float*)d_out);
        return;
    }

    float* ws = (float*)d_ws;
    ushortT* hb    = (ushortT*)(ws + HB_OFF);
    ushortT* obuf  = (ushortT*)(ws + OB_OFF);  // bf16 scratch (attn-out / ff2-out)
    u8*      q8    = (u8*)(ws + Q8_OFF);       // q; k = +TOKENS*H; vt = +2*TOKENS*H bytes
    u8*      k8    = q8 + (size_t)TOKENS * H;
    u8*      vt8   = q8 + 2 * (size_t)TOKENS * H;
    u8*      big8  = (u8*)(ws + BIG_OFF);      // probs fp8 / ff1 fp8 (sequential reuse)
    u8*      wtq8  = (u8*)(ws + WTQ_OFF);
    u8*      wto8  = (u8*)(ws + WTO_OFF);
    u8*      wt1   = (u8*)(ws + WT1_OFF);
    u8*      wt2   = (u8*)(ws + WT2_OFF);
    float*   embuf = ws + EM_OFF;
    float*   part  = ws + PART_OFF;
    float*   bqkv  = ws + BQKV_OFF;
    u8*      h8    = (u8*)(ws + H8_OFF);
    u8*      ctx8  = (u8*)(ws + CT8_OFF);

    pack_bias_k<<<NLAY * 3, 256, 0, stream>>>(bq, bk, bv, bqkv);
    embed_ln_k<<<TOKENS / 4, 256, 0, stream>>>(token_ids, token_type, wemb, pemb,
                                               temb, eg, eb, hb, h8);

    constexpr long long HH = (long long)H * H;
    constexpr long long HF = (long long)H * FF;
    constexpr long long SH = (long long)S * H;          // 196608
    constexpr long long ATT_B = (long long)NHD * S * S; // 786432
    constexpr long long ATT_H = (long long)S * S;       // 65536
    constexpr long long VT_B = (long long)NHD * DH * S; // 196608
    constexpr long long VT_H = (long long)DH * S;       // 16384

    dim3 gQKV(QKVN / 128, TOKENS / 128, 1);       // 18 x 64 = 1152 (%8==0)
    dim3 gProj(H / 128, TOKENS / 128, 1);         // 6 x 64 = 384
    dim3 gFF1(FF / 128, TOKENS / 128, 1);         // 24 x 64 = 1536
    dim3 gScores(1, S / 64, BATCH * NHD);         // 1 x 4 x 384
    dim3 gPV(1, 1, BATCH * NHD);                  // 256x64 tile covers head

    for (int l = 0; l < NLAY; ++l) {
        transpose_all_k<<<6912, 256, 0, stream>>>(
            Wq + l * HH, Wk + l * HH, Wv + l * HH, Wo + l * HH,
            W1 + l * HF, W2 + l * HF, wtq8, wto8, wt1, wt2);

        // fused q,k,v projections (FP8 GEMM, routing epilogue -> fp8 q/k/v^T)
        gemm_fp8b<2,2,9><<<gQKV, 256, 0, stream>>>(
            h8, H, 0, 0, wtq8, H, 0, 0, bqkv + (size_t)l * QKVN,
            q8, H, 0, 0, H, 1);

        // probs = softmax(mask(q @ k^T)) per (b,h), fused epilogue -> fp8
        gemm_fp8b<1,4,6><<<gScores, 256, 0, stream>>>(
            q8, H, SH, DH, k8, H, SH, DH, (const float*)amask,
            big8, S, ATT_B, ATT_H, DH, NHD);

        // ctx = probs @ v  (per b,h) -> ctx8 fp8 as [B,S,NH,DH]
        gemm_fp8b<4,1,10><<<gPV, 256, 0, stream>>>(
            big8, S, ATT_B, ATT_H, vt8, S, VT_B, VT_H, nullptr,
            ctx8, H, SH, DH, S, NHD);

        // attention output projection (FP8 GEMM) -> obuf bf16
        gemm_fp8b<2,2,8><<<gProj, 256, 0, stream>>>(
            ctx8, H, 0, 0, wto8, H, 0, 0, bo + l * H, obuf, H, 0, 0, H, 1);

        add_ln_k<<<TOKENS / 4, 256, 0, stream>>>(hb, obuf, ln1g + l * H, ln1b + l * H, h8);

        // ff1 = gelu(h @ W1 + b1) -> big8 fp8  (K=768)
        gemm_fp8b<2,2,7><<<gFF1, 256, 0, stream>>>(
            h8, H, 0, 0, wt1, H, 0, 0, b1 + (long long)l * FF, big8, FF, 0, 0, H, 1);

        // ff2 = big8 @ W2 + b2 -> obuf bf16  (K=3072)
        gemm_fp8b<2,2,8><<<gProj, 256, 0, stream>>>(
            big8, FF, 0, 0, wt2, FF, 0, 0, b2 + l * H, obuf, H, 0, 0, FF, 1);

        add_ln_k<<<TOKENS / 4, 256, 0, stream>>>(hb, obuf, ln2g + l * H, ln2b + l * H, h8);
    }

    logits_k<<<TOKENS, 256, 0, stream>>>(hb, fcw, embuf);
    crf_k<<<BATCH, 64, 0, stream>>>(embuf, y, amask, crf_s, crf_e, crf_t, part);
    finalize_k<<<1, 1, 0, stream>>>(part, (float*)d_out);
}

// Round 18
// 2526.477 us; speedup vs baseline: 1.7036x; 1.0035x over previous
//
#include <hip/hip_runtime.h>
#include <math.h>

typedef unsigned short ushortT;
typedef unsigned char u8;
typedef __attribute__((ext_vector_type(4))) float f32x4;
typedef __attribute__((ext_vector_type(4))) unsigned int u32x4;
typedef __attribute__((ext_vector_type(4))) unsigned short u16x4;
typedef __attribute__((ext_vector_type(4))) int i32x4;

namespace {
constexpr int S = 256;
constexpr int H = 768;
constexpr int NLAY = 12;
constexpr int NHD = 12;
constexpr int FF = 3072;
constexpr int LBL = 9;
constexpr int DH = 64;
constexpr int BATCH = 32;
constexpr int TOKENS = BATCH * S;      // 8192
constexpr int QKVN = 3 * H;            // 2304
// softmax scale folded into exponent: p = exp2(C2*(s_raw - m_raw)), C2 = 0.125*log2(e)
constexpr float C2 = 0.18033688011112042f;

constexpr size_t HHW = (size_t)H * H;   // 589824
constexpr size_t HFW = (size_t)H * FF;  // 2359296

// workspace layout (float-slot units)
constexpr size_t HB_OFF  = 0;                            // h bf16 [8192][768]
constexpr size_t OB_OFF  = HB_OFF + (size_t)TOKENS*H/2;  // bf16 scratch (attn-out / ff2-out)
constexpr size_t Q8_OFF  = OB_OFF + (size_t)TOKENS*H/2;  // fp8 q; k at +TH bytes; v^T at +2TH
constexpr size_t BIG_OFF = Q8_OFF + 3*(size_t)TOKENS*H/4; // probs fp8 [B,NH,S,S] == ff1 fp8
constexpr size_t WTQ_OFF = BIG_OFF + (size_t)TOKENS*FF/4; // all-layer Wqkv^T fp8 [12][2304][768]
constexpr size_t WTO_OFF = WTQ_OFF + (size_t)NLAY*3*HHW/4; // all-layer Wo^T fp8 [12][768][768]
constexpr size_t WT1_OFF = WTO_OFF + (size_t)NLAY*HHW/4;   // all-layer W1^T fp8 [12][3072][768]
constexpr size_t WT2_OFF = WT1_OFF + (size_t)NLAY*HFW/4;   // all-layer W2^T fp8 [12][768][3072]
constexpr size_t EM_OFF  = WT2_OFF + (size_t)NLAY*HFW/4;
constexpr size_t PART_OFF= EM_OFF + (size_t)TOKENS*LBL;
constexpr size_t BQKV_OFF= PART_OFF + 64;                // packed qkv bias [12][2304]
constexpr size_t H8_OFF  = BQKV_OFF + (size_t)NLAY*QKVN; // h fp8 copy
constexpr size_t CT8_OFF = H8_OFF + (size_t)TOKENS*H/4;  // ctx fp8 [8192][768]
constexpr size_t WS_FLOATS = CT8_OFF + (size_t)TOKENS*H/4;
}

__device__ __forceinline__ ushortT f2bf(float x) {
    unsigned u = __builtin_bit_cast(unsigned, x);
    u += 0x7fffu + ((u >> 16) & 1u);
    return (ushortT)(u >> 16);
}
__device__ __forceinline__ float bf2f(ushortT h) {
    unsigned u = ((unsigned)h) << 16;
    return __builtin_bit_cast(float, u);
}
__device__ __forceinline__ u8 f2fp8(float x) {
    return (u8)(__builtin_amdgcn_cvt_pk_fp8_f32(x, x, 0, false) & 0xff);
}
__device__ __forceinline__ unsigned f2fp8x4(float a, float b, float c, float d) {
    int p = __builtin_amdgcn_cvt_pk_fp8_f32(a, b, 0, false);
    p = __builtin_amdgcn_cvt_pk_fp8_f32(c, d, p, true);
    return (unsigned)p;
}

__device__ __forceinline__ float exp2i(float x) {
    float r; asm("v_exp_f32 %0, %1" : "=v"(r) : "v"(x)); return r;
}
__device__ __forceinline__ float log2i(float x) {
    float r; asm("v_log_f32 %0, %1" : "=v"(r) : "v"(x)); return r;
}

// tanh-gelu in sigmoid form: 0.5x(1+tanh(u)) == x*sigmoid(2u) == x/(1+exp2(-2u*log2e))
__device__ __forceinline__ float gelu_tanh(float x) {
    float u = 0.7978845608028654f * (x + 0.044715f * x * x * x);
    float t = exp2i(-2.8853900817779268f * u);
    return x / (1.0f + t);
}

__device__ __forceinline__ void gload_lds16b(const u8* g, u8* l) {
    __builtin_amdgcn_global_load_lds(
        (const __attribute__((address_space(1))) unsigned int*)g,
        (__attribute__((address_space(3))) unsigned int*)l,
        16, 0, 0);
}

// =====================================================================
// Unified FP8 e4m3 MFMA GEMM: BM=WM*64 x BN=WN*64 (WM*WN==4 waves of 64x64),
// K-step 64, 64B LDS rows, (row>>1)&3 16B-chunk both-sides swizzle,
// 3-buffer counted-vmcnt pipeline (stage group = WM+WN loads/thread ->
// vmcnt(WM+WN) certifies tile t with one group outstanding; tail re-stages
// keep the FIFO exact). 32 MFMAs/iter at bf16 MFMA rate with HALF the LDS
// bytes per FLOP (the measured binding resource).
// MODE: 6  = fused mask+row-softmax -> fp8 probs (WM=1,WN=4; BN==256==S;
//            `bias` carries the int mask pointer; ob indexes batch)
//       7  = bias+gelu -> fp8 (FF1)
//       8  = bias -> bf16 (Wo/FF2)
//       9  = fused-QKV routing -> fp8 q/k/v^T (Cv = q8; k8 +TH; vt8 +2TH bytes)
//       10 = no bias -> fp8 (PV -> ctx8)
// 2D grids (gridDim.z==1) get the XCD-aware block swizzle; grids are %8==0.
// =====================================================================
template<int WM, int WN, int MODE>
__global__ __launch_bounds__(256) void gemm_fp8b(
    const u8* __restrict__ A, int lda, long long sAo, long long sAi,
    const u8* __restrict__ Bt, int ldb, long long sBo, long long sBi,
    const float* __restrict__ bias,
    void* __restrict__ Cv, int ldc, long long sCo, long long sCi,
    int K, int innerN)
{
    constexpr int BM = WM * 64, BN = WN * 64;
    __shared__ __align__(16) u8 As[3][BM * 64];
    __shared__ __align__(16) u8 Bs[3][BN * 64];
    const int tid = threadIdx.x;
    const int wave = tid >> 6, lane = tid & 63;
    const int ob = blockIdx.z / innerN, ib = blockIdx.z - ob * innerN;

    int bxi = blockIdx.x, byi = blockIdx.y;
    if (gridDim.z == 1) {
        const int nwg = gridDim.x * gridDim.y;
        const int lin = byi * gridDim.x + bxi;
        const int cpx = nwg >> 3;
        const int sw = (lin & 7) * cpx + (lin >> 3);
        byi = sw / gridDim.x; bxi = sw - byi * gridDim.x;
    }
    const int bm = byi * BM, bn = bxi * BN;
    const u8* Ab = A + ob * sAo + ib * sAi + (size_t)bm * lda;
    const u8* Bb = Bt + ob * sBo + ib * sBi + (size_t)bn * ldb;
    const int wm = wave / WN, wn = wave - wm * WN;

    const int lrow = lane >> 2;                              // row within 16-row chunk
    const int lswb = ((lane & 3) ^ ((lrow >> 1) & 3)) * 16;  // swizzled SRC byte off
    const int rl = lane & 15;
    const int kg = lane >> 4;                                // 0..3
    const int kg4 = kg << 2;
    const int key = (rl >> 1) & 3;                           // read-side swizzle key
    const int kgh = kg >> 1, kgl8 = (kg & 1) * 8;

    f32x4 acc[4][4];
#pragma unroll
    for (int i = 0; i < 4; ++i)
#pragma unroll
        for (int j = 0; j < 4; ++j) acc[i][j] = (f32x4){0.f, 0.f, 0.f, 0.f};

    auto stage = [&](int buf, int kt) {
#pragma unroll
        for (int j = 0; j < WM; ++j) {
            int chunk = j * 4 + wave;
            gload_lds16b(Ab + (size_t)(chunk * 16 + lrow) * lda + kt * 64 + lswb,
                         &As[buf][chunk * 1024]);
        }
#pragma unroll
        for (int j = 0; j < WN; ++j) {
            int chunk = j * 4 + wave;
            gload_lds16b(Bb + (size_t)(chunk * 16 + lrow) * ldb + kt * 64 + lswb,
                         &Bs[buf][chunk * 1024]);
        }
    };

    const int nt = K >> 6;
    stage(0, 0);
    stage(1, (nt > 1) ? 1 : 0);
    int cur = 0;
    for (int t = 0; t < nt; ++t) {
        if constexpr (WM + WN == 4)
            asm volatile("s_waitcnt vmcnt(4)" ::: "memory");
        else
            asm volatile("s_waitcnt vmcnt(5)" ::: "memory");
        __builtin_amdgcn_s_barrier();
        __builtin_amdgcn_sched_barrier(0);
#pragma unroll
        for (int ks = 0; ks < 2; ++ks) {
            long a[4], b[4];
#pragma unroll
            for (int mf = 0; mf < 4; ++mf)
                a[mf] = *(const long*)&As[cur][(wm * 64 + mf * 16 + rl) * 64 +
                                               (((ks * 2 + kgh) ^ key) << 4) + kgl8];
#pragma unroll
            for (int nf = 0; nf < 4; ++nf)
                b[nf] = *(const long*)&Bs[cur][(wn * 64 + nf * 16 + rl) * 64 +
                                               (((ks * 2 + kgh) ^ key) << 4) + kgl8];
            if (ks == 0) {   // stage tile t+2 once per iter (keeps FIFO count exact)
                const int nx = (t + 2 < nt) ? t + 2 : nt - 1;
                int nb = cur + 2; if (nb >= 3) nb -= 3;
                stage(nb, nx);
            }
#pragma unroll
            for (int mf = 0; mf < 4; ++mf)
#pragma unroll
                for (int nf = 0; nf < 4; ++nf)
                    acc[mf][nf] = __builtin_amdgcn_mfma_f32_16x16x32_fp8_fp8(
                        a[mf], b[nf], acc[mf][nf], 0, 0, 0);
        }
        cur = (cur + 1 == 3) ? 0 : cur + 1;
    }
    asm volatile("s_waitcnt vmcnt(0)" ::: "memory");

    if constexpr (MODE == 6) {
        // ---- fused mask + row softmax epilogue (WM=1: all waves share rows) ----
        u8* C8 = (u8*)Cv + ob * sCo + ib * sCi;
        __shared__ float red6[2][4][64];
        const int* mrow = (const int*)bias + ob * S;
        float mb[4];
#pragma unroll
        for (int nf = 0; nf < 4; ++nf)
            mb[nf] = mrow[bn + wn * 64 + nf * 16 + rl] ? 0.f : -8e9f;
        float pm[4][4];
#pragma unroll
        for (int mf = 0; mf < 4; ++mf)
#pragma unroll
            for (int r = 0; r < 4; ++r) pm[mf][r] = -1e30f;
#pragma unroll
        for (int mf = 0; mf < 4; ++mf)
#pragma unroll
            for (int nf = 0; nf < 4; ++nf)
#pragma unroll
                for (int r = 0; r < 4; ++r) {
                    acc[mf][nf][r] += mb[nf];
                    pm[mf][r] = fmaxf(pm[mf][r], acc[mf][nf][r]);
                }
#pragma unroll
        for (int mf = 0; mf < 4; ++mf)
#pragma unroll
            for (int r = 0; r < 4; ++r) {
                float v = pm[mf][r];
                v = fmaxf(v, __shfl_xor(v, 1));
                v = fmaxf(v, __shfl_xor(v, 2));
                v = fmaxf(v, __shfl_xor(v, 4));
                v = fmaxf(v, __shfl_xor(v, 8));
                pm[mf][r] = v;
            }
        if (rl == 0) {
#pragma unroll
            for (int mf = 0; mf < 4; ++mf)
#pragma unroll
                for (int r = 0; r < 4; ++r)
                    red6[0][wn][mf * 16 + kg4 + r] = pm[mf][r];
        }
        __syncthreads();
        float Mx[4][4];
#pragma unroll
        for (int mf = 0; mf < 4; ++mf)
#pragma unroll
            for (int r = 0; r < 4; ++r) {
                const int row = mf * 16 + kg4 + r;
                Mx[mf][r] = fmaxf(fmaxf(red6[0][0][row], red6[0][1][row]),
                                  fmaxf(red6[0][2][row], red6[0][3][row]));
            }
        float ps[4][4];
#pragma unroll
        for (int mf = 0; mf < 4; ++mf)
#pragma unroll
            for (int r = 0; r < 4; ++r) ps[mf][r] = 0.f;
#pragma unroll
        for (int mf = 0; mf < 4; ++mf)
#pragma unroll
            for (int nf = 0; nf < 4; ++nf)
#pragma unroll
                for (int r = 0; r < 4; ++r) {
                    float e = exp2i(C2 * (acc[mf][nf][r] - Mx[mf][r]));
                    acc[mf][nf][r] = e;
                    ps[mf][r] += e;
                }
#pragma unroll
        for (int mf = 0; mf < 4; ++mf)
#pragma unroll
            for (int r = 0; r < 4; ++r) {
                float v = ps[mf][r];
                v += __shfl_xor(v, 1);
                v += __shfl_xor(v, 2);
                v += __shfl_xor(v, 4);
                v += __shfl_xor(v, 8);
                ps[mf][r] = v;
            }
        if (rl == 0) {
#pragma unroll
            for (int mf = 0; mf < 4; ++mf)
#pragma unroll
                for (int r = 0; r < 4; ++r)
                    red6[1][wn][mf * 16 + kg4 + r] = ps[mf][r];
        }
        __syncthreads();
#pragma unroll
        for (int mf = 0; mf < 4; ++mf) {
            float inv[4];
#pragma unroll
            for (int r = 0; r < 4; ++r) {
                const int row = mf * 16 + kg4 + r;
                inv[r] = 1.0f / (red6[1][0][row] + red6[1][1][row] +
                                 red6[1][2][row] + red6[1][3][row]);
            }
#pragma unroll
            for (int nf = 0; nf < 4; ++nf) {
                const int gn = bn + wn * 64 + nf * 16 + rl;
                const int gm = bm + mf * 16 + kg4;
#pragma unroll
                for (int r = 0; r < 4; ++r)
                    C8[(size_t)(gm + r) * ldc + gn] = f2fp8(acc[mf][nf][r] * inv[r]);
            }
        }
    } else {
#pragma unroll
        for (int nf = 0; nf < 4; ++nf) {
            const int gn = bn + wn * 64 + nf * 16 + rl;
            float bv = 0.f;
            if constexpr (MODE != 10) bv = bias[gn];
#pragma unroll
            for (int mf = 0; mf < 4; ++mf) {
                const int gm = bm + wm * 64 + mf * 16 + kg4;
                if constexpr (MODE == 7) {
                    u8* C8 = (u8*)Cv;
#pragma unroll
                    for (int r = 0; r < 4; ++r)
                        C8[(size_t)(gm + r) * ldc + gn] =
                            f2fp8(gelu_tanh(acc[mf][nf][r] + bv));
                } else if constexpr (MODE == 8) {
                    ushortT* Ch = (ushortT*)Cv;
#pragma unroll
                    for (int r = 0; r < 4; ++r)
                        Ch[(size_t)(gm + r) * ldc + gn] = f2bf(acc[mf][nf][r] + bv);
                } else if constexpr (MODE == 9) {
                    const int region = gn / H;          // 0=q,1=k,2=v
                    const int col = gn - region * H;
                    if (region < 2) {
                        u8* o = (u8*)Cv + (size_t)region * TOKENS * H;
#pragma unroll
                        for (int r = 0; r < 4; ++r)
                            o[(size_t)(gm + r) * H + col] = f2fp8(acc[mf][nf][r] + bv);
                    } else {
                        const int b_ = gm >> 8, s0 = gm & 255;
                        const int h_ = col >> 6, dh = col & 63;
                        *(unsigned*)((u8*)Cv + 2 * (size_t)TOKENS * H +
                                     (((size_t)(b_ * NHD + h_) * DH + dh) << 8) + s0) =
                            f2fp8x4(acc[mf][nf][0] + bv, acc[mf][nf][1] + bv,
                                    acc[mf][nf][2] + bv, acc[mf][nf][3] + bv);
                    }
                } else {   // MODE 10: no bias, fp8 out (PV -> ctx8)
                    u8* C8 = (u8*)Cv + ob * sCo + ib * sCi;
#pragma unroll
                    for (int r = 0; r < 4; ++r)
                        C8[(size_t)(gm + r) * ldc + gn] = f2fp8(acc[mf][nf][r]);
                }
            }
        }
    }
}

// ---------------- ALL layers' weight transposes -> fp8, one dispatch ----------------
// 6912 tiles/layer x 12 layers = 82944 blocks.
__global__ __launch_bounds__(256) void transpose_all_k(
    const float* __restrict__ Wq, const float* __restrict__ Wk,
    const float* __restrict__ Wv, const float* __restrict__ Wo,
    const float* __restrict__ W1, const float* __restrict__ W2,
    u8* __restrict__ wtqkv8, u8* __restrict__ wto8,
    u8* __restrict__ wt1, u8* __restrict__ wt2)
{
    const int gidx = blockIdx.x;
    const int l = gidx / 6912;
    const int idx = gidx - l * 6912;
    const float* W; int R, C, tr, tc; u8* WT8;
    if (idx < 2304) {
        int mat = idx / 576, t = idx - mat * 576;
        tr = t / 24; tc = t - tr * 24; R = 768; C = 768;
        const float* base = mat == 0 ? Wq : mat == 1 ? Wk : mat == 2 ? Wv : Wo;
        W = base + (size_t)l * HHW;
        WT8 = mat < 3 ? wtqkv8 + (size_t)l * 3 * HHW + (size_t)mat * HHW
                      : wto8 + (size_t)l * HHW;
    } else if (idx < 4608) {
        int t = idx - 2304; tr = t / 96; tc = t - tr * 96;
        R = 768; C = 3072; W = W1 + (size_t)l * HFW; WT8 = wt1 + (size_t)l * HFW;
    } else {
        int t = idx - 4608; tr = t / 24; tc = t - tr * 24;
        R = 3072; C = 768; W = W2 + (size_t)l * HFW; WT8 = wt2 + (size_t)l * HFW;
    }
    int r0 = tr * 32, c0 = tc * 32;
    __shared__ float tl[32][33];
    int trd = threadIdx.x >> 3;
    int tc4 = (threadIdx.x & 7) * 4;
    const float4 v = *(const float4*)(W + (size_t)(r0 + trd) * C + c0 + tc4);
    tl[trd][tc4 + 0] = v.x; tl[trd][tc4 + 1] = v.y;
    tl[trd][tc4 + 2] = v.z; tl[trd][tc4 + 3] = v.w;
    __syncthreads();
    unsigned p = f2fp8x4(tl[tc4 + 0][trd], tl[tc4 + 1][trd],
                         tl[tc4 + 2][trd], tl[tc4 + 3][trd]);
    *(unsigned*)(WT8 + (size_t)(c0 + trd) * R + r0 + tc4) = p;
}

// ---------------- pack qkv biases -> [NLAY][2304] ----------------
__global__ __launch_bounds__(256) void pack_bias_k(
    const float* __restrict__ bq, const float* __restrict__ bk,
    const float* __restrict__ bv, float* __restrict__ out)
{
    int l = blockIdx.x / 3, r = blockIdx.x - (blockIdx.x / 3) * 3;
    const float* src = r == 0 ? bq : r == 1 ? bk : bv;
#pragma unroll
    for (int j = 0; j < 3; ++j) {
        int d = threadIdx.x + 256 * j;
        out[(size_t)l * QKVN + r * H + d] = src[(size_t)l * H + d];
    }
}

// ---------------- embeddings + LN -> bf16 h + fp8 copy; 4 tokens/block ----------------
__global__ __launch_bounds__(256) void embed_ln_k(
    const int* __restrict__ ids, const int* __restrict__ tts,
    const float* __restrict__ wemb, const float* __restrict__ pemb,
    const float* __restrict__ temb, const float* __restrict__ g,
    const float* __restrict__ bp, ushortT* __restrict__ hb, u8* __restrict__ h8)
{
    const int tok = blockIdx.x * 4 + (threadIdx.x >> 6);
    const int lane = threadIdx.x & 63;
    const int d0 = lane * 12;
    const int spos = tok & (S - 1);
    const int id = ids[tok], tt = tts[tok];
    const float* wr = wemb + (size_t)id * H + d0;
    const float* pr = pemb + (size_t)spos * H + d0;
    const float* tr = temb + (size_t)tt * H + d0;
    float x[12]; float s = 0.f, ss = 0.f;
#pragma unroll
    for (int j = 0; j < 3; ++j) {
        float4 a = *(const float4*)(wr + j * 4);
        float4 b = *(const float4*)(pr + j * 4);
        float4 c = *(const float4*)(tr + j * 4);
        float v0 = a.x + b.x + c.x, v1 = a.y + b.y + c.y;
        float v2 = a.z + b.z + c.z, v3 = a.w + b.w + c.w;
        x[j*4+0] = v0; x[j*4+1] = v1; x[j*4+2] = v2; x[j*4+3] = v3;
        s += v0 + v1 + v2 + v3;
        ss += v0*v0 + v1*v1 + v2*v2 + v3*v3;
    }
#pragma unroll
    for (int m = 32; m; m >>= 1) { s += __shfl_xor(s, m); ss += __shfl_xor(ss, m); }
    float mu = s * (1.f / H);
    float var = ss * (1.f / H) - mu * mu;
    float rs = rsqrtf(var + 1e-12f);
#pragma unroll
    for (int j = 0; j < 3; ++j) {
        float4 gv = *(const float4*)(g + d0 + j * 4);
        float4 bv = *(const float4*)(bp + d0 + j * 4);
        float y0 = (x[j*4+0] - mu) * rs * gv.x + bv.x;
        float y1 = (x[j*4+1] - mu) * rs * gv.y + bv.y;
        float y2 = (x[j*4+2] - mu) * rs * gv.z + bv.z;
        float y3 = (x[j*4+3] - mu) * rs * gv.w + bv.w;
        u16x4 o;
        o[0] = f2bf(y0); o[1] = f2bf(y1); o[2] = f2bf(y2); o[3] = f2bf(y3);
        *(u16x4*)(hb + (size_t)tok * H + d0 + j * 4) = o;
        *(unsigned*)(h8 + (size_t)tok * H + d0 + j * 4) = f2fp8x4(y0, y1, y2, y3);
    }
}

// ---------------- bf16 residual add + LN, in place on hb; emits fp8 copy ----------------
__global__ __launch_bounds__(256) void add_ln_k(
    ushortT* __restrict__ hb, const ushortT* __restrict__ add,
    const float* __restrict__ g, const float* __restrict__ bp,
    u8* __restrict__ h8)
{
    const int tok = blockIdx.x * 4 + (threadIdx.x >> 6);
    const int lane = threadIdx.x & 63;
    const int d0 = lane * 12;
    const size_t base = (size_t)tok * H + d0;
    float x[12]; float s = 0.f, ss = 0.f;
#pragma unroll
    for (int j = 0; j < 3; ++j) {
        u16x4 hv = *(const u16x4*)(hb + base + j * 4);
        u16x4 av = *(const u16x4*)(add + base + j * 4);
#pragma unroll
        for (int q = 0; q < 4; ++q) {
            float v = bf2f(hv[q]) + bf2f(av[q]);
            x[j*4+q] = v; s += v; ss += v * v;
        }
    }
#pragma unroll
    for (int m = 32; m; m >>= 1) { s += __shfl_xor(s, m); ss += __shfl_xor(ss, m); }
    float mu = s * (1.f / H);
    float var = ss * (1.f / H) - mu * mu;
    float rs = rsqrtf(var + 1e-12f);
#pragma unroll
    for (int j = 0; j < 3; ++j) {
        float4 gv = *(const float4*)(g + d0 + j * 4);
        float4 bv = *(const float4*)(bp + d0 + j * 4);
        float y0 = (x[j*4+0] - mu) * rs * gv.x + bv.x;
        float y1 = (x[j*4+1] - mu) * rs * gv.y + bv.y;
        float y2 = (x[j*4+2] - mu) * rs * gv.z + bv.z;
        float y3 = (x[j*4+3] - mu) * rs * gv.w + bv.w;
        u16x4 o;
        o[0] = f2bf(y0); o[1] = f2bf(y1); o[2] = f2bf(y2); o[3] = f2bf(y3);
        *(u16x4*)(hb + base + j * 4) = o;
        *(unsigned*)(h8 + base + j * 4) = f2fp8x4(y0, y1, y2, y3);
    }
}

// ---------------- logits + log_softmax over 9 labels (bf16 h, f32 math) ----------------
__global__ __launch_bounds__(256) void logits_k(
    const ushortT* __restrict__ hb, const float* __restrict__ fcw,
    float* __restrict__ em)
{
    int tok = blockIdx.x, tid = threadIdx.x;
    float p[LBL];
#pragma unroll
    for (int l = 0; l < LBL; ++l) p[l] = 0.f;
    const ushortT* hr = hb + (size_t)tok * H;
#pragma unroll
    for (int j = 0; j < 3; ++j) {
        int d = tid + 256 * j;
        float hv = bf2f(hr[d]);
        const float* fr = fcw + (size_t)d * LBL;
#pragma unroll
        for (int l = 0; l < LBL; ++l) p[l] = fmaf(hv, fr[l], p[l]);
    }
    __shared__ float ls[4][LBL];
    __shared__ float lg[LBL];
    __shared__ float lse;
#pragma unroll
    for (int l = 0; l < LBL; ++l) {
        float v = p[l];
#pragma unroll
        for (int m = 32; m; m >>= 1) v += __shfl_xor(v, m);
        if ((tid & 63) == 0) ls[tid >> 6][l] = v;
    }
    __syncthreads();
    if (tid < LBL) lg[tid] = ls[0][tid] + ls[1][tid] + ls[2][tid] + ls[3][tid];
    __syncthreads();
    if (tid == 0) {
        float mx = lg[0];
#pragma unroll
        for (int j = 1; j < LBL; ++j) mx = fmaxf(mx, lg[j]);
        float sm = 0.f;
#pragma unroll
        for (int j = 0; j < LBL; ++j) sm += expf(lg[j] - mx);
        lse = mx + logf(sm);
    }
    __syncthreads();
    if (tid < LBL) em[(size_t)tok * LBL + tid] = lg[tid] - lse;
}

// ---------------- CRF: one wave per batch elem, base-2 fast recursion ----------------
__global__ __launch_bounds__(64) void crf_k(
    const float* __restrict__ em, const int* __restrict__ tags,
    const int* __restrict__ mask, const float* __restrict__ sp,
    const float* __restrict__ ep, const float* __restrict__ trans,
    float* __restrict__ partial)
{
    constexpr float LOG2E = 1.4426950408889634f;
    constexpr float LN2   = 0.6931471805599453f;
    int b = blockIdx.x, t = threadIdx.x;
    __shared__ float eml[S * LBL];     // emissions * log2(e)
    __shared__ int mkl[S];
    const float* emb = em + (size_t)b * S * LBL;
    const int* tg = tags + (size_t)b * S;
    const int* mk = mask + (size_t)b * S;

    for (int i = t * 4; i < S * LBL; i += 256) {
        float4 v = *(const float4*)&emb[i];
        v.x *= LOG2E; v.y *= LOG2E; v.z *= LOG2E; v.w *= LOG2E;
        *(float4*)&eml[i] = v;
    }
    *(i32x4*)&mkl[t * 4] = *(const i32x4*)&mk[t * 4];

    int cnt = 0; float ns = 0.f;
    for (int i = t; i < S; i += 64) {
        int m = mk[i];
        cnt += (m != 0);
        if (i >= 1 && m)
            ns += trans[tg[i - 1] * LBL + tg[i]] + emb[(size_t)i * LBL + tg[i]];
    }
#pragma unroll
    for (int m = 32; m; m >>= 1) { cnt += __shfl_xor(cnt, m); ns += __shfl_xor(ns, m); }
    float num = ns + sp[tg[0]] + emb[tg[0]] + ep[tg[cnt - 1]];

    int tt = t < LBL ? t : 0;
    float trc2[LBL];
#pragma unroll
    for (int i = 0; i < LBL; ++i) trc2[i] = trans[i * LBL + tt] * LOG2E;

    __syncthreads();

    float alpha2 = (t < LBL) ? sp[t] * LOG2E + eml[t] : -1e30f;
    for (int step = 1; step < S; ++step) {
        float av[LBL];
#pragma unroll
        for (int i = 0; i < LBL; ++i) av[i] = __shfl(alpha2, i) + trc2[i];
        float mx = av[0];
#pragma unroll
        for (int i = 1; i < LBL; ++i) mx = fmaxf(mx, av[i]);
        float sm = 0.f;
#pragma unroll
        for (int i = 0; i < LBL; ++i) sm += exp2i(av[i] - mx);
        float na = mx + log2i(sm) + eml[step * LBL + tt];
        alpha2 = (mkl[step] && t < LBL) ? na : alpha2;
    }
    float z = (t < LBL) ? alpha2 + ep[t] * LOG2E : -1e30f;
    float mx = z;
#pragma unroll
    for (int m = 8; m; m >>= 1) mx = fmaxf(mx, __shfl_xor(mx, m));
    float sm = exp2i(z - mx);
#pragma unroll
    for (int m = 8; m; m >>= 1) sm += __shfl_xor(sm, m);
    if (t == 0) partial[b] = (mx + log2i(sm)) * LN2 - num;
}

__global__ void finalize_k(const float* __restrict__ partial, float* __restrict__ out) {
    float s = 0.f;
    for (int i = 0; i < BATCH; ++i) s += partial[i];
    out[0] = s;
}

__global__ void sentinel_k(float* out) { out[0] = -12345.0f; }

extern "C" void kernel_launch(void* const* d_in, const int* in_sizes, int n_in,
                              void* d_out, int out_size, void* d_ws, size_t ws_size,
                              hipStream_t stream) {
    (void)in_sizes; (void)n_in; (void)out_size;
    const int* token_ids  = (const int*)d_in[0];
    const int* token_type = (const int*)d_in[1];
    const int* amask      = (const int*)d_in[2];
    const int* y          = (const int*)d_in[3];
    const float* wemb = (const float*)d_in[4];
    const float* pemb = (const float*)d_in[5];
    const float* temb = (const float*)d_in[6];
    const float* eg   = (const float*)d_in[7];
    const float* eb   = (const float*)d_in[8];
    const float* Wq = (const float*)d_in[9];
    const float* bq = (const float*)d_in[10];
    const float* Wk = (const float*)d_in[11];
    const float* bk = (const float*)d_in[12];
    const float* Wv = (const float*)d_in[13];
    const float* bv = (const float*)d_in[14];
    const float* Wo = (const float*)d_in[15];
    const float* bo = (const float*)d_in[16];
    const float* ln1g = (const float*)d_in[17];
    const float* ln1b = (const float*)d_in[18];
    const float* W1 = (const float*)d_in[19];
    const float* b1 = (const float*)d_in[20];
    const float* W2 = (const float*)d_in[21];
    const float* b2 = (const float*)d_in[22];
    const float* ln2g = (const float*)d_in[23];
    const float* ln2b = (const float*)d_in[24];
    const float* fcw = (const float*)d_in[25];
    const float* crf_s = (const float*)d_in[26];
    const float* crf_e = (const float*)d_in[27];
    const float* crf_t = (const float*)d_in[28];

    if (ws_size < WS_FLOATS * sizeof(float)) {
        sentinel_k<<<1, 1, 0, stream>>>((float*)d_out);
        return;
    }

    float* ws = (float*)d_ws;
    ushortT* hb    = (ushortT*)(ws + HB_OFF);
    ushortT* obuf  = (ushortT*)(ws + OB_OFF);  // bf16 scratch (attn-out / ff2-out)
    u8*      q8    = (u8*)(ws + Q8_OFF);       // q; k = +TOKENS*H; vt = +2*TOKENS*H bytes
    u8*      k8    = q8 + (size_t)TOKENS * H;
    u8*      vt8   = q8 + 2 * (size_t)TOKENS * H;
    u8*      big8  = (u8*)(ws + BIG_OFF);      // probs fp8 / ff1 fp8 (sequential reuse)
    u8*      wtq8  = (u8*)(ws + WTQ_OFF);      // [12][2304][768]
    u8*      wto8  = (u8*)(ws + WTO_OFF);      // [12][768][768]
    u8*      wt1   = (u8*)(ws + WT1_OFF);      // [12][3072][768]
    u8*      wt2   = (u8*)(ws + WT2_OFF);      // [12][768][3072]
    float*   embuf = ws + EM_OFF;
    float*   part  = ws + PART_OFF;
    float*   bqkv  = ws + BQKV_OFF;
    u8*      h8    = (u8*)(ws + H8_OFF);
    u8*      ctx8  = (u8*)(ws + CT8_OFF);

    // all weights -> fp8 transposed, once (no layer dependency)
    transpose_all_k<<<6912 * NLAY, 256, 0, stream>>>(
        Wq, Wk, Wv, Wo, W1, W2, wtq8, wto8, wt1, wt2);
    pack_bias_k<<<NLAY * 3, 256, 0, stream>>>(bq, bk, bv, bqkv);
    embed_ln_k<<<TOKENS / 4, 256, 0, stream>>>(token_ids, token_type, wemb, pemb,
                                               temb, eg, eb, hb, h8);

    constexpr long long SH = (long long)S * H;          // 196608
    constexpr long long ATT_B = (long long)NHD * S * S; // 786432
    constexpr long long ATT_H = (long long)S * S;       // 65536
    constexpr long long VT_B = (long long)NHD * DH * S; // 196608
    constexpr long long VT_H = (long long)DH * S;       // 16384

    dim3 gQKV(QKVN / 128, TOKENS / 128, 1);       // 18 x 64 = 1152 (%8==0)
    dim3 gProj(H / 128, TOKENS / 128, 1);         // 6 x 64 = 384
    dim3 gFF1(FF / 128, TOKENS / 128, 1);         // 24 x 64 = 1536
    dim3 gScores(1, S / 64, BATCH * NHD);         // 1 x 4 x 384
    dim3 gPV(1, 1, BATCH * NHD);                  // 256x64 tile covers head

    for (int l = 0; l < NLAY; ++l) {
        const u8* wtq_l = wtq8 + (size_t)l * 3 * HHW;
        const u8* wto_l = wto8 + (size_t)l * HHW;
        const u8* wt1_l = wt1 + (size_t)l * HFW;
        const u8* wt2_l = wt2 + (size_t)l * HFW;

        // fused q,k,v projections (FP8 GEMM, routing epilogue -> fp8 q/k/v^T)
        gemm_fp8b<2,2,9><<<gQKV, 256, 0, stream>>>(
            h8, H, 0, 0, wtq_l, H, 0, 0, bqkv + (size_t)l * QKVN,
            q8, H, 0, 0, H, 1);

        // probs = softmax(mask(q @ k^T)) per (b,h), fused epilogue -> fp8
        gemm_fp8b<1,4,6><<<gScores, 256, 0, stream>>>(
            q8, H, SH, DH, k8, H, SH, DH, (const float*)amask,
            big8, S, ATT_B, ATT_H, DH, NHD);

        // ctx = probs @ v  (per b,h) -> ctx8 fp8 as [B,S,NH,DH]
        gemm_fp8b<4,1,10><<<gPV, 256, 0, stream>>>(
            big8, S, ATT_B, ATT_H, vt8, S, VT_B, VT_H, nullptr,
            ctx8, H, SH, DH, S, NHD);

        // attention output projection (FP8 GEMM) -> obuf bf16
        gemm_fp8b<2,2,8><<<gProj, 256, 0, stream>>>(
            ctx8, H, 0, 0, wto_l, H, 0, 0, bo + l * H, obuf, H, 0, 0, H, 1);

        add_ln_k<<<TOKENS / 4, 256, 0, stream>>>(hb, obuf, ln1g + l * H, ln1b + l * H, h8);

        // ff1 = gelu(h @ W1 + b1) -> big8 fp8  (K=768)
        gemm_fp8b<2,2,7><<<gFF1, 256, 0, stream>>>(
            h8, H, 0, 0, wt1_l, H, 0, 0, b1 + (long long)l * FF, big8, FF, 0, 0, H, 1);

        // ff2 = big8 @ W2 + b2 -> obuf bf16  (K=3072)
        gemm_fp8b<2,2,8><<<gProj, 256, 0, stream>>>(
            big8, FF, 0, 0, wt2_l, FF, 0, 0, b2 + l * H, obuf, H, 0, 0, FF, 1);

        add_ln_k<<<TOKENS / 4, 256, 0, stream>>>(hb, obuf, ln2g + l * H, ln2b + l * H, h8);
    }

    logits_k<<<TOKENS, 256, 0, stream>>>(hb, fcw, embuf);
    crf_k<<<BATCH, 64, 0, stream>>>(embuf, y, amask, crf_s, crf_e, crf_t, part);
    finalize_k<<<1, 1, 0, stream>>>(part, (float*)d_out);
}

// Round 19
// 2522.557 us; speedup vs baseline: 1.7062x; 1.0016x over previous
//
#include <hip/hip_runtime.h>
#include <math.h>

typedef unsigned short ushortT;
typedef unsigned char u8;
typedef __attribute__((ext_vector_type(4))) float f32x4;
typedef __attribute__((ext_vector_type(4))) unsigned int u32x4;
typedef __attribute__((ext_vector_type(4))) unsigned short u16x4;
typedef __attribute__((ext_vector_type(4))) int i32x4;

namespace {
constexpr int S = 256;
constexpr int H = 768;
constexpr int NLAY = 12;
constexpr int NHD = 12;
constexpr int FF = 3072;
constexpr int LBL = 9;
constexpr int DH = 64;
constexpr int BATCH = 32;
constexpr int TOKENS = BATCH * S;      // 8192
constexpr int QKVN = 3 * H;            // 2304
// softmax scale folded into exponent: p = exp2(C2*(s_raw - m_raw)), C2 = 0.125*log2(e)
constexpr float C2 = 0.18033688011112042f;

constexpr size_t HHW = (size_t)H * H;   // 589824
constexpr size_t HFW = (size_t)H * FF;  // 2359296

// workspace layout (float-slot units)
constexpr size_t HB_OFF  = 0;                            // h bf16 [8192][768]
constexpr size_t OB_OFF  = HB_OFF + (size_t)TOKENS*H/2;  // bf16 scratch (attn-out / ff2-out)
constexpr size_t Q8_OFF  = OB_OFF + (size_t)TOKENS*H/2;  // fp8 q; k at +TH bytes; v^T at +2TH
constexpr size_t BIG_OFF = Q8_OFF + 3*(size_t)TOKENS*H/4; // probs fp8 [B,NH,S,S] == ff1 fp8
constexpr size_t WTQ_OFF = BIG_OFF + (size_t)TOKENS*FF/4; // all-layer Wqkv^T fp8 [12][2304][768]
constexpr size_t WTO_OFF = WTQ_OFF + (size_t)NLAY*3*HHW/4; // all-layer Wo^T fp8 [12][768][768]
constexpr size_t WT1_OFF = WTO_OFF + (size_t)NLAY*HHW/4;   // all-layer W1^T fp8 [12][3072][768]
constexpr size_t WT2_OFF = WT1_OFF + (size_t)NLAY*HFW/4;   // all-layer W2^T fp8 [12][768][3072]
constexpr size_t EM_OFF  = WT2_OFF + (size_t)NLAY*HFW/4;
constexpr size_t PART_OFF= EM_OFF + (size_t)TOKENS*LBL;
constexpr size_t BQKV_OFF= PART_OFF + 64;                // packed qkv bias [12][2304]
constexpr size_t H8_OFF  = BQKV_OFF + (size_t)NLAY*QKVN; // h fp8 copy
constexpr size_t CT8_OFF = H8_OFF + (size_t)TOKENS*H/4;  // ctx fp8 [8192][768]
constexpr size_t WS_FLOATS = CT8_OFF + (size_t)TOKENS*H/4;
}

__device__ __forceinline__ ushortT f2bf(float x) {
    unsigned u = __builtin_bit_cast(unsigned, x);
    u += 0x7fffu + ((u >> 16) & 1u);
    return (ushortT)(u >> 16);
}
__device__ __forceinline__ float bf2f(ushortT h) {
    unsigned u = ((unsigned)h) << 16;
    return __builtin_bit_cast(float, u);
}
__device__ __forceinline__ u8 f2fp8(float x) {
    return (u8)(__builtin_amdgcn_cvt_pk_fp8_f32(x, x, 0, false) & 0xff);
}
__device__ __forceinline__ unsigned f2fp8x4(float a, float b, float c, float d) {
    int p = __builtin_amdgcn_cvt_pk_fp8_f32(a, b, 0, false);
    p = __builtin_amdgcn_cvt_pk_fp8_f32(c, d, p, true);
    return (unsigned)p;
}

__device__ __forceinline__ float exp2i(float x) {
    float r; asm("v_exp_f32 %0, %1" : "=v"(r) : "v"(x)); return r;
}
__device__ __forceinline__ float log2i(float x) {
    float r; asm("v_log_f32 %0, %1" : "=v"(r) : "v"(x)); return r;
}

// tanh-gelu in sigmoid form: 0.5x(1+tanh(u)) == x*sigmoid(2u) == x/(1+exp2(-2u*log2e))
__device__ __forceinline__ float gelu_tanh(float x) {
    float u = 0.7978845608028654f * (x + 0.044715f * x * x * x);
    float t = exp2i(-2.8853900817779268f * u);
    return x / (1.0f + t);
}

__device__ __forceinline__ void gload_lds16b(const u8* g, u8* l) {
    __builtin_amdgcn_global_load_lds(
        (const __attribute__((address_space(1))) unsigned int*)g,
        (__attribute__((address_space(3))) unsigned int*)l,
        16, 0, 0);
}

// =====================================================================
// Unified FP8 e4m3 MFMA GEMM: BM=WM*64 x BN=WN*64 (WM*WN==4 waves of 64x64),
// K-step 64, 64B LDS rows, (row>>1)&3 16B-chunk both-sides swizzle,
// 3-buffer counted-vmcnt pipeline (stage group = WM+WN loads/thread ->
// vmcnt(WM+WN) certifies tile t with one group outstanding; tail re-stages
// keep the FIFO exact). 32 MFMAs/iter at bf16 MFMA rate with HALF the LDS
// bytes per FLOP (the measured binding resource).
// MODE: 6  = fused mask+row-softmax -> fp8 probs (WM=1,WN=4; BN==256==S;
//            `bias` carries the int mask pointer; ob indexes batch)
//       7  = bias+gelu -> fp8 (FF1)
//       8  = bias -> bf16 (Wo/FF2)
//       9  = fused-QKV routing -> fp8 q/k/v^T (Cv = q8; k8 +TH; vt8 +2TH bytes)
//       10 = no bias -> fp8 (PV -> ctx8)
// 2D grids (gridDim.z==1) get the XCD-aware block swizzle; grids are %8==0.
// =====================================================================
template<int WM, int WN, int MODE>
__global__ __launch_bounds__(256) void gemm_fp8b(
    const u8* __restrict__ A, int lda, long long sAo, long long sAi,
    const u8* __restrict__ Bt, int ldb, long long sBo, long long sBi,
    const float* __restrict__ bias,
    void* __restrict__ Cv, int ldc, long long sCo, long long sCi,
    int K, int innerN)
{
    constexpr int BM = WM * 64, BN = WN * 64;
    __shared__ __align__(16) u8 As[3][BM * 64];
    __shared__ __align__(16) u8 Bs[3][BN * 64];
    const int tid = threadIdx.x;
    const int wave = tid >> 6, lane = tid & 63;
    const int ob = blockIdx.z / innerN, ib = blockIdx.z - ob * innerN;

    int bxi = blockIdx.x, byi = blockIdx.y;
    if (gridDim.z == 1) {
        const int nwg = gridDim.x * gridDim.y;
        const int lin = byi * gridDim.x + bxi;
        const int cpx = nwg >> 3;
        const int sw = (lin & 7) * cpx + (lin >> 3);
        byi = sw / gridDim.x; bxi = sw - byi * gridDim.x;
    }
    const int bm = byi * BM, bn = bxi * BN;
    const u8* Ab = A + ob * sAo + ib * sAi + (size_t)bm * lda;
    const u8* Bb = Bt + ob * sBo + ib * sBi + (size_t)bn * ldb;
    const int wm = wave / WN, wn = wave - wm * WN;

    const int lrow = lane >> 2;                              // row within 16-row chunk
    const int lswb = ((lane & 3) ^ ((lrow >> 1) & 3)) * 16;  // swizzled SRC byte off
    const int rl = lane & 15;
    const int kg = lane >> 4;                                // 0..3
    const int kg4 = kg << 2;
    const int key = (rl >> 1) & 3;                           // read-side swizzle key
    const int kgh = kg >> 1, kgl8 = (kg & 1) * 8;

    f32x4 acc[4][4];
#pragma unroll
    for (int i = 0; i < 4; ++i)
#pragma unroll
        for (int j = 0; j < 4; ++j) acc[i][j] = (f32x4){0.f, 0.f, 0.f, 0.f};

    auto stage = [&](int buf, int kt) {
#pragma unroll
        for (int j = 0; j < WM; ++j) {
            int chunk = j * 4 + wave;
            gload_lds16b(Ab + (size_t)(chunk * 16 + lrow) * lda + kt * 64 + lswb,
                         &As[buf][chunk * 1024]);
        }
#pragma unroll
        for (int j = 0; j < WN; ++j) {
            int chunk = j * 4 + wave;
            gload_lds16b(Bb + (size_t)(chunk * 16 + lrow) * ldb + kt * 64 + lswb,
                         &Bs[buf][chunk * 1024]);
        }
    };

    const int nt = K >> 6;
    stage(0, 0);
    stage(1, (nt > 1) ? 1 : 0);
    int cur = 0;
    for (int t = 0; t < nt; ++t) {
        if constexpr (WM + WN == 4)
            asm volatile("s_waitcnt vmcnt(4)" ::: "memory");
        else
            asm volatile("s_waitcnt vmcnt(5)" ::: "memory");
        __builtin_amdgcn_s_barrier();
        __builtin_amdgcn_sched_barrier(0);
#pragma unroll
        for (int ks = 0; ks < 2; ++ks) {
            long a[4], b[4];
#pragma unroll
            for (int mf = 0; mf < 4; ++mf)
                a[mf] = *(const long*)&As[cur][(wm * 64 + mf * 16 + rl) * 64 +
                                               (((ks * 2 + kgh) ^ key) << 4) + kgl8];
#pragma unroll
            for (int nf = 0; nf < 4; ++nf)
                b[nf] = *(const long*)&Bs[cur][(wn * 64 + nf * 16 + rl) * 64 +
                                               (((ks * 2 + kgh) ^ key) << 4) + kgl8];
            if (ks == 0) {   // stage tile t+2 once per iter (keeps FIFO count exact)
                const int nx = (t + 2 < nt) ? t + 2 : nt - 1;
                int nb = cur + 2; if (nb >= 3) nb -= 3;
                stage(nb, nx);
            }
#pragma unroll
            for (int mf = 0; mf < 4; ++mf)
#pragma unroll
                for (int nf = 0; nf < 4; ++nf)
                    acc[mf][nf] = __builtin_amdgcn_mfma_f32_16x16x32_fp8_fp8(
                        a[mf], b[nf], acc[mf][nf], 0, 0, 0);
        }
        cur = (cur + 1 == 3) ? 0 : cur + 1;
    }
    asm volatile("s_waitcnt vmcnt(0)" ::: "memory");

    if constexpr (MODE == 6) {
        // ---- fused mask + row softmax epilogue (WM=1: all waves share rows) ----
        u8* C8 = (u8*)Cv + ob * sCo + ib * sCi;
        __shared__ float red6[2][4][64];
        const int* mrow = (const int*)bias + ob * S;
        float mb[4];
#pragma unroll
        for (int nf = 0; nf < 4; ++nf)
            mb[nf] = mrow[bn + wn * 64 + nf * 16 + rl] ? 0.f : -8e9f;
        float pm[4][4];
#pragma unroll
        for (int mf = 0; mf < 4; ++mf)
#pragma unroll
            for (int r = 0; r < 4; ++r) pm[mf][r] = -1e30f;
#pragma unroll
        for (int mf = 0; mf < 4; ++mf)
#pragma unroll
            for (int nf = 0; nf < 4; ++nf)
#pragma unroll
                for (int r = 0; r < 4; ++r) {
                    acc[mf][nf][r] += mb[nf];
                    pm[mf][r] = fmaxf(pm[mf][r], acc[mf][nf][r]);
                }
#pragma unroll
        for (int mf = 0; mf < 4; ++mf)
#pragma unroll
            for (int r = 0; r < 4; ++r) {
                float v = pm[mf][r];
                v = fmaxf(v, __shfl_xor(v, 1));
                v = fmaxf(v, __shfl_xor(v, 2));
                v = fmaxf(v, __shfl_xor(v, 4));
                v = fmaxf(v, __shfl_xor(v, 8));
                pm[mf][r] = v;
            }
        if (rl == 0) {
#pragma unroll
            for (int mf = 0; mf < 4; ++mf)
#pragma unroll
                for (int r = 0; r < 4; ++r)
                    red6[0][wn][mf * 16 + kg4 + r] = pm[mf][r];
        }
        __syncthreads();
        float Mx[4][4];
#pragma unroll
        for (int mf = 0; mf < 4; ++mf)
#pragma unroll
            for (int r = 0; r < 4; ++r) {
                const int row = mf * 16 + kg4 + r;
                Mx[mf][r] = fmaxf(fmaxf(red6[0][0][row], red6[0][1][row]),
                                  fmaxf(red6[0][2][row], red6[0][3][row]));
            }
        float ps[4][4];
#pragma unroll
        for (int mf = 0; mf < 4; ++mf)
#pragma unroll
            for (int r = 0; r < 4; ++r) ps[mf][r] = 0.f;
#pragma unroll
        for (int mf = 0; mf < 4; ++mf)
#pragma unroll
            for (int nf = 0; nf < 4; ++nf)
#pragma unroll
                for (int r = 0; r < 4; ++r) {
                    float e = exp2i(C2 * (acc[mf][nf][r] - Mx[mf][r]));
                    acc[mf][nf][r] = e;
                    ps[mf][r] += e;
                }
#pragma unroll
        for (int mf = 0; mf < 4; ++mf)
#pragma unroll
            for (int r = 0; r < 4; ++r) {
                float v = ps[mf][r];
                v += __shfl_xor(v, 1);
                v += __shfl_xor(v, 2);
                v += __shfl_xor(v, 4);
                v += __shfl_xor(v, 8);
                ps[mf][r] = v;
            }
        if (rl == 0) {
#pragma unroll
            for (int mf = 0; mf < 4; ++mf)
#pragma unroll
                for (int r = 0; r < 4; ++r)
                    red6[1][wn][mf * 16 + kg4 + r] = ps[mf][r];
        }
        __syncthreads();
#pragma unroll
        for (int mf = 0; mf < 4; ++mf) {
            float inv[4];
#pragma unroll
            for (int r = 0; r < 4; ++r) {
                const int row = mf * 16 + kg4 + r;
                inv[r] = 1.0f / (red6[1][0][row] + red6[1][1][row] +
                                 red6[1][2][row] + red6[1][3][row]);
            }
#pragma unroll
            for (int nf = 0; nf < 4; ++nf) {
                const int gn = bn + wn * 64 + nf * 16 + rl;
                const int gm = bm + mf * 16 + kg4;
#pragma unroll
                for (int r = 0; r < 4; ++r)
                    C8[(size_t)(gm + r) * ldc + gn] = f2fp8(acc[mf][nf][r] * inv[r]);
            }
        }
    } else {
#pragma unroll
        for (int nf = 0; nf < 4; ++nf) {
            const int gn = bn + wn * 64 + nf * 16 + rl;
            float bv = 0.f;
            if constexpr (MODE != 10) bv = bias[gn];
#pragma unroll
            for (int mf = 0; mf < 4; ++mf) {
                const int gm = bm + wm * 64 + mf * 16 + kg4;
                if constexpr (MODE == 7) {
                    u8* C8 = (u8*)Cv;
#pragma unroll
                    for (int r = 0; r < 4; ++r)
                        C8[(size_t)(gm + r) * ldc + gn] =
                            f2fp8(gelu_tanh(acc[mf][nf][r] + bv));
                } else if constexpr (MODE == 8) {
                    ushortT* Ch = (ushortT*)Cv;
#pragma unroll
                    for (int r = 0; r < 4; ++r)
                        Ch[(size_t)(gm + r) * ldc + gn] = f2bf(acc[mf][nf][r] + bv);
                } else if constexpr (MODE == 9) {
                    const int region = gn / H;          // 0=q,1=k,2=v
                    const int col = gn - region * H;
                    if (region < 2) {
                        u8* o = (u8*)Cv + (size_t)region * TOKENS * H;
#pragma unroll
                        for (int r = 0; r < 4; ++r)
                            o[(size_t)(gm + r) * H + col] = f2fp8(acc[mf][nf][r] + bv);
                    } else {
                        const int b_ = gm >> 8, s0 = gm & 255;
                        const int h_ = col >> 6, dh = col & 63;
                        *(unsigned*)((u8*)Cv + 2 * (size_t)TOKENS * H +
                                     (((size_t)(b_ * NHD + h_) * DH + dh) << 8) + s0) =
                            f2fp8x4(acc[mf][nf][0] + bv, acc[mf][nf][1] + bv,
                                    acc[mf][nf][2] + bv, acc[mf][nf][3] + bv);
                    }
                } else {   // MODE 10: no bias, fp8 out (PV -> ctx8)
                    u8* C8 = (u8*)Cv + ob * sCo + ib * sCi;
#pragma unroll
                    for (int r = 0; r < 4; ++r)
                        C8[(size_t)(gm + r) * ldc + gn] = f2fp8(acc[mf][nf][r]);
                }
            }
        }
    }
}

// ---------------- ALL layers' weight transposes -> fp8, one dispatch ----------------
// 64x64 input tiles; write phase = one u32x4 (16 fp8) per thread -> 64B
// contiguous per 4 lanes (the R18 32x32 version wrote 4B/thread at 2 TB/s).
// 1728 tiles/layer x 12 layers = 20736 blocks.
__global__ __launch_bounds__(256) void transpose_all_k(
    const float* __restrict__ Wq, const float* __restrict__ Wk,
    const float* __restrict__ Wv, const float* __restrict__ Wo,
    const float* __restrict__ W1, const float* __restrict__ W2,
    u8* __restrict__ wtqkv8, u8* __restrict__ wto8,
    u8* __restrict__ wt1, u8* __restrict__ wt2)
{
    const int gidx = blockIdx.x;
    const int l = gidx / 1728;
    const int idx = gidx - l * 1728;
    const float* W; int R, C, tr, tc; u8* WT8;
    if (idx < 576) {
        int mat = idx / 144, t = idx - mat * 144;
        tr = t / 12; tc = t - tr * 12; R = 768; C = 768;
        const float* base = mat == 0 ? Wq : mat == 1 ? Wk : mat == 2 ? Wv : Wo;
        W = base + (size_t)l * HHW;
        WT8 = mat < 3 ? wtqkv8 + (size_t)l * 3 * HHW + (size_t)mat * HHW
                      : wto8 + (size_t)l * HHW;
    } else if (idx < 1152) {
        int t = idx - 576; tr = t / 48; tc = t - tr * 48;
        R = 768; C = 3072; W = W1 + (size_t)l * HFW; WT8 = wt1 + (size_t)l * HFW;
    } else {
        int t = idx - 1152; tr = t / 12; tc = t - tr * 12;
        R = 3072; C = 768; W = W2 + (size_t)l * HFW; WT8 = wt2 + (size_t)l * HFW;
    }
    const int r0 = tr * 64, c0 = tc * 64;
    __shared__ float tl[64][65];
    const int tid = threadIdx.x;
    // read: 4 passes, each 64 rows x 64 f32; thread -> float4
    const int rrow = tid >> 4, rc4 = (tid & 15) * 4;
#pragma unroll
    for (int p = 0; p < 4; ++p) {
        const int row = p * 16 + rrow;
        const float4 v = *(const float4*)(W + (size_t)(r0 + row) * C + c0 + rc4);
        tl[row][rc4 + 0] = v.x; tl[row][rc4 + 1] = v.y;
        tl[row][rc4 + 2] = v.z; tl[row][rc4 + 3] = v.w;
    }
    __syncthreads();
    // write: thread -> out row c (= input col), 16 fp8 (= input rows q*16..+15)
    const int c = tid >> 2, q = tid & 3;
    u32x4 o;
#pragma unroll
    for (int w = 0; w < 4; ++w) {
        const int rb = q * 16 + w * 4;
        o[w] = f2fp8x4(tl[rb + 0][c], tl[rb + 1][c], tl[rb + 2][c], tl[rb + 3][c]);
    }
    *(u32x4*)(WT8 + (size_t)(c0 + c) * R + r0 + q * 16) = o;
}

// ---------------- pack qkv biases -> [NLAY][2304] ----------------
__global__ __launch_bounds__(256) void pack_bias_k(
    const float* __restrict__ bq, const float* __restrict__ bk,
    const float* __restrict__ bv, float* __restrict__ out)
{
    int l = blockIdx.x / 3, r = blockIdx.x - (blockIdx.x / 3) * 3;
    const float* src = r == 0 ? bq : r == 1 ? bk : bv;
#pragma unroll
    for (int j = 0; j < 3; ++j) {
        int d = threadIdx.x + 256 * j;
        out[(size_t)l * QKVN + r * H + d] = src[(size_t)l * H + d];
    }
}

// ---------------- embeddings + LN -> bf16 h + fp8 copy; 4 tokens/block ----------------
__global__ __launch_bounds__(256) void embed_ln_k(
    const int* __restrict__ ids, const int* __restrict__ tts,
    const float* __restrict__ wemb, const float* __restrict__ pemb,
    const float* __restrict__ temb, const float* __restrict__ g,
    const float* __restrict__ bp, ushortT* __restrict__ hb, u8* __restrict__ h8)
{
    const int tok = blockIdx.x * 4 + (threadIdx.x >> 6);
    const int lane = threadIdx.x & 63;
    const int d0 = lane * 12;
    const int spos = tok & (S - 1);
    const int id = ids[tok], tt = tts[tok];
    const float* wr = wemb + (size_t)id * H + d0;
    const float* pr = pemb + (size_t)spos * H + d0;
    const float* tr = temb + (size_t)tt * H + d0;
    float x[12]; float s = 0.f, ss = 0.f;
#pragma unroll
    for (int j = 0; j < 3; ++j) {
        float4 a = *(const float4*)(wr + j * 4);
        float4 b = *(const float4*)(pr + j * 4);
        float4 c = *(const float4*)(tr + j * 4);
        float v0 = a.x + b.x + c.x, v1 = a.y + b.y + c.y;
        float v2 = a.z + b.z + c.z, v3 = a.w + b.w + c.w;
        x[j*4+0] = v0; x[j*4+1] = v1; x[j*4+2] = v2; x[j*4+3] = v3;
        s += v0 + v1 + v2 + v3;
        ss += v0*v0 + v1*v1 + v2*v2 + v3*v3;
    }
#pragma unroll
    for (int m = 32; m; m >>= 1) { s += __shfl_xor(s, m); ss += __shfl_xor(ss, m); }
    float mu = s * (1.f / H);
    float var = ss * (1.f / H) - mu * mu;
    float rs = rsqrtf(var + 1e-12f);
#pragma unroll
    for (int j = 0; j < 3; ++j) {
        float4 gv = *(const float4*)(g + d0 + j * 4);
        float4 bv = *(const float4*)(bp + d0 + j * 4);
        float y0 = (x[j*4+0] - mu) * rs * gv.x + bv.x;
        float y1 = (x[j*4+1] - mu) * rs * gv.y + bv.y;
        float y2 = (x[j*4+2] - mu) * rs * gv.z + bv.z;
        float y3 = (x[j*4+3] - mu) * rs * gv.w + bv.w;
        u16x4 o;
        o[0] = f2bf(y0); o[1] = f2bf(y1); o[2] = f2bf(y2); o[3] = f2bf(y3);
        *(u16x4*)(hb + (size_t)tok * H + d0 + j * 4) = o;
        *(unsigned*)(h8 + (size_t)tok * H + d0 + j * 4) = f2fp8x4(y0, y1, y2, y3);
    }
}

// ---------------- bf16 residual add + LN, in place on hb; emits fp8 copy ----------------
__global__ __launch_bounds__(256) void add_ln_k(
    ushortT* __restrict__ hb, const ushortT* __restrict__ add,
    const float* __restrict__ g, const float* __restrict__ bp,
    u8* __restrict__ h8)
{
    const int tok = blockIdx.x * 4 + (threadIdx.x >> 6);
    const int lane = threadIdx.x & 63;
    const int d0 = lane * 12;
    const size_t base = (size_t)tok * H + d0;
    float x[12]; float s = 0.f, ss = 0.f;
#pragma unroll
    for (int j = 0; j < 3; ++j) {
        u16x4 hv = *(const u16x4*)(hb + base + j * 4);
        u16x4 av = *(const u16x4*)(add + base + j * 4);
#pragma unroll
        for (int q = 0; q < 4; ++q) {
            float v = bf2f(hv[q]) + bf2f(av[q]);
            x[j*4+q] = v; s += v; ss += v * v;
        }
    }
#pragma unroll
    for (int m = 32; m; m >>= 1) { s += __shfl_xor(s, m); ss += __shfl_xor(ss, m); }
    float mu = s * (1.f / H);
    float var = ss * (1.f / H) - mu * mu;
    float rs = rsqrtf(var + 1e-12f);
#pragma unroll
    for (int j = 0; j < 3; ++j) {
        float4 gv = *(const float4*)(g + d0 + j * 4);
        float4 bv = *(const float4*)(bp + d0 + j * 4);
        float y0 = (x[j*4+0] - mu) * rs * gv.x + bv.x;
        float y1 = (x[j*4+1] - mu) * rs * gv.y + bv.y;
        float y2 = (x[j*4+2] - mu) * rs * gv.z + bv.z;
        float y3 = (x[j*4+3] - mu) * rs * gv.w + bv.w;
        u16x4 o;
        o[0] = f2bf(y0); o[1] = f2bf(y1); o[2] = f2bf(y2); o[3] = f2bf(y3);
        *(u16x4*)(hb + base + j * 4) = o;
        *(unsigned*)(h8 + base + j * 4) = f2fp8x4(y0, y1, y2, y3);
    }
}

// ---------------- logits + log_softmax over 9 labels (bf16 h, f32 math) ----------------
__global__ __launch_bounds__(256) void logits_k(
    const ushortT* __restrict__ hb, const float* __restrict__ fcw,
    float* __restrict__ em)
{
    int tok = blockIdx.x, tid = threadIdx.x;
    float p[LBL];
#pragma unroll
    for (int l = 0; l < LBL; ++l) p[l] = 0.f;
    const ushortT* hr = hb + (size_t)tok * H;
#pragma unroll
    for (int j = 0; j < 3; ++j) {
        int d = tid + 256 * j;
        float hv = bf2f(hr[d]);
        const float* fr = fcw + (size_t)d * LBL;
#pragma unroll
        for (int l = 0; l < LBL; ++l) p[l] = fmaf(hv, fr[l], p[l]);
    }
    __shared__ float ls[4][LBL];
    __shared__ float lg[LBL];
    __shared__ float lse;
#pragma unroll
    for (int l = 0; l < LBL; ++l) {
        float v = p[l];
#pragma unroll
        for (int m = 32; m; m >>= 1) v += __shfl_xor(v, m);
        if ((tid & 63) == 0) ls[tid >> 6][l] = v;
    }
    __syncthreads();
    if (tid < LBL) lg[tid] = ls[0][tid] + ls[1][tid] + ls[2][tid] + ls[3][tid];
    __syncthreads();
    if (tid == 0) {
        float mx = lg[0];
#pragma unroll
        for (int j = 1; j < LBL; ++j) mx = fmaxf(mx, lg[j]);
        float sm = 0.f;
#pragma unroll
        for (int j = 0; j < LBL; ++j) sm += expf(lg[j] - mx);
        lse = mx + logf(sm);
    }
    __syncthreads();
    if (tid < LBL) em[(size_t)tok * LBL + tid] = lg[tid] - lse;
}

// ---------------- CRF: one wave per batch elem, base-2 fast recursion ----------------
__global__ __launch_bounds__(64) void crf_k(
    const float* __restrict__ em, const int* __restrict__ tags,
    const int* __restrict__ mask, const float* __restrict__ sp,
    const float* __restrict__ ep, const float* __restrict__ trans,
    float* __restrict__ partial)
{
    constexpr float LOG2E = 1.4426950408889634f;
    constexpr float LN2   = 0.6931471805599453f;
    int b = blockIdx.x, t = threadIdx.x;
    __shared__ float eml[S * LBL];     // emissions * log2(e)
    __shared__ int mkl[S];
    const float* emb = em + (size_t)b * S * LBL;
    const int* tg = tags + (size_t)b * S;
    const int* mk = mask + (size_t)b * S;

    for (int i = t * 4; i < S * LBL; i += 256) {
        float4 v = *(const float4*)&emb[i];
        v.x *= LOG2E; v.y *= LOG2E; v.z *= LOG2E; v.w *= LOG2E;
        *(float4*)&eml[i] = v;
    }
    *(i32x4*)&mkl[t * 4] = *(const i32x4*)&mk[t * 4];

    int cnt = 0; float ns = 0.f;
    for (int i = t; i < S; i += 64) {
        int m = mk[i];
        cnt += (m != 0);
        if (i >= 1 && m)
            ns += trans[tg[i - 1] * LBL + tg[i]] + emb[(size_t)i * LBL + tg[i]];
    }
#pragma unroll
    for (int m = 32; m; m >>= 1) { cnt += __shfl_xor(cnt, m); ns += __shfl_xor(ns, m); }
    float num = ns + sp[tg[0]] + emb[tg[0]] + ep[tg[cnt - 1]];

    int tt = t < LBL ? t : 0;
    float trc2[LBL];
#pragma unroll
    for (int i = 0; i < LBL; ++i) trc2[i] = trans[i * LBL + tt] * LOG2E;

    __syncthreads();

    float alpha2 = (t < LBL) ? sp[t] * LOG2E + eml[t] : -1e30f;
    for (int step = 1; step < S; ++step) {
        float av[LBL];
#pragma unroll
        for (int i = 0; i < LBL; ++i) av[i] = __shfl(alpha2, i) + trc2[i];
        float mx = av[0];
#pragma unroll
        for (int i = 1; i < LBL; ++i) mx = fmaxf(mx, av[i]);
        float sm = 0.f;
#pragma unroll
        for (int i = 0; i < LBL; ++i) sm += exp2i(av[i] - mx);
        float na = mx + log2i(sm) + eml[step * LBL + tt];
        alpha2 = (mkl[step] && t < LBL) ? na : alpha2;
    }
    float z = (t < LBL) ? alpha2 + ep[t] * LOG2E : -1e30f;
    float mx = z;
#pragma unroll
    for (int m = 8; m; m >>= 1) mx = fmaxf(mx, __shfl_xor(mx, m));
    float sm = exp2i(z - mx);
#pragma unroll
    for (int m = 8; m; m >>= 1) sm += __shfl_xor(sm, m);
    if (t == 0) partial[b] = (mx + log2i(sm)) * LN2 - num;
}

__global__ void finalize_k(const float* __restrict__ partial, float* __restrict__ out) {
    float s = 0.f;
    for (int i = 0; i < BATCH; ++i) s += partial[i];
    out[0] = s;
}

__global__ void sentinel_k(float* out) { out[0] = -12345.0f; }

extern "C" void kernel_launch(void* const* d_in, const int* in_sizes, int n_in,
                              void* d_out, int out_size, void* d_ws, size_t ws_size,
                              hipStream_t stream) {
    (void)in_sizes; (void)n_in; (void)out_size;
    const int* token_ids  = (const int*)d_in[0];
    const int* token_type = (const int*)d_in[1];
    const int* amask      = (const int*)d_in[2];
    const int* y          = (const int*)d_in[3];
    const float* wemb = (const float*)d_in[4];
    const float* pemb = (const float*)d_in[5];
    const float* temb = (const float*)d_in[6];
    const float* eg   = (const float*)d_in[7];
    const float* eb   = (const float*)d_in[8];
    const float* Wq = (const float*)d_in[9];
    const float* bq = (const float*)d_in[10];
    const float* Wk = (const float*)d_in[11];
    const float* bk = (const float*)d_in[12];
    const float* Wv = (const float*)d_in[13];
    const float* bv = (const float*)d_in[14];
    const float* Wo = (const float*)d_in[15];
    const float* bo = (const float*)d_in[16];
    const float* ln1g = (const float*)d_in[17];
    const float* ln1b = (const float*)d_in[18];
    const float* W1 = (const float*)d_in[19];
    const float* b1 = (const float*)d_in[20];
    const float* W2 = (const float*)d_in[21];
    const float* b2 = (const float*)d_in[22];
    const float* ln2g = (const float*)d_in[23];
    const float* ln2b = (const float*)d_in[24];
    const float* fcw = (const float*)d_in[25];
    const float* crf_s = (const float*)d_in[26];
    const float* crf_e = (const float*)d_in[27];
    const float* crf_t = (const float*)d_in[28];

    if (ws_size < WS_FLOATS * sizeof(float)) {
        sentinel_k<<<1, 1, 0, stream>>>((float*)d_out);
        return;
    }

    float* ws = (float*)d_ws;
    ushortT* hb    = (ushortT*)(ws + HB_OFF);
    ushortT* obuf  = (ushortT*)(ws + OB_OFF);  // bf16 scratch (attn-out / ff2-out)
    u8*      q8    = (u8*)(ws + Q8_OFF);       // q; k = +TOKENS*H; vt = +2*TOKENS*H bytes
    u8*      k8    = q8 + (size_t)TOKENS * H;
    u8*      vt8   = q8 + 2 * (size_t)TOKENS * H;
    u8*      big8  = (u8*)(ws + BIG_OFF);      // probs fp8 / ff1 fp8 (sequential reuse)
    u8*      wtq8  = (u8*)(ws + WTQ_OFF);      // [12][2304][768]
    u8*      wto8  = (u8*)(ws + WTO_OFF);      // [12][768][768]
    u8*      wt1   = (u8*)(ws + WT1_OFF);      // [12][3072][768]
    u8*      wt2   = (u8*)(ws + WT2_OFF);      // [12][768][3072]
    float*   embuf = ws + EM_OFF;
    float*   part  = ws + PART_OFF;
    float*   bqkv  = ws + BQKV_OFF;
    u8*      h8    = (u8*)(ws + H8_OFF);
    u8*      ctx8  = (u8*)(ws + CT8_OFF);

    // all weights -> fp8 transposed, once (no layer dependency)
    transpose_all_k<<<1728 * NLAY, 256, 0, stream>>>(
        Wq, Wk, Wv, Wo, W1, W2, wtq8, wto8, wt1, wt2);
    pack_bias_k<<<NLAY * 3, 256, 0, stream>>>(bq, bk, bv, bqkv);
    embed_ln_k<<<TOKENS / 4, 256, 0, stream>>>(token_ids, token_type, wemb, pemb,
                                               temb, eg, eb, hb, h8);

    constexpr long long SH = (long long)S * H;          // 196608
    constexpr long long ATT_B = (long long)NHD * S * S; // 786432
    constexpr long long ATT_H = (long long)S * S;       // 65536
    constexpr long long VT_B = (long long)NHD * DH * S; // 196608
    constexpr long long VT_H = (long long)DH * S;       // 16384

    dim3 gQKV(QKVN / 128, TOKENS / 128, 1);       // 18 x 64 = 1152 (%8==0)
    dim3 gProj(H / 128, TOKENS / 128, 1);         // 6 x 64 = 384
    dim3 gFF1(FF / 128, TOKENS / 128, 1);         // 24 x 64 = 1536
    dim3 gScores(1, S / 64, BATCH * NHD);         // 1 x 4 x 384
    dim3 gPV(1, 1, BATCH * NHD);                  // 256x64 tile covers head

    for (int l = 0; l < NLAY; ++l) {
        const u8* wtq_l = wtq8 + (size_t)l * 3 * HHW;
        const u8* wto_l = wto8 + (size_t)l * HHW;
        const u8* wt1_l = wt1 + (size_t)l * HFW;
        const u8* wt2_l = wt2 + (size_t)l * HFW;

        // fused q,k,v projections (FP8 GEMM, routing epilogue -> fp8 q/k/v^T)
        gemm_fp8b<2,2,9><<<gQKV, 256, 0, stream>>>(
            h8, H, 0, 0, wtq_l, H, 0, 0, bqkv + (size_t)l * QKVN,
            q8, H, 0, 0, H, 1);

        // probs = softmax(mask(q @ k^T)) per (b,h), fused epilogue -> fp8
        gemm_fp8b<1,4,6><<<gScores, 256, 0, stream>>>(
            q8, H, SH, DH, k8, H, SH, DH, (const float*)amask,
            big8, S, ATT_B, ATT_H, DH, NHD);

        // ctx = probs @ v  (per b,h) -> ctx8 fp8 as [B,S,NH,DH]
        gemm_fp8b<4,1,10><<<gPV, 256, 0, stream>>>(
            big8, S, ATT_B, ATT_H, vt8, S, VT_B, VT_H, nullptr,
            ctx8, H, SH, DH, S, NHD);

        // attention output projection (FP8 GEMM) -> obuf bf16
        gemm_fp8b<2,2,8><<<gProj, 256, 0, stream>>>(
            ctx8, H, 0, 0, wto_l, H, 0, 0, bo + l * H, obuf, H, 0, 0, H, 1);

        add_ln_k<<<TOKENS / 4, 256, 0, stream>>>(hb, obuf, ln1g + l * H, ln1b + l * H, h8);

        // ff1 = gelu(h @ W1 + b1) -> big8 fp8  (K=768)
        gemm_fp8b<2,2,7><<<gFF1, 256, 0, stream>>>(
            h8, H, 0, 0, wt1_l, H, 0, 0, b1 + (long long)l * FF, big8, FF, 0, 0, H, 1);

        // ff2 = big8 @ W2 + b2 -> obuf bf16  (K=3072)
        gemm_fp8b<2,2,8><<<gProj, 256, 0, stream>>>(
            big8, FF, 0, 0, wt2_l, FF, 0, 0, b2 + l * H, obuf, H, 0, 0, FF, 1);

        add_ln_k<<<TOKENS / 4, 256, 0, stream>>>(hb, obuf, ln2g + l * H, ln2b + l * H, h8);
    }

    logits_k<<<TOKENS, 256, 0, stream>>>(hb, fcw, embuf);
    crf_k<<<BATCH, 64, 0, stream>>>(embuf, y, amask, crf_s, crf_e, crf_t, part);
    finalize_k<<<1, 1, 0, stream>>>(part, (float*)d_out);
}